// Round 6
// baseline (189.756 us; speedup 1.0000x reference)
//
#include <hip/hip_runtime.h>
#include <hip/hip_bf16.h>
#include <math.h>

#define NH 12
#define DH 64
#define SL 1024
#define NB 8
#define ED 768
#define NTAP 2047
#define NF 33
#define NSEQ 2048

typedef __attribute__((ext_vector_type(8))) short bf16x8;
typedef __attribute__((ext_vector_type(4))) float f32x4;

#define GLB_U32(p) ((const __attribute__((address_space(1))) unsigned int*)(p))
#define LDS_U32(p) ((__attribute__((address_space(3))) unsigned int*)(p))

__device__ __forceinline__ float2 cadd(float2 a, float2 b){ return make_float2(a.x+b.x, a.y+b.y); }
__device__ __forceinline__ float2 csub(float2 a, float2 b){ return make_float2(a.x-b.x, a.y-b.y); }
__device__ __forceinline__ float2 cmul(float2 a, float2 b){ return make_float2(a.x*b.x - a.y*b.y, a.x*b.y + a.y*b.x); }

__device__ __forceinline__ unsigned short bf16bits(float f) {
    __hip_bfloat16 hb = __float2bfloat16(f);
    return *reinterpret_cast<unsigned short*>(&hb);
}
__device__ __forceinline__ float bf16val(unsigned short u) {
    __hip_bfloat16 hb = *reinterpret_cast<__hip_bfloat16*>(&u);
    return __bfloat162float(hb);
}
// split two fp32 into packed bf16 hi-pair and lo-pair
__device__ __forceinline__ void split2(float a, float b, unsigned int& hp, unsigned int& lp) {
    unsigned short ha = bf16bits(a), hb = bf16bits(b);
    unsigned short la = bf16bits(a - bf16val(ha)), lb = bf16bits(b - bf16val(hb));
    hp = (unsigned int)ha | ((unsigned int)hb << 16);
    lp = (unsigned int)la | ((unsigned int)lb << 16);
}

// ---------------- Stockham FFT pieces (N=2048 = 8*8*8*4, constant geometry) ----------------
#define FPAD(i) ((i) + ((i) >> 3))

template<int DIR>
__device__ __forceinline__ void dft4v(float2 v[4]) {
    float2 e0 = cadd(v[0], v[2]), e1 = csub(v[0], v[2]);
    float2 o0 = cadd(v[1], v[3]), o1 = csub(v[1], v[3]);
    float2 o1t = (DIR < 0) ? make_float2(o1.y, -o1.x) : make_float2(-o1.y, o1.x);
    v[0] = cadd(e0, o0);
    v[1] = cadd(e1, o1t);
    v[2] = csub(e0, o0);
    v[3] = csub(e1, o1t);
}

template<int DIR>
__device__ __forceinline__ void dft8v(float2 v[8]) {
    const float RS = 0.70710678118654752440f;
    float2 e[4] = { v[0], v[2], v[4], v[6] };
    float2 o[4] = { v[1], v[3], v[5], v[7] };
    dft4v<DIR>(e);
    dft4v<DIR>(o);
    float2 t1 = (DIR < 0) ? make_float2(RS * (o[1].x + o[1].y), RS * (o[1].y - o[1].x))
                          : make_float2(RS * (o[1].x - o[1].y), RS * (o[1].y + o[1].x));
    float2 t2 = (DIR < 0) ? make_float2(o[2].y, -o[2].x) : make_float2(-o[2].y, o[2].x);
    float2 t3 = (DIR < 0) ? make_float2(RS * (o[3].y - o[3].x), RS * (-o[3].x - o[3].y))
                          : make_float2(RS * (-o[3].x - o[3].y), RS * (o[3].x - o[3].y));
    v[0] = cadd(e[0], o[0]); v[4] = csub(e[0], o[0]);
    v[1] = cadd(e[1], t1);   v[5] = csub(e[1], t1);
    v[2] = cadd(e[2], t2);   v[6] = csub(e[2], t2);
    v[3] = cadd(e[3], t3);   v[7] = csub(e[3], t3);
}

template<int DIR, int L, int R>
__device__ __forceinline__ void fft_stage(const float* __restrict__ sr, const float* __restrict__ si,
                                          float* __restrict__ dr, float* __restrict__ di,
                                          const float2* __restrict__ twd, int tid) {
    const int T = 2048 / R;
    #pragma unroll
    for (int jj = 0; jj < T; jj += 256) {
        int j = tid + jj;
        int k = j & (L - 1);
        int blk = j / L;
        float2 v[R];
        #pragma unroll
        for (int r = 0; r < R; ++r) {
            int idx = FPAD(j + T * r);
            v[r] = make_float2(sr[idx], si[idx]);
        }
        if (L > 1) {
            const int c = 2048 / (R * L);
            float2 w1 = twd[c * k];
            if (DIR > 0) w1.y = -w1.y;
            float2 w = w1;
            v[1] = cmul(v[1], w);
            #pragma unroll
            for (int r = 2; r < R; ++r) { w = cmul(w, w1); v[r] = cmul(v[r], w); }
        }
        if (R == 8) dft8v<DIR>(v); else dft4v<DIR>(v);
        int base = blk * (R * L) + k;
        #pragma unroll
        for (int r = 0; r < R; ++r) {
            int idx = FPAD(base + L * r);
            dr[idx] = v[r].x; di[idx] = v[r].y;
        }
    }
}

// ktw: twiddle table W_2048^i, i<512
__global__ void ktw(float2* __restrict__ twg) {
    int i = blockIdx.x * 256 + threadIdx.x;
    if (i < 512) {
        float ang = -6.28318530717958647692f * (float)i / 2048.0f;
        twg[i] = make_float2(cosf(ang), sinf(ang));
    }
}

// ---------------- K1: 3-pass coalesced softmax over taps ----------------
__global__ void k1a_partial(const float* __restrict__ tp, float* __restrict__ pMax, float* __restrict__ pSum) {
    __shared__ float lm[4][64], ls[4][64];
    int c = blockIdx.x, h = blockIdx.y;
    int tid = threadIdx.x, w = tid >> 6, e = tid & 63;
    const float* base = tp + (size_t)h * NTAP * 64;
    float m = -1e30f, s = 0.f;
    #pragma unroll
    for (int i = 0; i < 16; ++i) {
        int row = c * 64 + w + 4 * i;
        if (row < NTAP) {
            float v = base[(size_t)row * 64 + e];
            float mn = fmaxf(m, v);
            s = s * expf(m - mn) + expf(v - mn);
            m = mn;
        }
    }
    lm[w][e] = m; ls[w][e] = s;
    __syncthreads();
    if (w == 0) {
        float M = m, S = s;
        #pragma unroll
        for (int i = 1; i < 4; ++i) {
            float mi = lm[i][e], si = ls[i][e];
            float mn = fmaxf(M, mi);
            S = S * expf(M - mn) + si * expf(mi - mn);
            M = mn;
        }
        pMax[(h * 32 + c) * 64 + e] = M;
        pSum[(h * 32 + c) * 64 + e] = S;
    }
}

__global__ void k1b_fold(const float* __restrict__ pMax, const float* __restrict__ pSum,
                         float* __restrict__ Mf, float* __restrict__ Invf) {
    int h = blockIdx.x, e = threadIdx.x;
    float M = -1e30f, S = 0.f;
    for (int c = 0; c < 32; ++c) {
        float mi = pMax[(h * 32 + c) * 64 + e], si = pSum[(h * 32 + c) * 64 + e];
        float mn = fmaxf(M, mi);
        S = S * expf(M - mn) + si * expf(mi - mn);
        M = mn;
    }
    Mf[h * 64 + e] = M;
    Invf[h * 64 + e] = 1.0f / S;
}

__global__ void k1c_norm(const float* __restrict__ tp, const float* __restrict__ Mf,
                         const float* __restrict__ Invf, float* __restrict__ psf_out) {
    int c = blockIdx.x, h = blockIdx.y;
    int tid = threadIdx.x, w = tid >> 6, e = tid & 63;
    float M = Mf[h * 64 + e], inv = Invf[h * 64 + e];
    const float* base = tp + (size_t)h * NTAP * 64;
    float* ob = psf_out + (size_t)h * NTAP * 64;
    #pragma unroll
    for (int i = 0; i < 16; ++i) {
        int row = c * 64 + w + 4 * i;
        if (row < NTAP) {
            float o = 0.f;
            if (row < SL) o = expf(base[(size_t)row * 64 + e] - M) * inv;
            ob[(size_t)row * 64 + e] = o;
        }
    }
}

// K2: channel DFT-64 (forward, f=0..32) of masked psf; output Pc[h][f][s] (s<1024).
__global__ void k2_psf_cdft(const float* __restrict__ psf, float2* __restrict__ Pc) {
    __shared__ float p[64][65];
    __shared__ float2 tw[64];
    int s0 = blockIdx.x * 64;
    int h = blockIdx.y;
    for (int i = threadIdx.x; i < 64; i += 256) {
        float ang = 6.28318530717958647692f * (float)i / 64.0f;
        tw[i] = make_float2(cosf(ang), sinf(ang));
    }
    for (int i = threadIdx.x; i < 4096; i += 256) {
        int sl = i >> 6, e = i & 63;
        p[sl][e] = psf[((size_t)h * NTAP + (s0 + sl)) * 64 + e];
    }
    __syncthreads();
    for (int o = threadIdx.x; o < NF * 64; o += 256) {
        int f = o >> 6, sl = o & 63;
        float re = 0.f, im = 0.f;
        for (int e = 0; e < 64; ++e) {
            int m = (e * f) & 63;
            float v = p[sl][e];
            re += v * tw[m].x;
            im -= v * tw[m].y;
        }
        Pc[(size_t)(h * NF + f) * SL + (s0 + sl)] = make_float2(re, im);
    }
}

// K3: seq FFT-2048 of psf per (h,f), Stockham, natural order out.
__global__ __launch_bounds__(256) void k3_psf_fft(const float2* __restrict__ Pc, float2* __restrict__ Pf,
                                                  const float2* __restrict__ twg) {
    __shared__ float Ar[2304], Ai[2304], Br[2304], Bi[2304];
    __shared__ float2 twd[512];
    int h = blockIdx.x / NF, f = blockIdx.x % NF;
    int tid = threadIdx.x;
    for (int i = tid; i < 512; i += 256) twd[i] = twg[i];
    const float2* src = Pc + (size_t)(h * NF + f) * SL;
    {
        float2 v[8];
        #pragma unroll
        for (int r = 0; r < 4; ++r) v[r] = src[tid + 256 * r];
        #pragma unroll
        for (int r = 4; r < 8; ++r) v[r] = make_float2(0.f, 0.f);
        dft8v<-1>(v);
        #pragma unroll
        for (int r = 0; r < 8; ++r) {
            int idx = FPAD(tid * 8 + r);
            Ar[idx] = v[r].x; Ai[idx] = v[r].y;
        }
    }
    __syncthreads();
    fft_stage<-1, 8, 8>(Ar, Ai, Br, Bi, twd, tid);  __syncthreads();
    fft_stage<-1, 64, 8>(Br, Bi, Ar, Ai, twd, tid); __syncthreads();
    float2* dst = Pf + (size_t)(h * NF + f) * NSEQ;
    #pragma unroll
    for (int jj = 0; jj < 512; jj += 256) {
        int j = tid + jj;
        float2 v[4];
        #pragma unroll
        for (int r = 0; r < 4; ++r) {
            int idx = FPAD(j + 512 * r);
            v[r] = make_float2(Ar[idx], Ai[idx]);
        }
        float2 w1 = twd[j];
        float2 w = w1;
        v[1] = cmul(v[1], w);
        w = cmul(w, w1); v[2] = cmul(v[2], w);
        w = cmul(w, w1); v[3] = cmul(v[3], w);
        dft4v<-1>(v);
        #pragma unroll
        for (int r = 0; r < 4; ++r) dst[j + 512 * r] = v[r];
    }
}

// K4m: channel DFT-64 as split-bf16 MFMA; staging pre-splits to bf16 hi/lo in LDS.
__global__ __launch_bounds__(256) void k4_mfma(const float* __restrict__ emb,
                                               float* __restrict__ XcRe, float* __restrict__ XcIm) {
    __shared__ union {
        struct {
            ushort EH[128][72], EL[128][72];   // emb hi/lo, 144B rows (16B aligned)
            ushort CH[80][72],  CL[80][72];    // dft matrix hi/lo
        } s;
        float Dl[66][133];
    } u;
    const int t0 = blockIdx.x * 128;
    const int bh = blockIdx.y;
    const int b = bh / NH, h = bh % NH;
    const int tid = threadIdx.x, lane = tid & 63, w = tid >> 6;

    // stage emb tile [128][64] -> bf16 hi/lo
    for (int i = tid; i < 128 * 16; i += 256) {
        int r = i >> 4, q = i & 15;
        float4 v = *(const float4*)&emb[((size_t)b * SL + t0 + r) * ED + h * 64 + q * 4];
        unsigned int hp, lp;
        split2(v.x, v.y, hp, lp);
        *(unsigned int*)&u.s.EH[r][q * 4]     = hp;  *(unsigned int*)&u.s.EL[r][q * 4]     = lp;
        split2(v.z, v.w, hp, lp);
        *(unsigned int*)&u.s.EH[r][q * 4 + 2] = hp;  *(unsigned int*)&u.s.EL[r][q * 4 + 2] = lp;
    }
    // stage DFT matrix C[c][e] (c<33 cos, 33..65 -sin, else 0) -> bf16 hi/lo, pack 2 e's
    for (int i = tid; i < 80 * 32; i += 256) {
        int c = i >> 5, e2 = (i & 31) * 2;
        float v0 = 0.f, v1 = 0.f;
        if (c < 33) {
            v0 = cosf(0.09817477042468103870f * (float)((c * e2) & 63));
            v1 = cosf(0.09817477042468103870f * (float)((c * (e2 + 1)) & 63));
        } else if (c < 66) {
            v0 = -sinf(0.09817477042468103870f * (float)(((c - 33) * e2) & 63));
            v1 = -sinf(0.09817477042468103870f * (float)(((c - 33) * (e2 + 1)) & 63));
        }
        unsigned int hp, lp;
        split2(v0, v1, hp, lp);
        *(unsigned int*)&u.s.CH[c][e2] = hp;  *(unsigned int*)&u.s.CL[c][e2] = lp;
    }
    __syncthreads();

    // MFMA: M=128 (4 waves x 2 frags), N=80 (5 frags), K=64 (2 steps); pure ds_read_b128 inner
    f32x4 acc[2][5] = {};
    const int lr = lane & 15, lg = lane >> 4;
    #pragma unroll
    for (int ks = 0; ks < 64; ks += 32) {
        const int kg = ks + lg * 8;
        bf16x8 bh8[5], bl8[5];
        #pragma unroll
        for (int n = 0; n < 5; ++n) {
            bh8[n] = *(const bf16x8*)&u.s.CH[n * 16 + lr][kg];
            bl8[n] = *(const bf16x8*)&u.s.CL[n * 16 + lr][kg];
        }
        #pragma unroll
        for (int m = 0; m < 2; ++m) {
            const int row = w * 32 + m * 16 + lr;
            bf16x8 ah8 = *(const bf16x8*)&u.s.EH[row][kg];
            bf16x8 al8 = *(const bf16x8*)&u.s.EL[row][kg];
            #pragma unroll
            for (int n = 0; n < 5; ++n) {
                acc[m][n] = __builtin_amdgcn_mfma_f32_16x16x32_bf16(ah8, bh8[n], acc[m][n], 0, 0, 0);
                acc[m][n] = __builtin_amdgcn_mfma_f32_16x16x32_bf16(ah8, bl8[n], acc[m][n], 0, 0, 0);
                acc[m][n] = __builtin_amdgcn_mfma_f32_16x16x32_bf16(al8, bh8[n], acc[m][n], 0, 0, 0);
            }
        }
    }
    __syncthreads();
    #pragma unroll
    for (int n = 0; n < 5; ++n) {
        int c = n * 16 + lr;
        if (c < 66) {
            #pragma unroll
            for (int m = 0; m < 2; ++m)
                #pragma unroll
                for (int j = 0; j < 4; ++j)
                    u.Dl[c][w * 32 + m * 16 + lg * 4 + j] = acc[m][n][j];
        }
    }
    __syncthreads();
    for (int i = tid; i < 66 * 128; i += 256) {
        int c = i >> 7, t = i & 127;
        float val = u.Dl[c][t];
        if (c < 33) XcRe[(size_t)(bh * NF + c) * SL + t0 + t] = val;
        else        XcIm[(size_t)(bh * NF + (c - 33)) * SL + t0 + t] = val;
    }
}

// K5: Stockham fwd FFT -> pointwise * Pf -> Stockham inv FFT, in-place on Xc planes.
__global__ __launch_bounds__(256) void k5_seq_conv(float* __restrict__ XcRe, float* __restrict__ XcIm,
                                                   const float2* __restrict__ Pf,
                                                   const float2* __restrict__ twg) {
    __shared__ float Ar[2304], Ai[2304], Br[2304], Bi[2304];
    __shared__ float2 twd[512];
    int f = blockIdx.x % NF;
    int bh = blockIdx.x / NF;
    int h = bh % NH;
    int tid = threadIdx.x;
    for (int i = tid; i < 512; i += 256) twd[i] = twg[i];
    float* xre = XcRe + (size_t)(bh * NF + f) * SL;
    float* xim = XcIm + (size_t)(bh * NF + f) * SL;
    {
        float2 v[8];
        #pragma unroll
        for (int r = 0; r < 4; ++r) v[r] = make_float2(xre[tid + 256 * r], xim[tid + 256 * r]);
        #pragma unroll
        for (int r = 4; r < 8; ++r) v[r] = make_float2(0.f, 0.f);
        dft8v<-1>(v);
        #pragma unroll
        for (int r = 0; r < 8; ++r) {
            int idx = FPAD(tid * 8 + r);
            Ar[idx] = v[r].x; Ai[idx] = v[r].y;
        }
    }
    __syncthreads();
    fft_stage<-1, 8, 8>(Ar, Ai, Br, Bi, twd, tid);   __syncthreads();
    fft_stage<-1, 64, 8>(Br, Bi, Ar, Ai, twd, tid);  __syncthreads();
    fft_stage<-1, 512, 4>(Ar, Ai, Br, Bi, twd, tid); __syncthreads();
    const float2* pf = Pf + (size_t)(h * NF + f) * NSEQ;
    #pragma unroll
    for (int q = 0; q < 8; ++q) {
        int i = tid + 256 * q;
        int idx = FPAD(i);
        float2 a = make_float2(Br[idx], Bi[idx]);
        float2 p = cmul(a, pf[i]);
        Br[idx] = p.x; Bi[idx] = p.y;
    }
    __syncthreads();
    fft_stage<1, 1, 8>(Br, Bi, Ar, Ai, twd, tid);  __syncthreads();
    fft_stage<1, 8, 8>(Ar, Ai, Br, Bi, twd, tid);  __syncthreads();
    fft_stage<1, 64, 8>(Br, Bi, Ar, Ai, twd, tid); __syncthreads();
    const float sc = 1.0f / 2048.0f;
    #pragma unroll
    for (int jj = 0; jj < 512; jj += 256) {
        int j = tid + jj;
        float2 v[4];
        #pragma unroll
        for (int r = 0; r < 4; ++r) {
            int idx = FPAD(j + 512 * r);
            v[r] = make_float2(Ar[idx], Ai[idx]);
        }
        float2 w1 = twd[j];
        w1.y = -w1.y;
        float2 w = w1;
        v[1] = cmul(v[1], w);
        w = cmul(w, w1); v[2] = cmul(v[2], w);
        w = cmul(w, w1); v[3] = cmul(v[3], w);
        dft4v<1>(v);
        xre[j] = v[0].x * sc;        xim[j] = v[0].y * sc;
        xre[j + 512] = v[1].x * sc;  xim[j + 512] = v[1].y * sc;
    }
}

// K6m: inverse channel DFT-64 as split-bf16 MFMA + exact GELU.
// Staging: fp32 [c][t] -> LDS transpose -> bf16 hi/lo [t][c]; inner loop pure ds_read_b128.
__global__ __launch_bounds__(256) void k6_mfma(const float* __restrict__ XcRe,
                                               const float* __restrict__ XcIm,
                                               ushort* __restrict__ Gh, ushort* __restrict__ Gl) {
    __shared__ union {
        float Y32[64][133];                         // pass1: [c][t_local] fp32
        struct { ushort CH[64][72], CL[64][72]; } c; // after pass2: DFT matrix hi/lo
    } uy;
    __shared__ ushort YH[128][72], YL[128][72];     // [t][c] bf16 hi/lo
    const int t0 = blockIdx.x * 128;
    const int bh = blockIdx.y;
    const int b = bh / NH, h = bh % NH;
    const int tid = threadIdx.x, lane = tid & 63, w = tid >> 6;

    // pass1: stage Y fp32 [c][t]
    for (int i = tid; i < 64 * 32; i += 256) {
        int c = i >> 5, tq = i & 31;
        const float* src = (c < 33) ? XcRe + (size_t)(bh * NF + c) * SL
                                    : XcIm + (size_t)(bh * NF + (c - 32)) * SL;
        float4 v = *(const float4*)&src[t0 + tq * 4];
        uy.Y32[c][tq * 4 + 0] = v.x; uy.Y32[c][tq * 4 + 1] = v.y;
        uy.Y32[c][tq * 4 + 2] = v.z; uy.Y32[c][tq * 4 + 3] = v.w;
    }
    __syncthreads();
    // pass2: transpose + split -> YH/YL [t][c]
    for (int i = tid; i < 128 * 8; i += 256) {
        int t = i & 127, c0 = (i >> 7) * 8;
        float v[8];
        #pragma unroll
        for (int j = 0; j < 8; ++j) v[j] = uy.Y32[c0 + j][t];
        unsigned int hp, lp;
        #pragma unroll
        for (int j = 0; j < 8; j += 2) {
            split2(v[j], v[j + 1], hp, lp);
            *(unsigned int*)&YH[t][c0 + j] = hp;
            *(unsigned int*)&YL[t][c0 + j] = lp;
        }
    }
    __syncthreads();
    // gen C[e][c] hi/lo into union (Y32 now dead)
    for (int i = tid; i < 64 * 32; i += 256) {
        int e = i >> 5, c2 = (i & 31) * 2;
        float v[2];
        #pragma unroll
        for (int j = 0; j < 2; ++j) {
            int c = c2 + j;
            if (c <= 32) {
                float wt = (c == 0 || c == 32) ? (1.0f / 64.0f) : (2.0f / 64.0f);
                v[j] = wt * cosf(0.09817477042468103870f * (float)((c * e) & 63));
            } else {
                v[j] = -(2.0f / 64.0f) * sinf(0.09817477042468103870f * (float)(((c - 32) * e) & 63));
            }
        }
        unsigned int hp, lp;
        split2(v[0], v[1], hp, lp);
        *(unsigned int*)&uy.c.CH[e][c2] = hp;
        *(unsigned int*)&uy.c.CL[e][c2] = lp;
    }
    __syncthreads();

    // MFMA: M=128 rows t (4 waves x 2), N=64 cols e (4 frags), K=64 (2 steps)
    f32x4 acc[2][4] = {};
    const int lr = lane & 15, lg = lane >> 4;
    #pragma unroll
    for (int ks = 0; ks < 64; ks += 32) {
        const int kg = ks + lg * 8;
        bf16x8 bh8[4], bl8[4];
        #pragma unroll
        for (int n = 0; n < 4; ++n) {
            bh8[n] = *(const bf16x8*)&uy.c.CH[n * 16 + lr][kg];
            bl8[n] = *(const bf16x8*)&uy.c.CL[n * 16 + lr][kg];
        }
        #pragma unroll
        for (int m = 0; m < 2; ++m) {
            const int row = w * 32 + m * 16 + lr;
            bf16x8 ah8 = *(const bf16x8*)&YH[row][kg];
            bf16x8 al8 = *(const bf16x8*)&YL[row][kg];
            #pragma unroll
            for (int n = 0; n < 4; ++n) {
                acc[m][n] = __builtin_amdgcn_mfma_f32_16x16x32_bf16(ah8, bh8[n], acc[m][n], 0, 0, 0);
                acc[m][n] = __builtin_amdgcn_mfma_f32_16x16x32_bf16(ah8, bl8[n], acc[m][n], 0, 0, 0);
                acc[m][n] = __builtin_amdgcn_mfma_f32_16x16x32_bf16(al8, bh8[n], acc[m][n], 0, 0, 0);
            }
        }
    }
    #pragma unroll
    for (int n = 0; n < 4; ++n) {
        const int col = h * 64 + n * 16 + lr;
        #pragma unroll
        for (int m = 0; m < 2; ++m) {
            #pragma unroll
            for (int j = 0; j < 4; ++j) {
                int t = t0 + w * 32 + m * 16 + lg * 4 + j;
                float v = acc[m][n][j];
                float g = 0.5f * v * (1.0f + erff(v * 0.70710678118654752440f));
                size_t idx = ((size_t)b * SL + t) * ED + col;
                unsigned short hb = bf16bits(g);
                Gh[idx] = hb;
                Gl[idx] = bf16bits(g - bf16val(hb));
            }
        }
    }
}

// K0b: cast W to bf16 hi/lo pair.
__global__ void k0_castW(const float* __restrict__ W,
                         ushort* __restrict__ Wh, ushort* __restrict__ Wl) {
    int i = blockIdx.x * 256 + threadIdx.x;
    if (i < ED * ED) {
        float w = W[i];
        unsigned short hb = bf16bits(w);
        Wh[i] = hb;
        Wl[i] = bf16bits(w - bf16val(hb));
    }
}

// K7: projection GEMM via split-bf16 MFMA; double-buffered 2-phase pipeline + XCD swizzle.
#define K7STAGE(p, kk) do { \
    const ushort* gA_  = Gh + (size_t)(i0 + stRow) * ED + (kk) + stCol; \
    const ushort* gAl_ = Gl + (size_t)(i0 + stRow) * ED + (kk) + stCol; \
    const ushort* gB_  = Wh + (size_t)(j0 + stRow) * ED + (kk) + stCol; \
    const ushort* gBl_ = Wl + (size_t)(j0 + stRow) * ED + (kk) + stCol; \
    __builtin_amdgcn_global_load_lds(GLB_U32(gA_),           LDS_U32(&Ah[p][ldsBase0]), 16, 0, 0); \
    __builtin_amdgcn_global_load_lds(GLB_U32(gA_ + 16 * ED), LDS_U32(&Ah[p][ldsBase1]), 16, 0, 0); \
    __builtin_amdgcn_global_load_lds(GLB_U32(gAl_),          LDS_U32(&Al[p][ldsBase0]), 16, 0, 0); \
    __builtin_amdgcn_global_load_lds(GLB_U32(gAl_ + 16 * ED),LDS_U32(&Al[p][ldsBase1]), 16, 0, 0); \
    __builtin_amdgcn_global_load_lds(GLB_U32(gB_),           LDS_U32(&Bh[p][ldsBase0]), 16, 0, 0); \
    __builtin_amdgcn_global_load_lds(GLB_U32(gB_ + 16 * ED), LDS_U32(&Bh[p][ldsBase1]), 16, 0, 0); \
    __builtin_amdgcn_global_load_lds(GLB_U32(gBl_),          LDS_U32(&Bl[p][ldsBase0]), 16, 0, 0); \
    __builtin_amdgcn_global_load_lds(GLB_U32(gBl_ + 16 * ED),LDS_U32(&Bl[p][ldsBase1]), 16, 0, 0); \
} while (0)

__global__ __launch_bounds__(256) void k7_mfma(
        const ushort* __restrict__ Gh, const ushort* __restrict__ Gl,
        const ushort* __restrict__ Wh, const ushort* __restrict__ Wl,
        const float* __restrict__ bias, float* __restrict__ out) {
    __shared__ ushort Ah[2][128 * 32], Al[2][128 * 32], Bh[2][128 * 32], Bl[2][128 * 32]; // 64 KB
    // XCD swizzle: 384 blocks = 8 XCDs x 48; give each XCD 8 consecutive i-panels (j fastest).
    const int bid = blockIdx.y * gridDim.x + blockIdx.x;
    const int swz = (bid & 7) * 48 + (bid >> 3);
    const int j0 = (swz % 6) * 128;
    const int i0 = (swz / 6) * 128;
    const int tid = threadIdx.x;
    const int lane = tid & 63, wid = tid >> 6;
    const int wm = wid >> 1, wn = wid & 1;

    const int stRow = wid * 32 + (lane >> 2);
    const int stCol = (lane & 3) * 8;
    const int ldsBase0 = wid * 1024;
    const int ldsBase1 = wid * 1024 + 512;

    f32x4 acc[4][4] = {};

    const int arow = wm * 64 + (lane & 15);
    const int brow = wn * 64 + (lane & 15);
    const int kb8  = (lane >> 4) * 8;

    K7STAGE(0, 0);
    asm volatile("s_waitcnt vmcnt(0)" ::: "memory");
    __syncthreads();

    for (int t = 0; t < 24; ++t) {
        const int cur = t & 1;
        if (t < 23) K7STAGE(cur ^ 1, (t + 1) * 32);   // prefetch next tile into other buffer

        bf16x8 ah[4], al[4], bh4[4], bl4[4];
        #pragma unroll
        for (int m = 0; m < 4; ++m) {
            ah[m] = *(const bf16x8*)&Ah[cur][(arow + m * 16) * 32 + kb8];
            al[m] = *(const bf16x8*)&Al[cur][(arow + m * 16) * 32 + kb8];
        }
        #pragma unroll
        for (int n = 0; n < 4; ++n) {
            bh4[n] = *(const bf16x8*)&Bh[cur][(brow + n * 16) * 32 + kb8];
            bl4[n] = *(const bf16x8*)&Bl[cur][(brow + n * 16) * 32 + kb8];
        }
        #pragma unroll
        for (int m = 0; m < 4; ++m)
            #pragma unroll
            for (int n = 0; n < 4; ++n) {
                acc[m][n] = __builtin_amdgcn_mfma_f32_16x16x32_bf16(ah[m], bh4[n], acc[m][n], 0, 0, 0);
                acc[m][n] = __builtin_amdgcn_mfma_f32_16x16x32_bf16(ah[m], bl4[n], acc[m][n], 0, 0, 0);
                acc[m][n] = __builtin_amdgcn_mfma_f32_16x16x32_bf16(al[m], bh4[n], acc[m][n], 0, 0, 0);
            }
        asm volatile("s_waitcnt vmcnt(0)" ::: "memory");  // next tile's stage complete
        __syncthreads();                                   // all reads of cur done; buffers swap
    }

    const int ocol0 = j0 + wn * 64 + (lane & 15);
    const int orow0 = i0 + wm * 64 + (lane >> 4) * 4;
    #pragma unroll
    for (int n = 0; n < 4; ++n) {
        const float bv = bias[ocol0 + n * 16];
        #pragma unroll
        for (int m = 0; m < 4; ++m) {
            #pragma unroll
            for (int j = 0; j < 4; ++j) {
                out[(size_t)(orow0 + m * 16 + j) * ED + ocol0 + n * 16] = acc[m][n][j] + bv;
            }
        }
    }
}

extern "C" void kernel_launch(void* const* d_in, const int* in_sizes, int n_in,
                              void* d_out, int out_size, void* d_ws, size_t ws_size,
                              hipStream_t stream) {
    (void)in_sizes; (void)n_in; (void)out_size; (void)ws_size;
    const float* emb  = (const float*)d_in[0];   // [8,1024,768]
    const float* tp   = (const float*)d_in[1];   // [12,2047,64]
    const float* W    = (const float*)d_in[2];   // [768,768]
    const float* bias = (const float*)d_in[3];   // [768]

    float* out_conv = (float*)d_out;                             // 8*1024*768
    float* out_psf  = out_conv + (size_t)NB * SL * ED;           // 12*2047*64

    // workspace layout:
    float2* Pc = (float2*)d_ws;                                  // 12*33*1024 complex (dead after k3)
    float2* Pf = Pc + (size_t)NH * NF * SL;                      // 12*33*2048 complex
    float*  XcRe = (float*)(Pf + (size_t)NH * NF * NSEQ);        // 96*33*1024 f32
    float*  XcIm = XcRe + (size_t)NB * NH * NF * SL;             // 96*33*1024 f32
    ushort* Gh = (ushort*)(XcIm + (size_t)NB * NH * NF * SL);    // 8192*768 bf16
    ushort* Gl = Gh + (size_t)NB * SL * ED;                      // 8192*768 bf16
    // W hi/lo overlaid on Pc region (2.36 MB <= 3.24 MB), written after k3 consumes Pc
    ushort* Whh = (ushort*)Pc;
    ushort* Wll = Whh + (size_t)ED * ED;
    // twiddle table overlaid on Gh start (4 KB): consumed by k3/k5 before k6 writes Gh
    float2* twg = (float2*)Gh;
    // softmax partials overlaid on Pf start (dead until k3 writes Pf)
    float* pMax = (float*)Pf;          // 12*32*64
    float* pSum = pMax + NH * 32 * 64; // 12*32*64
    float* Mf   = pSum + NH * 32 * 64; // 768
    float* Invf = Mf + NH * 64;        // 768

    ktw<<<dim3(2), dim3(256), 0, stream>>>(twg);
    k1a_partial<<<dim3(32, NH), dim3(256), 0, stream>>>(tp, pMax, pSum);
    k1b_fold<<<dim3(NH), dim3(64), 0, stream>>>(pMax, pSum, Mf, Invf);
    k1c_norm<<<dim3(32, NH), dim3(256), 0, stream>>>(tp, Mf, Invf, out_psf);
    k2_psf_cdft<<<dim3(SL / 64, NH), dim3(256), 0, stream>>>(out_psf, Pc);
    k3_psf_fft<<<dim3(NH * NF), dim3(256), 0, stream>>>(Pc, Pf, twg);
    k0_castW<<<dim3((ED * ED + 255) / 256), dim3(256), 0, stream>>>(W, Whh, Wll);
    k4_mfma<<<dim3(SL / 128, NB * NH), dim3(256), 0, stream>>>(emb, XcRe, XcIm);
    k5_seq_conv<<<dim3(NB * NH * NF), dim3(256), 0, stream>>>(XcRe, XcIm, Pf, twg);
    k6_mfma<<<dim3(SL / 128, NB * NH), dim3(256), 0, stream>>>(XcRe, XcIm, Gh, Gl);
    k7_mfma<<<dim3(ED / 128, (NB * SL) / 128), dim3(256), 0, stream>>>(
        Gh, Gl, Whh, Wll, bias, out_conv);
}

// Round 7
// 161.847 us; speedup vs baseline: 1.1724x; 1.1724x over previous
//
#include <hip/hip_runtime.h>
#include <hip/hip_bf16.h>
#include <math.h>

#define NH 12
#define DH 64
#define SL 1024
#define NB 8
#define ED 768
#define NTAP 2047
#define NF 33
#define NSEQ 2048

typedef __attribute__((ext_vector_type(8))) short bf16x8;
typedef __attribute__((ext_vector_type(4))) float f32x4;

#define GLB_U32(p) ((const __attribute__((address_space(1))) unsigned int*)(p))
#define LDS_U32(p) ((__attribute__((address_space(3))) unsigned int*)(p))

__device__ __forceinline__ float2 cadd(float2 a, float2 b){ return make_float2(a.x+b.x, a.y+b.y); }
__device__ __forceinline__ float2 csub(float2 a, float2 b){ return make_float2(a.x-b.x, a.y-b.y); }
__device__ __forceinline__ float2 cmul(float2 a, float2 b){ return make_float2(a.x*b.x - a.y*b.y, a.x*b.y + a.y*b.x); }

__device__ __forceinline__ unsigned short bf16bits(float f) {
    __hip_bfloat16 hb = __float2bfloat16(f);
    return *reinterpret_cast<unsigned short*>(&hb);
}
__device__ __forceinline__ float bf16val(unsigned short u) {
    __hip_bfloat16 hb = *reinterpret_cast<__hip_bfloat16*>(&u);
    return __bfloat162float(hb);
}
// split two fp32 into packed bf16 hi-pair and lo-pair
__device__ __forceinline__ void split2(float a, float b, unsigned int& hp, unsigned int& lp) {
    unsigned short ha = bf16bits(a), hb = bf16bits(b);
    unsigned short la = bf16bits(a - bf16val(ha)), lb = bf16bits(b - bf16val(hb));
    hp = (unsigned int)ha | ((unsigned int)hb << 16);
    lp = (unsigned int)la | ((unsigned int)lb << 16);
}

// ---------------- Stockham FFT pieces (N=2048 = 8*8*8*4, constant geometry) ----------------
#define FPAD(i) ((i) + ((i) >> 3))

template<int DIR>
__device__ __forceinline__ void dft4v(float2 v[4]) {
    float2 e0 = cadd(v[0], v[2]), e1 = csub(v[0], v[2]);
    float2 o0 = cadd(v[1], v[3]), o1 = csub(v[1], v[3]);
    float2 o1t = (DIR < 0) ? make_float2(o1.y, -o1.x) : make_float2(-o1.y, o1.x);
    v[0] = cadd(e0, o0);
    v[1] = cadd(e1, o1t);
    v[2] = csub(e0, o0);
    v[3] = csub(e1, o1t);
}

template<int DIR>
__device__ __forceinline__ void dft8v(float2 v[8]) {
    const float RS = 0.70710678118654752440f;
    float2 e[4] = { v[0], v[2], v[4], v[6] };
    float2 o[4] = { v[1], v[3], v[5], v[7] };
    dft4v<DIR>(e);
    dft4v<DIR>(o);
    float2 t1 = (DIR < 0) ? make_float2(RS * (o[1].x + o[1].y), RS * (o[1].y - o[1].x))
                          : make_float2(RS * (o[1].x - o[1].y), RS * (o[1].y + o[1].x));
    float2 t2 = (DIR < 0) ? make_float2(o[2].y, -o[2].x) : make_float2(-o[2].y, o[2].x);
    float2 t3 = (DIR < 0) ? make_float2(RS * (o[3].y - o[3].x), RS * (-o[3].x - o[3].y))
                          : make_float2(RS * (-o[3].x - o[3].y), RS * (o[3].x - o[3].y));
    v[0] = cadd(e[0], o[0]); v[4] = csub(e[0], o[0]);
    v[1] = cadd(e[1], t1);   v[5] = csub(e[1], t1);
    v[2] = cadd(e[2], t2);   v[6] = csub(e[2], t2);
    v[3] = cadd(e[3], t3);   v[7] = csub(e[3], t3);
}

template<int DIR, int L, int R>
__device__ __forceinline__ void fft_stage(const float* __restrict__ sr, const float* __restrict__ si,
                                          float* __restrict__ dr, float* __restrict__ di,
                                          const float2* __restrict__ twd, int tid) {
    const int T = 2048 / R;
    #pragma unroll
    for (int jj = 0; jj < T; jj += 256) {
        int j = tid + jj;
        int k = j & (L - 1);
        int blk = j / L;
        float2 v[R];
        #pragma unroll
        for (int r = 0; r < R; ++r) {
            int idx = FPAD(j + T * r);
            v[r] = make_float2(sr[idx], si[idx]);
        }
        if (L > 1) {
            const int c = 2048 / (R * L);
            float2 w1 = twd[c * k];
            if (DIR > 0) w1.y = -w1.y;
            float2 w = w1;
            v[1] = cmul(v[1], w);
            #pragma unroll
            for (int r = 2; r < R; ++r) { w = cmul(w, w1); v[r] = cmul(v[r], w); }
        }
        if (R == 8) dft8v<DIR>(v); else dft4v<DIR>(v);
        int base = blk * (R * L) + k;
        #pragma unroll
        for (int r = 0; r < R; ++r) {
            int idx = FPAD(base + L * r);
            dr[idx] = v[r].x; di[idx] = v[r].y;
        }
    }
}

// ktw: twiddle table W_2048^i, i<512
__global__ void ktw(float2* __restrict__ twg) {
    int i = blockIdx.x * 256 + threadIdx.x;
    if (i < 512) {
        float ang = -6.28318530717958647692f * (float)i / 2048.0f;
        twg[i] = make_float2(cosf(ang), sinf(ang));
    }
}

// ---------------- K1: 3-pass coalesced softmax over taps ----------------
__global__ void k1a_partial(const float* __restrict__ tp, float* __restrict__ pMax, float* __restrict__ pSum) {
    __shared__ float lm[4][64], ls[4][64];
    int c = blockIdx.x, h = blockIdx.y;
    int tid = threadIdx.x, w = tid >> 6, e = tid & 63;
    const float* base = tp + (size_t)h * NTAP * 64;
    float m = -1e30f, s = 0.f;
    #pragma unroll
    for (int i = 0; i < 16; ++i) {
        int row = c * 64 + w + 4 * i;
        if (row < NTAP) {
            float v = base[(size_t)row * 64 + e];
            float mn = fmaxf(m, v);
            s = s * expf(m - mn) + expf(v - mn);
            m = mn;
        }
    }
    lm[w][e] = m; ls[w][e] = s;
    __syncthreads();
    if (w == 0) {
        float M = m, S = s;
        #pragma unroll
        for (int i = 1; i < 4; ++i) {
            float mi = lm[i][e], si = ls[i][e];
            float mn = fmaxf(M, mi);
            S = S * expf(M - mn) + si * expf(mi - mn);
            M = mn;
        }
        pMax[(h * 32 + c) * 64 + e] = M;
        pSum[(h * 32 + c) * 64 + e] = S;
    }
}

__global__ void k1b_fold(const float* __restrict__ pMax, const float* __restrict__ pSum,
                         float* __restrict__ Mf, float* __restrict__ Invf) {
    int h = blockIdx.x, e = threadIdx.x;
    float M = -1e30f, S = 0.f;
    for (int c = 0; c < 32; ++c) {
        float mi = pMax[(h * 32 + c) * 64 + e], si = pSum[(h * 32 + c) * 64 + e];
        float mn = fmaxf(M, mi);
        S = S * expf(M - mn) + si * expf(mi - mn);
        M = mn;
    }
    Mf[h * 64 + e] = M;
    Invf[h * 64 + e] = 1.0f / S;
}

__global__ void k1c_norm(const float* __restrict__ tp, const float* __restrict__ Mf,
                         const float* __restrict__ Invf, float* __restrict__ psf_out) {
    int c = blockIdx.x, h = blockIdx.y;
    int tid = threadIdx.x, w = tid >> 6, e = tid & 63;
    float M = Mf[h * 64 + e], inv = Invf[h * 64 + e];
    const float* base = tp + (size_t)h * NTAP * 64;
    float* ob = psf_out + (size_t)h * NTAP * 64;
    #pragma unroll
    for (int i = 0; i < 16; ++i) {
        int row = c * 64 + w + 4 * i;
        if (row < NTAP) {
            float o = 0.f;
            if (row < SL) o = expf(base[(size_t)row * 64 + e] - M) * inv;
            ob[(size_t)row * 64 + e] = o;
        }
    }
}

// K2m: psf channel DFT-64 as split-bf16 MFMA (same matmul as k4).
// Pc[h][f][s] = sum_e psf[h][s][e] * B[c][e]; Re = row f, Im = row 33+f of D.
__global__ __launch_bounds__(256) void k2_mfma(const float* __restrict__ psf, float2* __restrict__ Pc) {
    __shared__ union {
        struct {
            ushort EH[128][72], EL[128][72];
            ushort CH[80][72],  CL[80][72];
        } s;
        float Dl[66][133];
    } u;
    const int t0 = blockIdx.x * 128;
    const int h = blockIdx.y;
    const int tid = threadIdx.x, lane = tid & 63, w = tid >> 6;

    // stage psf tile [128][64] (rows t0..t0+127 < 1024) -> bf16 hi/lo
    for (int i = tid; i < 128 * 16; i += 256) {
        int r = i >> 4, q = i & 15;
        float4 v = *(const float4*)&psf[((size_t)h * NTAP + t0 + r) * 64 + q * 4];
        unsigned int hp, lp;
        split2(v.x, v.y, hp, lp);
        *(unsigned int*)&u.s.EH[r][q * 4]     = hp;  *(unsigned int*)&u.s.EL[r][q * 4]     = lp;
        split2(v.z, v.w, hp, lp);
        *(unsigned int*)&u.s.EH[r][q * 4 + 2] = hp;  *(unsigned int*)&u.s.EL[r][q * 4 + 2] = lp;
    }
    // stage DFT matrix C[c][e]: c<33 cos, 33..65 -sin, else 0
    for (int i = tid; i < 80 * 32; i += 256) {
        int c = i >> 5, e2 = (i & 31) * 2;
        float v0 = 0.f, v1 = 0.f;
        if (c < 33) {
            v0 = cosf(0.09817477042468103870f * (float)((c * e2) & 63));
            v1 = cosf(0.09817477042468103870f * (float)((c * (e2 + 1)) & 63));
        } else if (c < 66) {
            v0 = -sinf(0.09817477042468103870f * (float)(((c - 33) * e2) & 63));
            v1 = -sinf(0.09817477042468103870f * (float)(((c - 33) * (e2 + 1)) & 63));
        }
        unsigned int hp, lp;
        split2(v0, v1, hp, lp);
        *(unsigned int*)&u.s.CH[c][e2] = hp;  *(unsigned int*)&u.s.CL[c][e2] = lp;
    }
    __syncthreads();

    f32x4 acc[2][5] = {};
    const int lr = lane & 15, lg = lane >> 4;
    #pragma unroll
    for (int ks = 0; ks < 64; ks += 32) {
        const int kg = ks + lg * 8;
        bf16x8 bh8[5], bl8[5];
        #pragma unroll
        for (int n = 0; n < 5; ++n) {
            bh8[n] = *(const bf16x8*)&u.s.CH[n * 16 + lr][kg];
            bl8[n] = *(const bf16x8*)&u.s.CL[n * 16 + lr][kg];
        }
        #pragma unroll
        for (int m = 0; m < 2; ++m) {
            const int row = w * 32 + m * 16 + lr;
            bf16x8 ah8 = *(const bf16x8*)&u.s.EH[row][kg];
            bf16x8 al8 = *(const bf16x8*)&u.s.EL[row][kg];
            #pragma unroll
            for (int n = 0; n < 5; ++n) {
                acc[m][n] = __builtin_amdgcn_mfma_f32_16x16x32_bf16(ah8, bh8[n], acc[m][n], 0, 0, 0);
                acc[m][n] = __builtin_amdgcn_mfma_f32_16x16x32_bf16(ah8, bl8[n], acc[m][n], 0, 0, 0);
                acc[m][n] = __builtin_amdgcn_mfma_f32_16x16x32_bf16(al8, bh8[n], acc[m][n], 0, 0, 0);
            }
        }
    }
    __syncthreads();
    #pragma unroll
    for (int n = 0; n < 5; ++n) {
        int c = n * 16 + lr;
        if (c < 66) {
            #pragma unroll
            for (int m = 0; m < 2; ++m)
                #pragma unroll
                for (int j = 0; j < 4; ++j)
                    u.Dl[c][w * 32 + m * 16 + lg * 4 + j] = acc[m][n][j];
        }
    }
    __syncthreads();
    for (int i = tid; i < 33 * 128; i += 256) {
        int f = i >> 7, t = i & 127;
        Pc[(size_t)(h * NF + f) * SL + t0 + t] = make_float2(u.Dl[f][t], u.Dl[f + 33][t]);
    }
}

// K3: seq FFT-2048 of psf per (h,f), Stockham, natural order out.
__global__ __launch_bounds__(256) void k3_psf_fft(const float2* __restrict__ Pc, float2* __restrict__ Pf,
                                                  const float2* __restrict__ twg) {
    __shared__ float Ar[2304], Ai[2304], Br[2304], Bi[2304];
    __shared__ float2 twd[512];
    int h = blockIdx.x / NF, f = blockIdx.x % NF;
    int tid = threadIdx.x;
    for (int i = tid; i < 512; i += 256) twd[i] = twg[i];
    const float2* src = Pc + (size_t)(h * NF + f) * SL;
    {
        float2 v[8];
        #pragma unroll
        for (int r = 0; r < 4; ++r) v[r] = src[tid + 256 * r];
        #pragma unroll
        for (int r = 4; r < 8; ++r) v[r] = make_float2(0.f, 0.f);
        dft8v<-1>(v);
        #pragma unroll
        for (int r = 0; r < 8; ++r) {
            int idx = FPAD(tid * 8 + r);
            Ar[idx] = v[r].x; Ai[idx] = v[r].y;
        }
    }
    __syncthreads();
    fft_stage<-1, 8, 8>(Ar, Ai, Br, Bi, twd, tid);  __syncthreads();
    fft_stage<-1, 64, 8>(Br, Bi, Ar, Ai, twd, tid); __syncthreads();
    float2* dst = Pf + (size_t)(h * NF + f) * NSEQ;
    #pragma unroll
    for (int jj = 0; jj < 512; jj += 256) {
        int j = tid + jj;
        float2 v[4];
        #pragma unroll
        for (int r = 0; r < 4; ++r) {
            int idx = FPAD(j + 512 * r);
            v[r] = make_float2(Ar[idx], Ai[idx]);
        }
        float2 w1 = twd[j];
        float2 w = w1;
        v[1] = cmul(v[1], w);
        w = cmul(w, w1); v[2] = cmul(v[2], w);
        w = cmul(w, w1); v[3] = cmul(v[3], w);
        dft4v<-1>(v);
        #pragma unroll
        for (int r = 0; r < 4; ++r) dst[j + 512 * r] = v[r];
    }
}

// K4m: channel DFT-64 as split-bf16 MFMA; staging pre-splits to bf16 hi/lo in LDS.
__global__ __launch_bounds__(256) void k4_mfma(const float* __restrict__ emb,
                                               float* __restrict__ XcRe, float* __restrict__ XcIm) {
    __shared__ union {
        struct {
            ushort EH[128][72], EL[128][72];
            ushort CH[80][72],  CL[80][72];
        } s;
        float Dl[66][133];
    } u;
    const int t0 = blockIdx.x * 128;
    const int bh = blockIdx.y;
    const int b = bh / NH, h = bh % NH;
    const int tid = threadIdx.x, lane = tid & 63, w = tid >> 6;

    for (int i = tid; i < 128 * 16; i += 256) {
        int r = i >> 4, q = i & 15;
        float4 v = *(const float4*)&emb[((size_t)b * SL + t0 + r) * ED + h * 64 + q * 4];
        unsigned int hp, lp;
        split2(v.x, v.y, hp, lp);
        *(unsigned int*)&u.s.EH[r][q * 4]     = hp;  *(unsigned int*)&u.s.EL[r][q * 4]     = lp;
        split2(v.z, v.w, hp, lp);
        *(unsigned int*)&u.s.EH[r][q * 4 + 2] = hp;  *(unsigned int*)&u.s.EL[r][q * 4 + 2] = lp;
    }
    for (int i = tid; i < 80 * 32; i += 256) {
        int c = i >> 5, e2 = (i & 31) * 2;
        float v0 = 0.f, v1 = 0.f;
        if (c < 33) {
            v0 = cosf(0.09817477042468103870f * (float)((c * e2) & 63));
            v1 = cosf(0.09817477042468103870f * (float)((c * (e2 + 1)) & 63));
        } else if (c < 66) {
            v0 = -sinf(0.09817477042468103870f * (float)(((c - 33) * e2) & 63));
            v1 = -sinf(0.09817477042468103870f * (float)(((c - 33) * (e2 + 1)) & 63));
        }
        unsigned int hp, lp;
        split2(v0, v1, hp, lp);
        *(unsigned int*)&u.s.CH[c][e2] = hp;  *(unsigned int*)&u.s.CL[c][e2] = lp;
    }
    __syncthreads();

    f32x4 acc[2][5] = {};
    const int lr = lane & 15, lg = lane >> 4;
    #pragma unroll
    for (int ks = 0; ks < 64; ks += 32) {
        const int kg = ks + lg * 8;
        bf16x8 bh8[5], bl8[5];
        #pragma unroll
        for (int n = 0; n < 5; ++n) {
            bh8[n] = *(const bf16x8*)&u.s.CH[n * 16 + lr][kg];
            bl8[n] = *(const bf16x8*)&u.s.CL[n * 16 + lr][kg];
        }
        #pragma unroll
        for (int m = 0; m < 2; ++m) {
            const int row = w * 32 + m * 16 + lr;
            bf16x8 ah8 = *(const bf16x8*)&u.s.EH[row][kg];
            bf16x8 al8 = *(const bf16x8*)&u.s.EL[row][kg];
            #pragma unroll
            for (int n = 0; n < 5; ++n) {
                acc[m][n] = __builtin_amdgcn_mfma_f32_16x16x32_bf16(ah8, bh8[n], acc[m][n], 0, 0, 0);
                acc[m][n] = __builtin_amdgcn_mfma_f32_16x16x32_bf16(ah8, bl8[n], acc[m][n], 0, 0, 0);
                acc[m][n] = __builtin_amdgcn_mfma_f32_16x16x32_bf16(al8, bh8[n], acc[m][n], 0, 0, 0);
            }
        }
    }
    __syncthreads();
    #pragma unroll
    for (int n = 0; n < 5; ++n) {
        int c = n * 16 + lr;
        if (c < 66) {
            #pragma unroll
            for (int m = 0; m < 2; ++m)
                #pragma unroll
                for (int j = 0; j < 4; ++j)
                    u.Dl[c][w * 32 + m * 16 + lg * 4 + j] = acc[m][n][j];
        }
    }
    __syncthreads();
    for (int i = tid; i < 66 * 128; i += 256) {
        int c = i >> 7, t = i & 127;
        float val = u.Dl[c][t];
        if (c < 33) XcRe[(size_t)(bh * NF + c) * SL + t0 + t] = val;
        else        XcIm[(size_t)(bh * NF + (c - 33)) * SL + t0 + t] = val;
    }
}

// K5: Stockham fwd FFT -> pointwise * Pf -> Stockham inv FFT, in-place on Xc planes.
__global__ __launch_bounds__(256) void k5_seq_conv(float* __restrict__ XcRe, float* __restrict__ XcIm,
                                                   const float2* __restrict__ Pf,
                                                   const float2* __restrict__ twg) {
    __shared__ float Ar[2304], Ai[2304], Br[2304], Bi[2304];
    __shared__ float2 twd[512];
    int f = blockIdx.x % NF;
    int bh = blockIdx.x / NF;
    int h = bh % NH;
    int tid = threadIdx.x;
    for (int i = tid; i < 512; i += 256) twd[i] = twg[i];
    float* xre = XcRe + (size_t)(bh * NF + f) * SL;
    float* xim = XcIm + (size_t)(bh * NF + f) * SL;
    {
        float2 v[8];
        #pragma unroll
        for (int r = 0; r < 4; ++r) v[r] = make_float2(xre[tid + 256 * r], xim[tid + 256 * r]);
        #pragma unroll
        for (int r = 4; r < 8; ++r) v[r] = make_float2(0.f, 0.f);
        dft8v<-1>(v);
        #pragma unroll
        for (int r = 0; r < 8; ++r) {
            int idx = FPAD(tid * 8 + r);
            Ar[idx] = v[r].x; Ai[idx] = v[r].y;
        }
    }
    __syncthreads();
    fft_stage<-1, 8, 8>(Ar, Ai, Br, Bi, twd, tid);   __syncthreads();
    fft_stage<-1, 64, 8>(Br, Bi, Ar, Ai, twd, tid);  __syncthreads();
    fft_stage<-1, 512, 4>(Ar, Ai, Br, Bi, twd, tid); __syncthreads();
    const float2* pf = Pf + (size_t)(h * NF + f) * NSEQ;
    #pragma unroll
    for (int q = 0; q < 8; ++q) {
        int i = tid + 256 * q;
        int idx = FPAD(i);
        float2 a = make_float2(Br[idx], Bi[idx]);
        float2 p = cmul(a, pf[i]);
        Br[idx] = p.x; Bi[idx] = p.y;
    }
    __syncthreads();
    fft_stage<1, 1, 8>(Br, Bi, Ar, Ai, twd, tid);  __syncthreads();
    fft_stage<1, 8, 8>(Ar, Ai, Br, Bi, twd, tid);  __syncthreads();
    fft_stage<1, 64, 8>(Br, Bi, Ar, Ai, twd, tid); __syncthreads();
    const float sc = 1.0f / 2048.0f;
    #pragma unroll
    for (int jj = 0; jj < 512; jj += 256) {
        int j = tid + jj;
        float2 v[4];
        #pragma unroll
        for (int r = 0; r < 4; ++r) {
            int idx = FPAD(j + 512 * r);
            v[r] = make_float2(Ar[idx], Ai[idx]);
        }
        float2 w1 = twd[j];
        w1.y = -w1.y;
        float2 w = w1;
        v[1] = cmul(v[1], w);
        w = cmul(w, w1); v[2] = cmul(v[2], w);
        w = cmul(w, w1); v[3] = cmul(v[3], w);
        dft4v<1>(v);
        xre[j] = v[0].x * sc;        xim[j] = v[0].y * sc;
        xre[j + 512] = v[1].x * sc;  xim[j + 512] = v[1].y * sc;
    }
}

// K6m: inverse channel DFT-64 as split-bf16 MFMA + exact GELU.
__global__ __launch_bounds__(256) void k6_mfma(const float* __restrict__ XcRe,
                                               const float* __restrict__ XcIm,
                                               ushort* __restrict__ Gh, ushort* __restrict__ Gl) {
    __shared__ union {
        float Y32[64][133];
        struct { ushort CH[64][72], CL[64][72]; } c;
    } uy;
    __shared__ ushort YH[128][72], YL[128][72];
    const int t0 = blockIdx.x * 128;
    const int bh = blockIdx.y;
    const int b = bh / NH, h = bh % NH;
    const int tid = threadIdx.x, lane = tid & 63, w = tid >> 6;

    for (int i = tid; i < 64 * 32; i += 256) {
        int c = i >> 5, tq = i & 31;
        const float* src = (c < 33) ? XcRe + (size_t)(bh * NF + c) * SL
                                    : XcIm + (size_t)(bh * NF + (c - 32)) * SL;
        float4 v = *(const float4*)&src[t0 + tq * 4];
        uy.Y32[c][tq * 4 + 0] = v.x; uy.Y32[c][tq * 4 + 1] = v.y;
        uy.Y32[c][tq * 4 + 2] = v.z; uy.Y32[c][tq * 4 + 3] = v.w;
    }
    __syncthreads();
    for (int i = tid; i < 128 * 8; i += 256) {
        int t = i & 127, c0 = (i >> 7) * 8;
        float v[8];
        #pragma unroll
        for (int j = 0; j < 8; ++j) v[j] = uy.Y32[c0 + j][t];
        unsigned int hp, lp;
        #pragma unroll
        for (int j = 0; j < 8; j += 2) {
            split2(v[j], v[j + 1], hp, lp);
            *(unsigned int*)&YH[t][c0 + j] = hp;
            *(unsigned int*)&YL[t][c0 + j] = lp;
        }
    }
    __syncthreads();
    for (int i = tid; i < 64 * 32; i += 256) {
        int e = i >> 5, c2 = (i & 31) * 2;
        float v[2];
        #pragma unroll
        for (int j = 0; j < 2; ++j) {
            int c = c2 + j;
            if (c <= 32) {
                float wt = (c == 0 || c == 32) ? (1.0f / 64.0f) : (2.0f / 64.0f);
                v[j] = wt * cosf(0.09817477042468103870f * (float)((c * e) & 63));
            } else {
                v[j] = -(2.0f / 64.0f) * sinf(0.09817477042468103870f * (float)(((c - 32) * e) & 63));
            }
        }
        unsigned int hp, lp;
        split2(v[0], v[1], hp, lp);
        *(unsigned int*)&uy.c.CH[e][c2] = hp;
        *(unsigned int*)&uy.c.CL[e][c2] = lp;
    }
    __syncthreads();

    f32x4 acc[2][4] = {};
    const int lr = lane & 15, lg = lane >> 4;
    #pragma unroll
    for (int ks = 0; ks < 64; ks += 32) {
        const int kg = ks + lg * 8;
        bf16x8 bh8[4], bl8[4];
        #pragma unroll
        for (int n = 0; n < 4; ++n) {
            bh8[n] = *(const bf16x8*)&uy.c.CH[n * 16 + lr][kg];
            bl8[n] = *(const bf16x8*)&uy.c.CL[n * 16 + lr][kg];
        }
        #pragma unroll
        for (int m = 0; m < 2; ++m) {
            const int row = w * 32 + m * 16 + lr;
            bf16x8 ah8 = *(const bf16x8*)&YH[row][kg];
            bf16x8 al8 = *(const bf16x8*)&YL[row][kg];
            #pragma unroll
            for (int n = 0; n < 4; ++n) {
                acc[m][n] = __builtin_amdgcn_mfma_f32_16x16x32_bf16(ah8, bh8[n], acc[m][n], 0, 0, 0);
                acc[m][n] = __builtin_amdgcn_mfma_f32_16x16x32_bf16(ah8, bl8[n], acc[m][n], 0, 0, 0);
                acc[m][n] = __builtin_amdgcn_mfma_f32_16x16x32_bf16(al8, bh8[n], acc[m][n], 0, 0, 0);
            }
        }
    }
    #pragma unroll
    for (int n = 0; n < 4; ++n) {
        const int col = h * 64 + n * 16 + lr;
        #pragma unroll
        for (int m = 0; m < 2; ++m) {
            #pragma unroll
            for (int j = 0; j < 4; ++j) {
                int t = t0 + w * 32 + m * 16 + lg * 4 + j;
                float v = acc[m][n][j];
                float g = 0.5f * v * (1.0f + erff(v * 0.70710678118654752440f));
                size_t idx = ((size_t)b * SL + t) * ED + col;
                unsigned short hb = bf16bits(g);
                Gh[idx] = hb;
                Gl[idx] = bf16bits(g - bf16val(hb));
            }
        }
    }
}

// K0b: cast W to bf16 hi/lo pair.
__global__ void k0_castW(const float* __restrict__ W,
                         ushort* __restrict__ Wh, ushort* __restrict__ Wl) {
    int i = blockIdx.x * 256 + threadIdx.x;
    if (i < ED * ED) {
        float w = W[i];
        unsigned short hb = bf16bits(w);
        Wh[i] = hb;
        Wl[i] = bf16bits(w - bf16val(hb));
    }
}

// K7: projection GEMM via split-bf16 MFMA; double-buffered 2-phase pipeline + XCD swizzle.
#define K7STAGE(p, kk) do { \
    const ushort* gA_  = Gh + (size_t)(i0 + stRow) * ED + (kk) + stCol; \
    const ushort* gAl_ = Gl + (size_t)(i0 + stRow) * ED + (kk) + stCol; \
    const ushort* gB_  = Wh + (size_t)(j0 + stRow) * ED + (kk) + stCol; \
    const ushort* gBl_ = Wl + (size_t)(j0 + stRow) * ED + (kk) + stCol; \
    __builtin_amdgcn_global_load_lds(GLB_U32(gA_),           LDS_U32(&Ah[p][ldsBase0]), 16, 0, 0); \
    __builtin_amdgcn_global_load_lds(GLB_U32(gA_ + 16 * ED), LDS_U32(&Ah[p][ldsBase1]), 16, 0, 0); \
    __builtin_amdgcn_global_load_lds(GLB_U32(gAl_),          LDS_U32(&Al[p][ldsBase0]), 16, 0, 0); \
    __builtin_amdgcn_global_load_lds(GLB_U32(gAl_ + 16 * ED),LDS_U32(&Al[p][ldsBase1]), 16, 0, 0); \
    __builtin_amdgcn_global_load_lds(GLB_U32(gB_),           LDS_U32(&Bh[p][ldsBase0]), 16, 0, 0); \
    __builtin_amdgcn_global_load_lds(GLB_U32(gB_ + 16 * ED), LDS_U32(&Bh[p][ldsBase1]), 16, 0, 0); \
    __builtin_amdgcn_global_load_lds(GLB_U32(gBl_),          LDS_U32(&Bl[p][ldsBase0]), 16, 0, 0); \
    __builtin_amdgcn_global_load_lds(GLB_U32(gBl_ + 16 * ED),LDS_U32(&Bl[p][ldsBase1]), 16, 0, 0); \
} while (0)

__global__ __launch_bounds__(256) void k7_mfma(
        const ushort* __restrict__ Gh, const ushort* __restrict__ Gl,
        const ushort* __restrict__ Wh, const ushort* __restrict__ Wl,
        const float* __restrict__ bias, float* __restrict__ out) {
    __shared__ ushort Ah[2][128 * 32], Al[2][128 * 32], Bh[2][128 * 32], Bl[2][128 * 32]; // 64 KB
    const int bid = blockIdx.y * gridDim.x + blockIdx.x;
    const int swz = (bid & 7) * 48 + (bid >> 3);
    const int j0 = (swz % 6) * 128;
    const int i0 = (swz / 6) * 128;
    const int tid = threadIdx.x;
    const int lane = tid & 63, wid = tid >> 6;
    const int wm = wid >> 1, wn = wid & 1;

    const int stRow = wid * 32 + (lane >> 2);
    const int stCol = (lane & 3) * 8;
    const int ldsBase0 = wid * 1024;
    const int ldsBase1 = wid * 1024 + 512;

    f32x4 acc[4][4] = {};

    const int arow = wm * 64 + (lane & 15);
    const int brow = wn * 64 + (lane & 15);
    const int kb8  = (lane >> 4) * 8;

    K7STAGE(0, 0);
    asm volatile("s_waitcnt vmcnt(0)" ::: "memory");
    __syncthreads();

    for (int t = 0; t < 24; ++t) {
        const int cur = t & 1;
        if (t < 23) K7STAGE(cur ^ 1, (t + 1) * 32);

        bf16x8 ah[4], al[4], bh4[4], bl4[4];
        #pragma unroll
        for (int m = 0; m < 4; ++m) {
            ah[m] = *(const bf16x8*)&Ah[cur][(arow + m * 16) * 32 + kb8];
            al[m] = *(const bf16x8*)&Al[cur][(arow + m * 16) * 32 + kb8];
        }
        #pragma unroll
        for (int n = 0; n < 4; ++n) {
            bh4[n] = *(const bf16x8*)&Bh[cur][(brow + n * 16) * 32 + kb8];
            bl4[n] = *(const bf16x8*)&Bl[cur][(brow + n * 16) * 32 + kb8];
        }
        #pragma unroll
        for (int m = 0; m < 4; ++m)
            #pragma unroll
            for (int n = 0; n < 4; ++n) {
                acc[m][n] = __builtin_amdgcn_mfma_f32_16x16x32_bf16(ah[m], bh4[n], acc[m][n], 0, 0, 0);
                acc[m][n] = __builtin_amdgcn_mfma_f32_16x16x32_bf16(ah[m], bl4[n], acc[m][n], 0, 0, 0);
                acc[m][n] = __builtin_amdgcn_mfma_f32_16x16x32_bf16(al[m], bh4[n], acc[m][n], 0, 0, 0);
            }
        asm volatile("s_waitcnt vmcnt(0)" ::: "memory");
        __syncthreads();
    }

    const int ocol0 = j0 + wn * 64 + (lane & 15);
    const int orow0 = i0 + wm * 64 + (lane >> 4) * 4;
    #pragma unroll
    for (int n = 0; n < 4; ++n) {
        const float bv = bias[ocol0 + n * 16];
        #pragma unroll
        for (int m = 0; m < 4; ++m) {
            #pragma unroll
            for (int j = 0; j < 4; ++j) {
                out[(size_t)(orow0 + m * 16 + j) * ED + ocol0 + n * 16] = acc[m][n][j] + bv;
            }
        }
    }
}

extern "C" void kernel_launch(void* const* d_in, const int* in_sizes, int n_in,
                              void* d_out, int out_size, void* d_ws, size_t ws_size,
                              hipStream_t stream) {
    (void)in_sizes; (void)n_in; (void)out_size; (void)ws_size;
    const float* emb  = (const float*)d_in[0];   // [8,1024,768]
    const float* tp   = (const float*)d_in[1];   // [12,2047,64]
    const float* W    = (const float*)d_in[2];   // [768,768]
    const float* bias = (const float*)d_in[3];   // [768]

    float* out_conv = (float*)d_out;                             // 8*1024*768
    float* out_psf  = out_conv + (size_t)NB * SL * ED;           // 12*2047*64

    // workspace layout:
    float2* Pc = (float2*)d_ws;                                  // 12*33*1024 complex (dead after k3)
    float2* Pf = Pc + (size_t)NH * NF * SL;                      // 12*33*2048 complex
    float*  XcRe = (float*)(Pf + (size_t)NH * NF * NSEQ);        // 96*33*1024 f32
    float*  XcIm = XcRe + (size_t)NB * NH * NF * SL;             // 96*33*1024 f32
    ushort* Gh = (ushort*)(XcIm + (size_t)NB * NH * NF * SL);    // 8192*768 bf16
    ushort* Gl = Gh + (size_t)NB * SL * ED;                      // 8192*768 bf16
    // W hi/lo overlaid on Pc region (2.36 MB <= 3.24 MB), written after k3 consumes Pc
    ushort* Whh = (ushort*)Pc;
    ushort* Wll = Whh + (size_t)ED * ED;
    // twiddle table overlaid on Gh start (4 KB): consumed by k3/k5 before k6 writes Gh
    float2* twg = (float2*)Gh;
    // softmax partials overlaid on Pf start (dead until k3 writes Pf)
    float* pMax = (float*)Pf;          // 12*32*64
    float* pSum = pMax + NH * 32 * 64; // 12*32*64
    float* Mf   = pSum + NH * 32 * 64; // 768
    float* Invf = Mf + NH * 64;        // 768

    ktw<<<dim3(2), dim3(256), 0, stream>>>(twg);
    k1a_partial<<<dim3(32, NH), dim3(256), 0, stream>>>(tp, pMax, pSum);
    k1b_fold<<<dim3(NH), dim3(64), 0, stream>>>(pMax, pSum, Mf, Invf);
    k1c_norm<<<dim3(32, NH), dim3(256), 0, stream>>>(tp, Mf, Invf, out_psf);
    k2_mfma<<<dim3(SL / 128, NH), dim3(256), 0, stream>>>(out_psf, Pc);
    k3_psf_fft<<<dim3(NH * NF), dim3(256), 0, stream>>>(Pc, Pf, twg);
    k0_castW<<<dim3((ED * ED + 255) / 256), dim3(256), 0, stream>>>(W, Whh, Wll);
    k4_mfma<<<dim3(SL / 128, NB * NH), dim3(256), 0, stream>>>(emb, XcRe, XcIm);
    k5_seq_conv<<<dim3(NB * NH * NF), dim3(256), 0, stream>>>(XcRe, XcIm, Pf, twg);
    k6_mfma<<<dim3(SL / 128, NB * NH), dim3(256), 0, stream>>>(XcRe, XcIm, Gh, Gl);
    k7_mfma<<<dim3(ED / 128, (NB * SL) / 128), dim3(256), 0, stream>>>(
        Gh, Gl, Whh, Wll, bias, out_conv);
}

// Round 8
// 156.004 us; speedup vs baseline: 1.2164x; 1.0375x over previous
//
#include <hip/hip_runtime.h>
#include <hip/hip_bf16.h>
#include <math.h>

#define NH 12
#define DH 64
#define SL 1024
#define NB 8
#define ED 768
#define NTAP 2047
#define NF 33
#define NSEQ 2048

typedef __attribute__((ext_vector_type(8))) short bf16x8;
typedef __attribute__((ext_vector_type(4))) float f32x4;

#define GLB_U32(p) ((const __attribute__((address_space(1))) unsigned int*)(p))
#define LDS_U32(p) ((__attribute__((address_space(3))) unsigned int*)(p))

__device__ __forceinline__ float2 cadd(float2 a, float2 b){ return make_float2(a.x+b.x, a.y+b.y); }
__device__ __forceinline__ float2 csub(float2 a, float2 b){ return make_float2(a.x-b.x, a.y-b.y); }
__device__ __forceinline__ float2 cmul(float2 a, float2 b){ return make_float2(a.x*b.x - a.y*b.y, a.x*b.y + a.y*b.x); }

__device__ __forceinline__ unsigned short bf16bits(float f) {
    __hip_bfloat16 hb = __float2bfloat16(f);
    return *reinterpret_cast<unsigned short*>(&hb);
}
__device__ __forceinline__ float bf16val(unsigned short u) {
    __hip_bfloat16 hb = *reinterpret_cast<__hip_bfloat16*>(&u);
    return __bfloat162float(hb);
}
// split two fp32 into packed bf16 hi-pair and lo-pair
__device__ __forceinline__ void split2(float a, float b, unsigned int& hp, unsigned int& lp) {
    unsigned short ha = bf16bits(a), hb = bf16bits(b);
    unsigned short la = bf16bits(a - bf16val(ha)), lb = bf16bits(b - bf16val(hb));
    hp = (unsigned int)ha | ((unsigned int)hb << 16);
    lp = (unsigned int)la | ((unsigned int)lb << 16);
}

// ---------------- Stockham FFT pieces (N=2048 = 8*8*8*4, constant geometry) ----------------
#define FPAD(i) ((i) + ((i) >> 3))

template<int DIR>
__device__ __forceinline__ void dft4v(float2 v[4]) {
    float2 e0 = cadd(v[0], v[2]), e1 = csub(v[0], v[2]);
    float2 o0 = cadd(v[1], v[3]), o1 = csub(v[1], v[3]);
    float2 o1t = (DIR < 0) ? make_float2(o1.y, -o1.x) : make_float2(-o1.y, o1.x);
    v[0] = cadd(e0, o0);
    v[1] = cadd(e1, o1t);
    v[2] = csub(e0, o0);
    v[3] = csub(e1, o1t);
}

template<int DIR>
__device__ __forceinline__ void dft8v(float2 v[8]) {
    const float RS = 0.70710678118654752440f;
    float2 e[4] = { v[0], v[2], v[4], v[6] };
    float2 o[4] = { v[1], v[3], v[5], v[7] };
    dft4v<DIR>(e);
    dft4v<DIR>(o);
    float2 t1 = (DIR < 0) ? make_float2(RS * (o[1].x + o[1].y), RS * (o[1].y - o[1].x))
                          : make_float2(RS * (o[1].x - o[1].y), RS * (o[1].y + o[1].x));
    float2 t2 = (DIR < 0) ? make_float2(o[2].y, -o[2].x) : make_float2(-o[2].y, o[2].x);
    float2 t3 = (DIR < 0) ? make_float2(RS * (o[3].y - o[3].x), RS * (-o[3].x - o[3].y))
                          : make_float2(RS * (-o[3].x - o[3].y), RS * (o[3].x - o[3].y));
    v[0] = cadd(e[0], o[0]); v[4] = csub(e[0], o[0]);
    v[1] = cadd(e[1], t1);   v[5] = csub(e[1], t1);
    v[2] = cadd(e[2], t2);   v[6] = csub(e[2], t2);
    v[3] = cadd(e[3], t3);   v[7] = csub(e[3], t3);
}

template<int DIR, int L, int R>
__device__ __forceinline__ void fft_stage(const float* __restrict__ sr, const float* __restrict__ si,
                                          float* __restrict__ dr, float* __restrict__ di,
                                          const float2* __restrict__ twd, int tid) {
    const int T = 2048 / R;
    #pragma unroll
    for (int jj = 0; jj < T; jj += 256) {
        int j = tid + jj;
        int k = j & (L - 1);
        int blk = j / L;
        float2 v[R];
        #pragma unroll
        for (int r = 0; r < R; ++r) {
            int idx = FPAD(j + T * r);
            v[r] = make_float2(sr[idx], si[idx]);
        }
        if (L > 1) {
            const int c = 2048 / (R * L);
            float2 w1 = twd[c * k];
            if (DIR > 0) w1.y = -w1.y;
            float2 w = w1;
            v[1] = cmul(v[1], w);
            #pragma unroll
            for (int r = 2; r < R; ++r) { w = cmul(w, w1); v[r] = cmul(v[r], w); }
        }
        if (R == 8) dft8v<DIR>(v); else dft4v<DIR>(v);
        int base = blk * (R * L) + k;
        #pragma unroll
        for (int r = 0; r < R; ++r) {
            int idx = FPAD(base + L * r);
            dr[idx] = v[r].x; di[idx] = v[r].y;
        }
    }
}

// compute twiddle LUT W_2048^i (i<512) into LDS
__device__ __forceinline__ void gen_twd(float2* twd, int tid) {
    for (int i = tid; i < 512; i += 256) {
        float ang = -6.28318530717958647692f * (float)i / 2048.0f;
        twd[i] = make_float2(cosf(ang), sinf(ang));
    }
}

// ---------------- K1: 3-pass coalesced softmax over taps ----------------
__global__ void k1a_partial(const float* __restrict__ tp, float* __restrict__ pMax, float* __restrict__ pSum) {
    __shared__ float lm[4][64], ls[4][64];
    int c = blockIdx.x, h = blockIdx.y;
    int tid = threadIdx.x, w = tid >> 6, e = tid & 63;
    const float* base = tp + (size_t)h * NTAP * 64;
    float m = -1e30f, s = 0.f;
    #pragma unroll
    for (int i = 0; i < 16; ++i) {
        int row = c * 64 + w + 4 * i;
        if (row < NTAP) {
            float v = base[(size_t)row * 64 + e];
            float mn = fmaxf(m, v);
            s = s * expf(m - mn) + expf(v - mn);
            m = mn;
        }
    }
    lm[w][e] = m; ls[w][e] = s;
    __syncthreads();
    if (w == 0) {
        float M = m, S = s;
        #pragma unroll
        for (int i = 1; i < 4; ++i) {
            float mi = lm[i][e], si = ls[i][e];
            float mn = fmaxf(M, mi);
            S = S * expf(M - mn) + si * expf(mi - mn);
            M = mn;
        }
        pMax[(h * 32 + c) * 64 + e] = M;
        pSum[(h * 32 + c) * 64 + e] = S;
    }
}

__global__ void k1b_fold(const float* __restrict__ pMax, const float* __restrict__ pSum,
                         float* __restrict__ Mf, float* __restrict__ Invf) {
    int h = blockIdx.x, e = threadIdx.x;
    float M = -1e30f, S = 0.f;
    for (int c = 0; c < 32; ++c) {
        float mi = pMax[(h * 32 + c) * 64 + e], si = pSum[(h * 32 + c) * 64 + e];
        float mn = fmaxf(M, mi);
        S = S * expf(M - mn) + si * expf(mi - mn);
        M = mn;
    }
    Mf[h * 64 + e] = M;
    Invf[h * 64 + e] = 1.0f / S;
}

__global__ void k1c_norm(const float* __restrict__ tp, const float* __restrict__ Mf,
                         const float* __restrict__ Invf, float* __restrict__ psf_out) {
    int c = blockIdx.x, h = blockIdx.y;
    int tid = threadIdx.x, w = tid >> 6, e = tid & 63;
    float M = Mf[h * 64 + e], inv = Invf[h * 64 + e];
    const float* base = tp + (size_t)h * NTAP * 64;
    float* ob = psf_out + (size_t)h * NTAP * 64;
    #pragma unroll
    for (int i = 0; i < 16; ++i) {
        int row = c * 64 + w + 4 * i;
        if (row < NTAP) {
            float o = 0.f;
            if (row < SL) o = expf(base[(size_t)row * 64 + e] - M) * inv;
            ob[(size_t)row * 64 + e] = o;
        }
    }
}

// K2m: psf channel DFT-64 as split-bf16 MFMA.
__global__ __launch_bounds__(256) void k2_mfma(const float* __restrict__ psf, float2* __restrict__ Pc) {
    __shared__ union {
        struct {
            ushort EH[128][72], EL[128][72];
            ushort CH[80][72],  CL[80][72];
        } s;
        float Dl[66][133];
    } u;
    const int t0 = blockIdx.x * 128;
    const int h = blockIdx.y;
    const int tid = threadIdx.x, lane = tid & 63, w = tid >> 6;

    for (int i = tid; i < 128 * 16; i += 256) {
        int r = i >> 4, q = i & 15;
        float4 v = *(const float4*)&psf[((size_t)h * NTAP + t0 + r) * 64 + q * 4];
        unsigned int hp, lp;
        split2(v.x, v.y, hp, lp);
        *(unsigned int*)&u.s.EH[r][q * 4]     = hp;  *(unsigned int*)&u.s.EL[r][q * 4]     = lp;
        split2(v.z, v.w, hp, lp);
        *(unsigned int*)&u.s.EH[r][q * 4 + 2] = hp;  *(unsigned int*)&u.s.EL[r][q * 4 + 2] = lp;
    }
    for (int i = tid; i < 80 * 32; i += 256) {
        int c = i >> 5, e2 = (i & 31) * 2;
        float v0 = 0.f, v1 = 0.f;
        if (c < 33) {
            v0 = cosf(0.09817477042468103870f * (float)((c * e2) & 63));
            v1 = cosf(0.09817477042468103870f * (float)((c * (e2 + 1)) & 63));
        } else if (c < 66) {
            v0 = -sinf(0.09817477042468103870f * (float)(((c - 33) * e2) & 63));
            v1 = -sinf(0.09817477042468103870f * (float)(((c - 33) * (e2 + 1)) & 63));
        }
        unsigned int hp, lp;
        split2(v0, v1, hp, lp);
        *(unsigned int*)&u.s.CH[c][e2] = hp;  *(unsigned int*)&u.s.CL[c][e2] = lp;
    }
    __syncthreads();

    f32x4 acc[2][5] = {};
    const int lr = lane & 15, lg = lane >> 4;
    #pragma unroll
    for (int ks = 0; ks < 64; ks += 32) {
        const int kg = ks + lg * 8;
        bf16x8 bh8[5], bl8[5];
        #pragma unroll
        for (int n = 0; n < 5; ++n) {
            bh8[n] = *(const bf16x8*)&u.s.CH[n * 16 + lr][kg];
            bl8[n] = *(const bf16x8*)&u.s.CL[n * 16 + lr][kg];
        }
        #pragma unroll
        for (int m = 0; m < 2; ++m) {
            const int row = w * 32 + m * 16 + lr;
            bf16x8 ah8 = *(const bf16x8*)&u.s.EH[row][kg];
            bf16x8 al8 = *(const bf16x8*)&u.s.EL[row][kg];
            #pragma unroll
            for (int n = 0; n < 5; ++n) {
                acc[m][n] = __builtin_amdgcn_mfma_f32_16x16x32_bf16(ah8, bh8[n], acc[m][n], 0, 0, 0);
                acc[m][n] = __builtin_amdgcn_mfma_f32_16x16x32_bf16(ah8, bl8[n], acc[m][n], 0, 0, 0);
                acc[m][n] = __builtin_amdgcn_mfma_f32_16x16x32_bf16(al8, bh8[n], acc[m][n], 0, 0, 0);
            }
        }
    }
    __syncthreads();
    #pragma unroll
    for (int n = 0; n < 5; ++n) {
        int c = n * 16 + lr;
        if (c < 66) {
            #pragma unroll
            for (int m = 0; m < 2; ++m)
                #pragma unroll
                for (int j = 0; j < 4; ++j)
                    u.Dl[c][w * 32 + m * 16 + lg * 4 + j] = acc[m][n][j];
        }
    }
    __syncthreads();
    for (int i = tid; i < 33 * 128; i += 256) {
        int f = i >> 7, t = i & 127;
        Pc[(size_t)(h * NF + f) * SL + t0 + t] = make_float2(u.Dl[f][t], u.Dl[f + 33][t]);
    }
}

// K3: seq FFT-2048 of psf per (h,f), Stockham, natural order out.
__global__ __launch_bounds__(256) void k3_psf_fft(const float2* __restrict__ Pc, float2* __restrict__ Pf) {
    __shared__ float Ar[2304], Ai[2304], Br[2304], Bi[2304];
    __shared__ float2 twd[512];
    int h = blockIdx.x / NF, f = blockIdx.x % NF;
    int tid = threadIdx.x;
    gen_twd(twd, tid);
    const float2* src = Pc + (size_t)(h * NF + f) * SL;
    {
        float2 v[8];
        #pragma unroll
        for (int r = 0; r < 4; ++r) v[r] = src[tid + 256 * r];
        #pragma unroll
        for (int r = 4; r < 8; ++r) v[r] = make_float2(0.f, 0.f);
        dft8v<-1>(v);
        #pragma unroll
        for (int r = 0; r < 8; ++r) {
            int idx = FPAD(tid * 8 + r);
            Ar[idx] = v[r].x; Ai[idx] = v[r].y;
        }
    }
    __syncthreads();
    fft_stage<-1, 8, 8>(Ar, Ai, Br, Bi, twd, tid);  __syncthreads();
    fft_stage<-1, 64, 8>(Br, Bi, Ar, Ai, twd, tid); __syncthreads();
    float2* dst = Pf + (size_t)(h * NF + f) * NSEQ;
    #pragma unroll
    for (int jj = 0; jj < 512; jj += 256) {
        int j = tid + jj;
        float2 v[4];
        #pragma unroll
        for (int r = 0; r < 4; ++r) {
            int idx = FPAD(j + 512 * r);
            v[r] = make_float2(Ar[idx], Ai[idx]);
        }
        float2 w1 = twd[j];
        float2 w = w1;
        v[1] = cmul(v[1], w);
        w = cmul(w, w1); v[2] = cmul(v[2], w);
        w = cmul(w, w1); v[3] = cmul(v[3], w);
        dft4v<-1>(v);
        #pragma unroll
        for (int r = 0; r < 4; ++r) dst[j + 512 * r] = v[r];
    }
}

// K4m: channel DFT-64 as split-bf16 MFMA; staging pre-splits to bf16 hi/lo in LDS.
__global__ __launch_bounds__(256) void k4_mfma(const float* __restrict__ emb,
                                               float* __restrict__ XcRe, float* __restrict__ XcIm) {
    __shared__ union {
        struct {
            ushort EH[128][72], EL[128][72];
            ushort CH[80][72],  CL[80][72];
        } s;
        float Dl[66][133];
    } u;
    const int t0 = blockIdx.x * 128;
    const int bh = blockIdx.y;
    const int b = bh / NH, h = bh % NH;
    const int tid = threadIdx.x, lane = tid & 63, w = tid >> 6;

    for (int i = tid; i < 128 * 16; i += 256) {
        int r = i >> 4, q = i & 15;
        float4 v = *(const float4*)&emb[((size_t)b * SL + t0 + r) * ED + h * 64 + q * 4];
        unsigned int hp, lp;
        split2(v.x, v.y, hp, lp);
        *(unsigned int*)&u.s.EH[r][q * 4]     = hp;  *(unsigned int*)&u.s.EL[r][q * 4]     = lp;
        split2(v.z, v.w, hp, lp);
        *(unsigned int*)&u.s.EH[r][q * 4 + 2] = hp;  *(unsigned int*)&u.s.EL[r][q * 4 + 2] = lp;
    }
    for (int i = tid; i < 80 * 32; i += 256) {
        int c = i >> 5, e2 = (i & 31) * 2;
        float v0 = 0.f, v1 = 0.f;
        if (c < 33) {
            v0 = cosf(0.09817477042468103870f * (float)((c * e2) & 63));
            v1 = cosf(0.09817477042468103870f * (float)((c * (e2 + 1)) & 63));
        } else if (c < 66) {
            v0 = -sinf(0.09817477042468103870f * (float)(((c - 33) * e2) & 63));
            v1 = -sinf(0.09817477042468103870f * (float)(((c - 33) * (e2 + 1)) & 63));
        }
        unsigned int hp, lp;
        split2(v0, v1, hp, lp);
        *(unsigned int*)&u.s.CH[c][e2] = hp;  *(unsigned int*)&u.s.CL[c][e2] = lp;
    }
    __syncthreads();

    f32x4 acc[2][5] = {};
    const int lr = lane & 15, lg = lane >> 4;
    #pragma unroll
    for (int ks = 0; ks < 64; ks += 32) {
        const int kg = ks + lg * 8;
        bf16x8 bh8[5], bl8[5];
        #pragma unroll
        for (int n = 0; n < 5; ++n) {
            bh8[n] = *(const bf16x8*)&u.s.CH[n * 16 + lr][kg];
            bl8[n] = *(const bf16x8*)&u.s.CL[n * 16 + lr][kg];
        }
        #pragma unroll
        for (int m = 0; m < 2; ++m) {
            const int row = w * 32 + m * 16 + lr;
            bf16x8 ah8 = *(const bf16x8*)&u.s.EH[row][kg];
            bf16x8 al8 = *(const bf16x8*)&u.s.EL[row][kg];
            #pragma unroll
            for (int n = 0; n < 5; ++n) {
                acc[m][n] = __builtin_amdgcn_mfma_f32_16x16x32_bf16(ah8, bh8[n], acc[m][n], 0, 0, 0);
                acc[m][n] = __builtin_amdgcn_mfma_f32_16x16x32_bf16(ah8, bl8[n], acc[m][n], 0, 0, 0);
                acc[m][n] = __builtin_amdgcn_mfma_f32_16x16x32_bf16(al8, bh8[n], acc[m][n], 0, 0, 0);
            }
        }
    }
    __syncthreads();
    #pragma unroll
    for (int n = 0; n < 5; ++n) {
        int c = n * 16 + lr;
        if (c < 66) {
            #pragma unroll
            for (int m = 0; m < 2; ++m)
                #pragma unroll
                for (int j = 0; j < 4; ++j)
                    u.Dl[c][w * 32 + m * 16 + lg * 4 + j] = acc[m][n][j];
        }
    }
    __syncthreads();
    for (int i = tid; i < 66 * 128; i += 256) {
        int c = i >> 7, t = i & 127;
        float val = u.Dl[c][t];
        if (c < 33) XcRe[(size_t)(bh * NF + c) * SL + t0 + t] = val;
        else        XcIm[(size_t)(bh * NF + (c - 33)) * SL + t0 + t] = val;
    }
}

// K5: Stockham fwd FFT -> pointwise * Pf -> Stockham inv FFT, in-place on Xc planes.
__global__ __launch_bounds__(256) void k5_seq_conv(float* __restrict__ XcRe, float* __restrict__ XcIm,
                                                   const float2* __restrict__ Pf) {
    __shared__ float Ar[2304], Ai[2304], Br[2304], Bi[2304];
    __shared__ float2 twd[512];
    int f = blockIdx.x % NF;
    int bh = blockIdx.x / NF;
    int h = bh % NH;
    int tid = threadIdx.x;
    gen_twd(twd, tid);
    float* xre = XcRe + (size_t)(bh * NF + f) * SL;
    float* xim = XcIm + (size_t)(bh * NF + f) * SL;
    {
        float2 v[8];
        #pragma unroll
        for (int r = 0; r < 4; ++r) v[r] = make_float2(xre[tid + 256 * r], xim[tid + 256 * r]);
        #pragma unroll
        for (int r = 4; r < 8; ++r) v[r] = make_float2(0.f, 0.f);
        dft8v<-1>(v);
        #pragma unroll
        for (int r = 0; r < 8; ++r) {
            int idx = FPAD(tid * 8 + r);
            Ar[idx] = v[r].x; Ai[idx] = v[r].y;
        }
    }
    __syncthreads();
    fft_stage<-1, 8, 8>(Ar, Ai, Br, Bi, twd, tid);   __syncthreads();
    fft_stage<-1, 64, 8>(Br, Bi, Ar, Ai, twd, tid);  __syncthreads();
    fft_stage<-1, 512, 4>(Ar, Ai, Br, Bi, twd, tid); __syncthreads();
    const float2* pf = Pf + (size_t)(h * NF + f) * NSEQ;
    #pragma unroll
    for (int q = 0; q < 8; ++q) {
        int i = tid + 256 * q;
        int idx = FPAD(i);
        float2 a = make_float2(Br[idx], Bi[idx]);
        float2 p = cmul(a, pf[i]);
        Br[idx] = p.x; Bi[idx] = p.y;
    }
    __syncthreads();
    fft_stage<1, 1, 8>(Br, Bi, Ar, Ai, twd, tid);  __syncthreads();
    fft_stage<1, 8, 8>(Ar, Ai, Br, Bi, twd, tid);  __syncthreads();
    fft_stage<1, 64, 8>(Br, Bi, Ar, Ai, twd, tid); __syncthreads();
    const float sc = 1.0f / 2048.0f;
    #pragma unroll
    for (int jj = 0; jj < 512; jj += 256) {
        int j = tid + jj;
        float2 v[4];
        #pragma unroll
        for (int r = 0; r < 4; ++r) {
            int idx = FPAD(j + 512 * r);
            v[r] = make_float2(Ar[idx], Ai[idx]);
        }
        float2 w1 = twd[j];
        w1.y = -w1.y;
        float2 w = w1;
        v[1] = cmul(v[1], w);
        w = cmul(w, w1); v[2] = cmul(v[2], w);
        w = cmul(w, w1); v[3] = cmul(v[3], w);
        dft4v<1>(v);
        xre[j] = v[0].x * sc;        xim[j] = v[0].y * sc;
        xre[j + 512] = v[1].x * sc;  xim[j + 512] = v[1].y * sc;
    }
}

// K6m: inverse channel DFT-64 as split-bf16 MFMA + exact GELU.
__global__ __launch_bounds__(256) void k6_mfma(const float* __restrict__ XcRe,
                                               const float* __restrict__ XcIm,
                                               ushort* __restrict__ Gh, ushort* __restrict__ Gl) {
    __shared__ union {
        float Y32[64][133];
        struct { ushort CH[64][72], CL[64][72]; } c;
    } uy;
    __shared__ ushort YH[128][72], YL[128][72];
    const int t0 = blockIdx.x * 128;
    const int bh = blockIdx.y;
    const int b = bh / NH, h = bh % NH;
    const int tid = threadIdx.x, lane = tid & 63, w = tid >> 6;

    for (int i = tid; i < 64 * 32; i += 256) {
        int c = i >> 5, tq = i & 31;
        const float* src = (c < 33) ? XcRe + (size_t)(bh * NF + c) * SL
                                    : XcIm + (size_t)(bh * NF + (c - 32)) * SL;
        float4 v = *(const float4*)&src[t0 + tq * 4];
        uy.Y32[c][tq * 4 + 0] = v.x; uy.Y32[c][tq * 4 + 1] = v.y;
        uy.Y32[c][tq * 4 + 2] = v.z; uy.Y32[c][tq * 4 + 3] = v.w;
    }
    __syncthreads();
    for (int i = tid; i < 128 * 8; i += 256) {
        int t = i & 127, c0 = (i >> 7) * 8;
        float v[8];
        #pragma unroll
        for (int j = 0; j < 8; ++j) v[j] = uy.Y32[c0 + j][t];
        unsigned int hp, lp;
        #pragma unroll
        for (int j = 0; j < 8; j += 2) {
            split2(v[j], v[j + 1], hp, lp);
            *(unsigned int*)&YH[t][c0 + j] = hp;
            *(unsigned int*)&YL[t][c0 + j] = lp;
        }
    }
    __syncthreads();
    for (int i = tid; i < 64 * 32; i += 256) {
        int e = i >> 5, c2 = (i & 31) * 2;
        float v[2];
        #pragma unroll
        for (int j = 0; j < 2; ++j) {
            int c = c2 + j;
            if (c <= 32) {
                float wt = (c == 0 || c == 32) ? (1.0f / 64.0f) : (2.0f / 64.0f);
                v[j] = wt * cosf(0.09817477042468103870f * (float)((c * e) & 63));
            } else {
                v[j] = -(2.0f / 64.0f) * sinf(0.09817477042468103870f * (float)(((c - 32) * e) & 63));
            }
        }
        unsigned int hp, lp;
        split2(v[0], v[1], hp, lp);
        *(unsigned int*)&uy.c.CH[e][c2] = hp;
        *(unsigned int*)&uy.c.CL[e][c2] = lp;
    }
    __syncthreads();

    f32x4 acc[2][4] = {};
    const int lr = lane & 15, lg = lane >> 4;
    #pragma unroll
    for (int ks = 0; ks < 64; ks += 32) {
        const int kg = ks + lg * 8;
        bf16x8 bh8[4], bl8[4];
        #pragma unroll
        for (int n = 0; n < 4; ++n) {
            bh8[n] = *(const bf16x8*)&uy.c.CH[n * 16 + lr][kg];
            bl8[n] = *(const bf16x8*)&uy.c.CL[n * 16 + lr][kg];
        }
        #pragma unroll
        for (int m = 0; m < 2; ++m) {
            const int row = w * 32 + m * 16 + lr;
            bf16x8 ah8 = *(const bf16x8*)&YH[row][kg];
            bf16x8 al8 = *(const bf16x8*)&YL[row][kg];
            #pragma unroll
            for (int n = 0; n < 4; ++n) {
                acc[m][n] = __builtin_amdgcn_mfma_f32_16x16x32_bf16(ah8, bh8[n], acc[m][n], 0, 0, 0);
                acc[m][n] = __builtin_amdgcn_mfma_f32_16x16x32_bf16(ah8, bl8[n], acc[m][n], 0, 0, 0);
                acc[m][n] = __builtin_amdgcn_mfma_f32_16x16x32_bf16(al8, bh8[n], acc[m][n], 0, 0, 0);
            }
        }
    }
    #pragma unroll
    for (int n = 0; n < 4; ++n) {
        const int col = h * 64 + n * 16 + lr;
        #pragma unroll
        for (int m = 0; m < 2; ++m) {
            #pragma unroll
            for (int j = 0; j < 4; ++j) {
                int t = t0 + w * 32 + m * 16 + lg * 4 + j;
                float v = acc[m][n][j];
                float g = 0.5f * v * (1.0f + erff(v * 0.70710678118654752440f));
                size_t idx = ((size_t)b * SL + t) * ED + col;
                unsigned short hb = bf16bits(g);
                Gh[idx] = hb;
                Gl[idx] = bf16bits(g - bf16val(hb));
            }
        }
    }
}

// K0b: cast W to bf16 hi/lo pair.
__global__ void k0_castW(const float* __restrict__ W,
                         ushort* __restrict__ Wh, ushort* __restrict__ Wl) {
    int i = blockIdx.x * 256 + threadIdx.x;
    if (i < ED * ED) {
        float w = W[i];
        unsigned short hb = bf16bits(w);
        Wh[i] = hb;
        Wl[i] = bf16bits(w - bf16val(hb));
    }
}

// K7: projection GEMM via split-bf16 MFMA; 64x128 tile, 48 KB dbuf (3 blocks/CU, 768 blocks).
// A: 64x32 hi/lo (1 gload/wave each), B: 128x32 hi/lo (2 gloads/wave each).
#define K7STAGE(p, kk) do { \
    const ushort* gA_  = Gh + (size_t)(i0 + aRow) * ED + (kk) + stCol; \
    const ushort* gAl_ = Gl + (size_t)(i0 + aRow) * ED + (kk) + stCol; \
    const ushort* gB_  = Wh + (size_t)(j0 + bRow) * ED + (kk) + stCol; \
    const ushort* gBl_ = Wl + (size_t)(j0 + bRow) * ED + (kk) + stCol; \
    __builtin_amdgcn_global_load_lds(GLB_U32(gA_),           LDS_U32(&Ah[p][aBase]), 16, 0, 0); \
    __builtin_amdgcn_global_load_lds(GLB_U32(gAl_),          LDS_U32(&Al[p][aBase]), 16, 0, 0); \
    __builtin_amdgcn_global_load_lds(GLB_U32(gB_),           LDS_U32(&Bh[p][bBase]), 16, 0, 0); \
    __builtin_amdgcn_global_load_lds(GLB_U32(gB_ + 16 * ED), LDS_U32(&Bh[p][bBase + 512]), 16, 0, 0); \
    __builtin_amdgcn_global_load_lds(GLB_U32(gBl_),          LDS_U32(&Bl[p][bBase]), 16, 0, 0); \
    __builtin_amdgcn_global_load_lds(GLB_U32(gBl_ + 16 * ED),LDS_U32(&Bl[p][bBase + 512]), 16, 0, 0); \
} while (0)

__global__ __launch_bounds__(256) void k7_mfma(
        const ushort* __restrict__ Gh, const ushort* __restrict__ Gl,
        const ushort* __restrict__ Wh, const ushort* __restrict__ Wl,
        const float* __restrict__ bias, float* __restrict__ out) {
    __shared__ ushort Ah[2][64 * 32], Al[2][64 * 32];     // 8 KB each pair-set
    __shared__ ushort Bh[2][128 * 32], Bl[2][128 * 32];   // 16 KB each -> total 48 KB
    // 768 blocks = 8 XCDs x 96; bijective swizzle.
    const int bid = blockIdx.y * gridDim.x + blockIdx.x;
    const int swz = (bid & 7) * 96 + (bid >> 3);
    const int j0 = (swz % 6) * 128;
    const int i0 = (swz / 6) * 64;
    const int tid = threadIdx.x;
    const int lane = tid & 63, wid = tid >> 6;
    const int wm = wid >> 1, wn = wid & 1;    // 2(M) x 2(N); wave = 32x64 output

    // staging geometry
    const int aRow = wid * 16 + (lane >> 2);            // A rows 0..63
    const int bRow = wid * 32 + (lane >> 2);            // B rows 0..127 (first 16; +16 in 2nd load)
    const int stCol = (lane & 3) * 8;
    const int aBase = wid * 512;                         // ushort offsets
    const int bBase = wid * 1024;

    f32x4 acc[2][4] = {};

    const int arow = wm * 32 + (lane & 15);
    const int brow = wn * 64 + (lane & 15);
    const int kb8  = (lane >> 4) * 8;

    K7STAGE(0, 0);
    asm volatile("s_waitcnt vmcnt(0)" ::: "memory");
    __syncthreads();

    for (int t = 0; t < 24; ++t) {
        const int cur = t & 1;
        if (t < 23) K7STAGE(cur ^ 1, (t + 1) * 32);

        bf16x8 ah[2], al[2], bh4[4], bl4[4];
        #pragma unroll
        for (int m = 0; m < 2; ++m) {
            ah[m] = *(const bf16x8*)&Ah[cur][(arow + m * 16) * 32 + kb8];
            al[m] = *(const bf16x8*)&Al[cur][(arow + m * 16) * 32 + kb8];
        }
        #pragma unroll
        for (int n = 0; n < 4; ++n) {
            bh4[n] = *(const bf16x8*)&Bh[cur][(brow + n * 16) * 32 + kb8];
            bl4[n] = *(const bf16x8*)&Bl[cur][(brow + n * 16) * 32 + kb8];
        }
        #pragma unroll
        for (int m = 0; m < 2; ++m)
            #pragma unroll
            for (int n = 0; n < 4; ++n) {
                acc[m][n] = __builtin_amdgcn_mfma_f32_16x16x32_bf16(ah[m], bh4[n], acc[m][n], 0, 0, 0);
                acc[m][n] = __builtin_amdgcn_mfma_f32_16x16x32_bf16(ah[m], bl4[n], acc[m][n], 0, 0, 0);
                acc[m][n] = __builtin_amdgcn_mfma_f32_16x16x32_bf16(al[m], bh4[n], acc[m][n], 0, 0, 0);
            }
        asm volatile("s_waitcnt vmcnt(0)" ::: "memory");
        __syncthreads();
    }

    const int ocol0 = j0 + wn * 64 + (lane & 15);
    const int orow0 = i0 + wm * 32 + (lane >> 4) * 4;
    #pragma unroll
    for (int n = 0; n < 4; ++n) {
        const float bv = bias[ocol0 + n * 16];
        #pragma unroll
        for (int m = 0; m < 2; ++m) {
            #pragma unroll
            for (int j = 0; j < 4; ++j) {
                out[(size_t)(orow0 + m * 16 + j) * ED + ocol0 + n * 16] = acc[m][n][j] + bv;
            }
        }
    }
}

extern "C" void kernel_launch(void* const* d_in, const int* in_sizes, int n_in,
                              void* d_out, int out_size, void* d_ws, size_t ws_size,
                              hipStream_t stream) {
    (void)in_sizes; (void)n_in; (void)out_size; (void)ws_size;
    const float* emb  = (const float*)d_in[0];   // [8,1024,768]
    const float* tp   = (const float*)d_in[1];   // [12,2047,64]
    const float* W    = (const float*)d_in[2];   // [768,768]
    const float* bias = (const float*)d_in[3];   // [768]

    float* out_conv = (float*)d_out;                             // 8*1024*768
    float* out_psf  = out_conv + (size_t)NB * SL * ED;           // 12*2047*64

    // workspace layout:
    float2* Pc = (float2*)d_ws;                                  // 12*33*1024 complex (dead after k3)
    float2* Pf = Pc + (size_t)NH * NF * SL;                      // 12*33*2048 complex
    float*  XcRe = (float*)(Pf + (size_t)NH * NF * NSEQ);        // 96*33*1024 f32
    float*  XcIm = XcRe + (size_t)NB * NH * NF * SL;             // 96*33*1024 f32
    ushort* Gh = (ushort*)(XcIm + (size_t)NB * NH * NF * SL);    // 8192*768 bf16
    ushort* Gl = Gh + (size_t)NB * SL * ED;                      // 8192*768 bf16
    // W hi/lo overlaid on Pc region (2.36 MB <= 3.24 MB), written after k3 consumes Pc
    ushort* Whh = (ushort*)Pc;
    ushort* Wll = Whh + (size_t)ED * ED;
    // softmax partials overlaid on Pf start (dead until k3 writes Pf)
    float* pMax = (float*)Pf;          // 12*32*64
    float* pSum = pMax + NH * 32 * 64; // 12*32*64
    float* Mf   = pSum + NH * 32 * 64; // 768
    float* Invf = Mf + NH * 64;        // 768

    k1a_partial<<<dim3(32, NH), dim3(256), 0, stream>>>(tp, pMax, pSum);
    k1b_fold<<<dim3(NH), dim3(64), 0, stream>>>(pMax, pSum, Mf, Invf);
    k1c_norm<<<dim3(32, NH), dim3(256), 0, stream>>>(tp, Mf, Invf, out_psf);
    k2_mfma<<<dim3(SL / 128, NH), dim3(256), 0, stream>>>(out_psf, Pc);
    k3_psf_fft<<<dim3(NH * NF), dim3(256), 0, stream>>>(Pc, Pf);
    k0_castW<<<dim3((ED * ED + 255) / 256), dim3(256), 0, stream>>>(W, Whh, Wll);
    k4_mfma<<<dim3(SL / 128, NB * NH), dim3(256), 0, stream>>>(emb, XcRe, XcIm);
    k5_seq_conv<<<dim3(NB * NH * NF), dim3(256), 0, stream>>>(XcRe, XcIm, Pf);
    k6_mfma<<<dim3(SL / 128, NB * NH), dim3(256), 0, stream>>>(XcRe, XcIm, Gh, Gl);
    k7_mfma<<<dim3(ED / 128, (NB * SL) / 64), dim3(256), 0, stream>>>(
        Gh, Gl, Whh, Wll, bias, out_conv);
}

// Round 9
// 155.680 us; speedup vs baseline: 1.2189x; 1.0021x over previous
//
#include <hip/hip_runtime.h>
#include <hip/hip_bf16.h>
#include <math.h>

#define NH 12
#define DH 64
#define SL 1024
#define NB 8
#define ED 768
#define NTAP 2047
#define NF 33
#define NSEQ 2048

typedef __attribute__((ext_vector_type(8))) short bf16x8;
typedef __attribute__((ext_vector_type(4))) float f32x4;

#define GLB_U32(p) ((const __attribute__((address_space(1))) unsigned int*)(p))
#define LDS_U32(p) ((__attribute__((address_space(3))) unsigned int*)(p))

__device__ __forceinline__ float2 cadd(float2 a, float2 b){ return make_float2(a.x+b.x, a.y+b.y); }
__device__ __forceinline__ float2 csub(float2 a, float2 b){ return make_float2(a.x-b.x, a.y-b.y); }
__device__ __forceinline__ float2 cmul(float2 a, float2 b){ return make_float2(a.x*b.x - a.y*b.y, a.x*b.y + a.y*b.x); }

__device__ __forceinline__ unsigned short bf16bits(float f) {
    __hip_bfloat16 hb = __float2bfloat16(f);
    return *reinterpret_cast<unsigned short*>(&hb);
}
__device__ __forceinline__ float bf16val(unsigned short u) {
    __hip_bfloat16 hb = *reinterpret_cast<__hip_bfloat16*>(&u);
    return __bfloat162float(hb);
}
// split two fp32 into packed bf16 hi-pair and lo-pair
__device__ __forceinline__ void split2(float a, float b, unsigned int& hp, unsigned int& lp) {
    unsigned short ha = bf16bits(a), hb = bf16bits(b);
    unsigned short la = bf16bits(a - bf16val(ha)), lb = bf16bits(b - bf16val(hb));
    hp = (unsigned int)ha | ((unsigned int)hb << 16);
    lp = (unsigned int)la | ((unsigned int)lb << 16);
}

// ---------------- Stockham FFT pieces (N=2048 = 8*8*8*4, constant geometry) ----------------
#define FPAD(i) ((i) + ((i) >> 3))

template<int DIR>
__device__ __forceinline__ void dft4v(float2 v[4]) {
    float2 e0 = cadd(v[0], v[2]), e1 = csub(v[0], v[2]);
    float2 o0 = cadd(v[1], v[3]), o1 = csub(v[1], v[3]);
    float2 o1t = (DIR < 0) ? make_float2(o1.y, -o1.x) : make_float2(-o1.y, o1.x);
    v[0] = cadd(e0, o0);
    v[1] = cadd(e1, o1t);
    v[2] = csub(e0, o0);
    v[3] = csub(e1, o1t);
}

template<int DIR>
__device__ __forceinline__ void dft8v(float2 v[8]) {
    const float RS = 0.70710678118654752440f;
    float2 e[4] = { v[0], v[2], v[4], v[6] };
    float2 o[4] = { v[1], v[3], v[5], v[7] };
    dft4v<DIR>(e);
    dft4v<DIR>(o);
    float2 t1 = (DIR < 0) ? make_float2(RS * (o[1].x + o[1].y), RS * (o[1].y - o[1].x))
                          : make_float2(RS * (o[1].x - o[1].y), RS * (o[1].y + o[1].x));
    float2 t2 = (DIR < 0) ? make_float2(o[2].y, -o[2].x) : make_float2(-o[2].y, o[2].x);
    float2 t3 = (DIR < 0) ? make_float2(RS * (o[3].y - o[3].x), RS * (-o[3].x - o[3].y))
                          : make_float2(RS * (-o[3].x - o[3].y), RS * (o[3].x - o[3].y));
    v[0] = cadd(e[0], o[0]); v[4] = csub(e[0], o[0]);
    v[1] = cadd(e[1], t1);   v[5] = csub(e[1], t1);
    v[2] = cadd(e[2], t2);   v[6] = csub(e[2], t2);
    v[3] = cadd(e[3], t3);   v[7] = csub(e[3], t3);
}

template<int DIR, int L, int R>
__device__ __forceinline__ void fft_stage(const float* __restrict__ sr, const float* __restrict__ si,
                                          float* __restrict__ dr, float* __restrict__ di,
                                          const float2* __restrict__ twd, int tid) {
    const int T = 2048 / R;
    #pragma unroll
    for (int jj = 0; jj < T; jj += 256) {
        int j = tid + jj;
        int k = j & (L - 1);
        int blk = j / L;
        float2 v[R];
        #pragma unroll
        for (int r = 0; r < R; ++r) {
            int idx = FPAD(j + T * r);
            v[r] = make_float2(sr[idx], si[idx]);
        }
        if (L > 1) {
            const int c = 2048 / (R * L);
            float2 w1 = twd[c * k];
            if (DIR > 0) w1.y = -w1.y;
            float2 w = w1;
            v[1] = cmul(v[1], w);
            #pragma unroll
            for (int r = 2; r < R; ++r) { w = cmul(w, w1); v[r] = cmul(v[r], w); }
        }
        if (R == 8) dft8v<DIR>(v); else dft4v<DIR>(v);
        int base = blk * (R * L) + k;
        #pragma unroll
        for (int r = 0; r < R; ++r) {
            int idx = FPAD(base + L * r);
            dr[idx] = v[r].x; di[idx] = v[r].y;
        }
    }
}

// compute twiddle LUT W_2048^i (i<512) into LDS
__device__ __forceinline__ void gen_twd(float2* twd, int tid) {
    for (int i = tid; i < 512; i += 256) {
        float ang = -6.28318530717958647692f * (float)i / 2048.0f;
        twd[i] = make_float2(cosf(ang), sinf(ang));
    }
}

// ---------------- K1: 3-pass coalesced softmax over taps ----------------
__global__ void k1a_partial(const float* __restrict__ tp, float* __restrict__ pMax, float* __restrict__ pSum) {
    __shared__ float lm[4][64], ls[4][64];
    int c = blockIdx.x, h = blockIdx.y;
    int tid = threadIdx.x, w = tid >> 6, e = tid & 63;
    const float* base = tp + (size_t)h * NTAP * 64;
    float m = -1e30f, s = 0.f;
    #pragma unroll
    for (int i = 0; i < 16; ++i) {
        int row = c * 64 + w + 4 * i;
        if (row < NTAP) {
            float v = base[(size_t)row * 64 + e];
            float mn = fmaxf(m, v);
            s = s * expf(m - mn) + expf(v - mn);
            m = mn;
        }
    }
    lm[w][e] = m; ls[w][e] = s;
    __syncthreads();
    if (w == 0) {
        float M = m, S = s;
        #pragma unroll
        for (int i = 1; i < 4; ++i) {
            float mi = lm[i][e], si = ls[i][e];
            float mn = fmaxf(M, mi);
            S = S * expf(M - mn) + si * expf(mi - mn);
            M = mn;
        }
        pMax[(h * 32 + c) * 64 + e] = M;
        pSum[(h * 32 + c) * 64 + e] = S;
    }
}

__global__ void k1b_fold(const float* __restrict__ pMax, const float* __restrict__ pSum,
                         float* __restrict__ Mf, float* __restrict__ Invf) {
    int h = blockIdx.x, e = threadIdx.x;
    float M = -1e30f, S = 0.f;
    for (int c = 0; c < 32; ++c) {
        float mi = pMax[(h * 32 + c) * 64 + e], si = pSum[(h * 32 + c) * 64 + e];
        float mn = fmaxf(M, mi);
        S = S * expf(M - mn) + si * expf(mi - mn);
        M = mn;
    }
    Mf[h * 64 + e] = M;
    Invf[h * 64 + e] = 1.0f / S;
}

__global__ void k1c_norm(const float* __restrict__ tp, const float* __restrict__ Mf,
                         const float* __restrict__ Invf, float* __restrict__ psf_out) {
    int c = blockIdx.x, h = blockIdx.y;
    int tid = threadIdx.x, w = tid >> 6, e = tid & 63;
    float M = Mf[h * 64 + e], inv = Invf[h * 64 + e];
    const float* base = tp + (size_t)h * NTAP * 64;
    float* ob = psf_out + (size_t)h * NTAP * 64;
    #pragma unroll
    for (int i = 0; i < 16; ++i) {
        int row = c * 64 + w + 4 * i;
        if (row < NTAP) {
            float o = 0.f;
            if (row < SL) o = expf(base[(size_t)row * 64 + e] - M) * inv;
            ob[(size_t)row * 64 + e] = o;
        }
    }
}

// K2m: psf channel DFT-64 as split-bf16 MFMA.
__global__ __launch_bounds__(256) void k2_mfma(const float* __restrict__ psf, float2* __restrict__ Pc) {
    __shared__ union {
        struct {
            ushort EH[128][72], EL[128][72];
            ushort CH[80][72],  CL[80][72];
        } s;
        float Dl[66][133];
    } u;
    const int t0 = blockIdx.x * 128;
    const int h = blockIdx.y;
    const int tid = threadIdx.x, lane = tid & 63, w = tid >> 6;

    for (int i = tid; i < 128 * 16; i += 256) {
        int r = i >> 4, q = i & 15;
        float4 v = *(const float4*)&psf[((size_t)h * NTAP + t0 + r) * 64 + q * 4];
        unsigned int hp, lp;
        split2(v.x, v.y, hp, lp);
        *(unsigned int*)&u.s.EH[r][q * 4]     = hp;  *(unsigned int*)&u.s.EL[r][q * 4]     = lp;
        split2(v.z, v.w, hp, lp);
        *(unsigned int*)&u.s.EH[r][q * 4 + 2] = hp;  *(unsigned int*)&u.s.EL[r][q * 4 + 2] = lp;
    }
    for (int i = tid; i < 80 * 32; i += 256) {
        int c = i >> 5, e2 = (i & 31) * 2;
        float v0 = 0.f, v1 = 0.f;
        if (c < 33) {
            v0 = cosf(0.09817477042468103870f * (float)((c * e2) & 63));
            v1 = cosf(0.09817477042468103870f * (float)((c * (e2 + 1)) & 63));
        } else if (c < 66) {
            v0 = -sinf(0.09817477042468103870f * (float)(((c - 33) * e2) & 63));
            v1 = -sinf(0.09817477042468103870f * (float)(((c - 33) * (e2 + 1)) & 63));
        }
        unsigned int hp, lp;
        split2(v0, v1, hp, lp);
        *(unsigned int*)&u.s.CH[c][e2] = hp;  *(unsigned int*)&u.s.CL[c][e2] = lp;
    }
    __syncthreads();

    f32x4 acc[2][5] = {};
    const int lr = lane & 15, lg = lane >> 4;
    #pragma unroll
    for (int ks = 0; ks < 64; ks += 32) {
        const int kg = ks + lg * 8;
        bf16x8 bh8[5], bl8[5];
        #pragma unroll
        for (int n = 0; n < 5; ++n) {
            bh8[n] = *(const bf16x8*)&u.s.CH[n * 16 + lr][kg];
            bl8[n] = *(const bf16x8*)&u.s.CL[n * 16 + lr][kg];
        }
        #pragma unroll
        for (int m = 0; m < 2; ++m) {
            const int row = w * 32 + m * 16 + lr;
            bf16x8 ah8 = *(const bf16x8*)&u.s.EH[row][kg];
            bf16x8 al8 = *(const bf16x8*)&u.s.EL[row][kg];
            #pragma unroll
            for (int n = 0; n < 5; ++n) {
                acc[m][n] = __builtin_amdgcn_mfma_f32_16x16x32_bf16(ah8, bh8[n], acc[m][n], 0, 0, 0);
                acc[m][n] = __builtin_amdgcn_mfma_f32_16x16x32_bf16(ah8, bl8[n], acc[m][n], 0, 0, 0);
                acc[m][n] = __builtin_amdgcn_mfma_f32_16x16x32_bf16(al8, bh8[n], acc[m][n], 0, 0, 0);
            }
        }
    }
    __syncthreads();
    #pragma unroll
    for (int n = 0; n < 5; ++n) {
        int c = n * 16 + lr;
        if (c < 66) {
            #pragma unroll
            for (int m = 0; m < 2; ++m)
                #pragma unroll
                for (int j = 0; j < 4; ++j)
                    u.Dl[c][w * 32 + m * 16 + lg * 4 + j] = acc[m][n][j];
        }
    }
    __syncthreads();
    for (int i = tid; i < 33 * 128; i += 256) {
        int f = i >> 7, t = i & 127;
        Pc[(size_t)(h * NF + f) * SL + t0 + t] = make_float2(u.Dl[f][t], u.Dl[f + 33][t]);
    }
}

// K3: seq FFT-2048 of psf per (h,f), Stockham, natural order out.
__global__ __launch_bounds__(256) void k3_psf_fft(const float2* __restrict__ Pc, float2* __restrict__ Pf) {
    __shared__ float Ar[2304], Ai[2304], Br[2304], Bi[2304];
    __shared__ float2 twd[512];
    int h = blockIdx.x / NF, f = blockIdx.x % NF;
    int tid = threadIdx.x;
    gen_twd(twd, tid);
    const float2* src = Pc + (size_t)(h * NF + f) * SL;
    {
        float2 v[8];
        #pragma unroll
        for (int r = 0; r < 4; ++r) v[r] = src[tid + 256 * r];
        #pragma unroll
        for (int r = 4; r < 8; ++r) v[r] = make_float2(0.f, 0.f);
        dft8v<-1>(v);
        #pragma unroll
        for (int r = 0; r < 8; ++r) {
            int idx = FPAD(tid * 8 + r);
            Ar[idx] = v[r].x; Ai[idx] = v[r].y;
        }
    }
    __syncthreads();
    fft_stage<-1, 8, 8>(Ar, Ai, Br, Bi, twd, tid);  __syncthreads();
    fft_stage<-1, 64, 8>(Br, Bi, Ar, Ai, twd, tid); __syncthreads();
    float2* dst = Pf + (size_t)(h * NF + f) * NSEQ;
    #pragma unroll
    for (int jj = 0; jj < 512; jj += 256) {
        int j = tid + jj;
        float2 v[4];
        #pragma unroll
        for (int r = 0; r < 4; ++r) {
            int idx = FPAD(j + 512 * r);
            v[r] = make_float2(Ar[idx], Ai[idx]);
        }
        float2 w1 = twd[j];
        float2 w = w1;
        v[1] = cmul(v[1], w);
        w = cmul(w, w1); v[2] = cmul(v[2], w);
        w = cmul(w, w1); v[3] = cmul(v[3], w);
        dft4v<-1>(v);
        #pragma unroll
        for (int r = 0; r < 4; ++r) dst[j + 512 * r] = v[r];
    }
}

// K4m: channel DFT-64 as split-bf16 MFMA; staging pre-splits to bf16 hi/lo in LDS.
__global__ __launch_bounds__(256) void k4_mfma(const float* __restrict__ emb,
                                               float* __restrict__ XcRe, float* __restrict__ XcIm) {
    __shared__ union {
        struct {
            ushort EH[128][72], EL[128][72];
            ushort CH[80][72],  CL[80][72];
        } s;
        float Dl[66][133];
    } u;
    const int t0 = blockIdx.x * 128;
    const int bh = blockIdx.y;
    const int b = bh / NH, h = bh % NH;
    const int tid = threadIdx.x, lane = tid & 63, w = tid >> 6;

    for (int i = tid; i < 128 * 16; i += 256) {
        int r = i >> 4, q = i & 15;
        float4 v = *(const float4*)&emb[((size_t)b * SL + t0 + r) * ED + h * 64 + q * 4];
        unsigned int hp, lp;
        split2(v.x, v.y, hp, lp);
        *(unsigned int*)&u.s.EH[r][q * 4]     = hp;  *(unsigned int*)&u.s.EL[r][q * 4]     = lp;
        split2(v.z, v.w, hp, lp);
        *(unsigned int*)&u.s.EH[r][q * 4 + 2] = hp;  *(unsigned int*)&u.s.EL[r][q * 4 + 2] = lp;
    }
    for (int i = tid; i < 80 * 32; i += 256) {
        int c = i >> 5, e2 = (i & 31) * 2;
        float v0 = 0.f, v1 = 0.f;
        if (c < 33) {
            v0 = cosf(0.09817477042468103870f * (float)((c * e2) & 63));
            v1 = cosf(0.09817477042468103870f * (float)((c * (e2 + 1)) & 63));
        } else if (c < 66) {
            v0 = -sinf(0.09817477042468103870f * (float)(((c - 33) * e2) & 63));
            v1 = -sinf(0.09817477042468103870f * (float)(((c - 33) * (e2 + 1)) & 63));
        }
        unsigned int hp, lp;
        split2(v0, v1, hp, lp);
        *(unsigned int*)&u.s.CH[c][e2] = hp;  *(unsigned int*)&u.s.CL[c][e2] = lp;
    }
    __syncthreads();

    f32x4 acc[2][5] = {};
    const int lr = lane & 15, lg = lane >> 4;
    #pragma unroll
    for (int ks = 0; ks < 64; ks += 32) {
        const int kg = ks + lg * 8;
        bf16x8 bh8[5], bl8[5];
        #pragma unroll
        for (int n = 0; n < 5; ++n) {
            bh8[n] = *(const bf16x8*)&u.s.CH[n * 16 + lr][kg];
            bl8[n] = *(const bf16x8*)&u.s.CL[n * 16 + lr][kg];
        }
        #pragma unroll
        for (int m = 0; m < 2; ++m) {
            const int row = w * 32 + m * 16 + lr;
            bf16x8 ah8 = *(const bf16x8*)&u.s.EH[row][kg];
            bf16x8 al8 = *(const bf16x8*)&u.s.EL[row][kg];
            #pragma unroll
            for (int n = 0; n < 5; ++n) {
                acc[m][n] = __builtin_amdgcn_mfma_f32_16x16x32_bf16(ah8, bh8[n], acc[m][n], 0, 0, 0);
                acc[m][n] = __builtin_amdgcn_mfma_f32_16x16x32_bf16(ah8, bl8[n], acc[m][n], 0, 0, 0);
                acc[m][n] = __builtin_amdgcn_mfma_f32_16x16x32_bf16(al8, bh8[n], acc[m][n], 0, 0, 0);
            }
        }
    }
    __syncthreads();
    #pragma unroll
    for (int n = 0; n < 5; ++n) {
        int c = n * 16 + lr;
        if (c < 66) {
            #pragma unroll
            for (int m = 0; m < 2; ++m)
                #pragma unroll
                for (int j = 0; j < 4; ++j)
                    u.Dl[c][w * 32 + m * 16 + lg * 4 + j] = acc[m][n][j];
        }
    }
    __syncthreads();
    for (int i = tid; i < 66 * 128; i += 256) {
        int c = i >> 7, t = i & 127;
        float val = u.Dl[c][t];
        if (c < 33) XcRe[(size_t)(bh * NF + c) * SL + t0 + t] = val;
        else        XcIm[(size_t)(bh * NF + (c - 33)) * SL + t0 + t] = val;
    }
}

// K5: Stockham fwd FFT -> pointwise * Pf -> Stockham inv FFT, in-place on Xc planes.
__global__ __launch_bounds__(256) void k5_seq_conv(float* __restrict__ XcRe, float* __restrict__ XcIm,
                                                   const float2* __restrict__ Pf) {
    __shared__ float Ar[2304], Ai[2304], Br[2304], Bi[2304];
    __shared__ float2 twd[512];
    int f = blockIdx.x % NF;
    int bh = blockIdx.x / NF;
    int h = bh % NH;
    int tid = threadIdx.x;
    gen_twd(twd, tid);
    float* xre = XcRe + (size_t)(bh * NF + f) * SL;
    float* xim = XcIm + (size_t)(bh * NF + f) * SL;
    {
        float2 v[8];
        #pragma unroll
        for (int r = 0; r < 4; ++r) v[r] = make_float2(xre[tid + 256 * r], xim[tid + 256 * r]);
        #pragma unroll
        for (int r = 4; r < 8; ++r) v[r] = make_float2(0.f, 0.f);
        dft8v<-1>(v);
        #pragma unroll
        for (int r = 0; r < 8; ++r) {
            int idx = FPAD(tid * 8 + r);
            Ar[idx] = v[r].x; Ai[idx] = v[r].y;
        }
    }
    __syncthreads();
    fft_stage<-1, 8, 8>(Ar, Ai, Br, Bi, twd, tid);   __syncthreads();
    fft_stage<-1, 64, 8>(Br, Bi, Ar, Ai, twd, tid);  __syncthreads();
    fft_stage<-1, 512, 4>(Ar, Ai, Br, Bi, twd, tid); __syncthreads();
    const float2* pf = Pf + (size_t)(h * NF + f) * NSEQ;
    #pragma unroll
    for (int q = 0; q < 8; ++q) {
        int i = tid + 256 * q;
        int idx = FPAD(i);
        float2 a = make_float2(Br[idx], Bi[idx]);
        float2 p = cmul(a, pf[i]);
        Br[idx] = p.x; Bi[idx] = p.y;
    }
    __syncthreads();
    fft_stage<1, 1, 8>(Br, Bi, Ar, Ai, twd, tid);  __syncthreads();
    fft_stage<1, 8, 8>(Ar, Ai, Br, Bi, twd, tid);  __syncthreads();
    fft_stage<1, 64, 8>(Br, Bi, Ar, Ai, twd, tid); __syncthreads();
    const float sc = 1.0f / 2048.0f;
    #pragma unroll
    for (int jj = 0; jj < 512; jj += 256) {
        int j = tid + jj;
        float2 v[4];
        #pragma unroll
        for (int r = 0; r < 4; ++r) {
            int idx = FPAD(j + 512 * r);
            v[r] = make_float2(Ar[idx], Ai[idx]);
        }
        float2 w1 = twd[j];
        w1.y = -w1.y;
        float2 w = w1;
        v[1] = cmul(v[1], w);
        w = cmul(w, w1); v[2] = cmul(v[2], w);
        w = cmul(w, w1); v[3] = cmul(v[3], w);
        dft4v<1>(v);
        xre[j] = v[0].x * sc;        xim[j] = v[0].y * sc;
        xre[j + 512] = v[1].x * sc;  xim[j + 512] = v[1].y * sc;
    }
}

// K6m: inverse channel DFT-64 as split-bf16 MFMA + exact GELU.
__global__ __launch_bounds__(256) void k6_mfma(const float* __restrict__ XcRe,
                                               const float* __restrict__ XcIm,
                                               ushort* __restrict__ Gh, ushort* __restrict__ Gl) {
    __shared__ union {
        float Y32[64][133];
        struct { ushort CH[64][72], CL[64][72]; } c;
    } uy;
    __shared__ ushort YH[128][72], YL[128][72];
    const int t0 = blockIdx.x * 128;
    const int bh = blockIdx.y;
    const int b = bh / NH, h = bh % NH;
    const int tid = threadIdx.x, lane = tid & 63, w = tid >> 6;

    for (int i = tid; i < 64 * 32; i += 256) {
        int c = i >> 5, tq = i & 31;
        const float* src = (c < 33) ? XcRe + (size_t)(bh * NF + c) * SL
                                    : XcIm + (size_t)(bh * NF + (c - 32)) * SL;
        float4 v = *(const float4*)&src[t0 + tq * 4];
        uy.Y32[c][tq * 4 + 0] = v.x; uy.Y32[c][tq * 4 + 1] = v.y;
        uy.Y32[c][tq * 4 + 2] = v.z; uy.Y32[c][tq * 4 + 3] = v.w;
    }
    __syncthreads();
    for (int i = tid; i < 128 * 8; i += 256) {
        int t = i & 127, c0 = (i >> 7) * 8;
        float v[8];
        #pragma unroll
        for (int j = 0; j < 8; ++j) v[j] = uy.Y32[c0 + j][t];
        unsigned int hp, lp;
        #pragma unroll
        for (int j = 0; j < 8; j += 2) {
            split2(v[j], v[j + 1], hp, lp);
            *(unsigned int*)&YH[t][c0 + j] = hp;
            *(unsigned int*)&YL[t][c0 + j] = lp;
        }
    }
    __syncthreads();
    for (int i = tid; i < 64 * 32; i += 256) {
        int e = i >> 5, c2 = (i & 31) * 2;
        float v[2];
        #pragma unroll
        for (int j = 0; j < 2; ++j) {
            int c = c2 + j;
            if (c <= 32) {
                float wt = (c == 0 || c == 32) ? (1.0f / 64.0f) : (2.0f / 64.0f);
                v[j] = wt * cosf(0.09817477042468103870f * (float)((c * e) & 63));
            } else {
                v[j] = -(2.0f / 64.0f) * sinf(0.09817477042468103870f * (float)(((c - 32) * e) & 63));
            }
        }
        unsigned int hp, lp;
        split2(v[0], v[1], hp, lp);
        *(unsigned int*)&uy.c.CH[e][c2] = hp;
        *(unsigned int*)&uy.c.CL[e][c2] = lp;
    }
    __syncthreads();

    f32x4 acc[2][4] = {};
    const int lr = lane & 15, lg = lane >> 4;
    #pragma unroll
    for (int ks = 0; ks < 64; ks += 32) {
        const int kg = ks + lg * 8;
        bf16x8 bh8[4], bl8[4];
        #pragma unroll
        for (int n = 0; n < 4; ++n) {
            bh8[n] = *(const bf16x8*)&uy.c.CH[n * 16 + lr][kg];
            bl8[n] = *(const bf16x8*)&uy.c.CL[n * 16 + lr][kg];
        }
        #pragma unroll
        for (int m = 0; m < 2; ++m) {
            const int row = w * 32 + m * 16 + lr;
            bf16x8 ah8 = *(const bf16x8*)&YH[row][kg];
            bf16x8 al8 = *(const bf16x8*)&YL[row][kg];
            #pragma unroll
            for (int n = 0; n < 4; ++n) {
                acc[m][n] = __builtin_amdgcn_mfma_f32_16x16x32_bf16(ah8, bh8[n], acc[m][n], 0, 0, 0);
                acc[m][n] = __builtin_amdgcn_mfma_f32_16x16x32_bf16(ah8, bl8[n], acc[m][n], 0, 0, 0);
                acc[m][n] = __builtin_amdgcn_mfma_f32_16x16x32_bf16(al8, bh8[n], acc[m][n], 0, 0, 0);
            }
        }
    }
    #pragma unroll
    for (int n = 0; n < 4; ++n) {
        const int col = h * 64 + n * 16 + lr;
        #pragma unroll
        for (int m = 0; m < 2; ++m) {
            #pragma unroll
            for (int j = 0; j < 4; ++j) {
                int t = t0 + w * 32 + m * 16 + lg * 4 + j;
                float v = acc[m][n][j];
                float g = 0.5f * v * (1.0f + erff(v * 0.70710678118654752440f));
                size_t idx = ((size_t)b * SL + t) * ED + col;
                unsigned short hb = bf16bits(g);
                Gh[idx] = hb;
                Gl[idx] = bf16bits(g - bf16val(hb));
            }
        }
    }
}

// K0b: cast W to bf16 hi/lo pair.
__global__ void k0_castW(const float* __restrict__ W,
                         ushort* __restrict__ Wh, ushort* __restrict__ Wl) {
    int i = blockIdx.x * 256 + threadIdx.x;
    if (i < ED * ED) {
        float w = W[i];
        unsigned short hb = bf16bits(w);
        Wh[i] = hb;
        Wl[i] = bf16bits(w - bf16val(hb));
    }
}

// K7: projection GEMM via split-bf16 MFMA; 64x128 tile, 48 KB dbuf, XOR bank swizzle,
// counted vmcnt(6) pipeline (never drain to 0 in the main loop).
// LDS k-slot swizzle: LDS slot s of row r holds global k-slot s ^ ((r>>1)&3); dest stays linear,
// source address carries the XOR (rule: both-sides-or-neither with global_load_lds).
#define K7STAGE(p, kk) do { \
    const ushort* gA_  = Gh + (size_t)(i0 + aRow) * ED + (kk) + stCol; \
    const ushort* gAl_ = Gl + (size_t)(i0 + aRow) * ED + (kk) + stCol; \
    const ushort* gB_  = Wh + (size_t)(j0 + bRow) * ED + (kk) + stCol; \
    const ushort* gBl_ = Wl + (size_t)(j0 + bRow) * ED + (kk) + stCol; \
    __builtin_amdgcn_global_load_lds(GLB_U32(gA_),           LDS_U32(&Ah[p][aBase]), 16, 0, 0); \
    __builtin_amdgcn_global_load_lds(GLB_U32(gAl_),          LDS_U32(&Al[p][aBase]), 16, 0, 0); \
    __builtin_amdgcn_global_load_lds(GLB_U32(gB_),           LDS_U32(&Bh[p][bBase]), 16, 0, 0); \
    __builtin_amdgcn_global_load_lds(GLB_U32(gB_ + 16 * ED), LDS_U32(&Bh[p][bBase + 512]), 16, 0, 0); \
    __builtin_amdgcn_global_load_lds(GLB_U32(gBl_),          LDS_U32(&Bl[p][bBase]), 16, 0, 0); \
    __builtin_amdgcn_global_load_lds(GLB_U32(gBl_ + 16 * ED),LDS_U32(&Bl[p][bBase + 512]), 16, 0, 0); \
} while (0)

__global__ __launch_bounds__(256) void k7_mfma(
        const ushort* __restrict__ Gh, const ushort* __restrict__ Gl,
        const ushort* __restrict__ Wh, const ushort* __restrict__ Wl,
        const float* __restrict__ bias, float* __restrict__ out) {
    __shared__ ushort Ah[2][64 * 32], Al[2][64 * 32];
    __shared__ ushort Bh[2][128 * 32], Bl[2][128 * 32];   // 48 KB total
    const int bid = blockIdx.y * gridDim.x + blockIdx.x;
    const int swz = (bid & 7) * 96 + (bid >> 3);
    const int j0 = (swz % 6) * 128;
    const int i0 = (swz / 6) * 64;
    const int tid = threadIdx.x;
    const int lane = tid & 63, wid = tid >> 6;
    const int wm = wid >> 1, wn = wid & 1;    // 2(M) x 2(N); wave = 32x64 output

    // staging geometry: lane covers row = base + (lane>>2), LDS slot = lane&3;
    // global slot = (lane&3) ^ ((row>>1)&3) = (lane&3) ^ ((lane>>3)&3)
    const int aRow = wid * 16 + (lane >> 2);
    const int bRow = wid * 32 + (lane >> 2);
    const int stCol = (((lane & 3) ^ ((lane >> 3) & 3)) * 8);
    const int aBase = wid * 512;
    const int bBase = wid * 1024;

    f32x4 acc[2][4] = {};

    const int lr = lane & 15;
    const int arow = wm * 32 + lr;
    const int brow = wn * 64 + lr;
    // read slot: ks ^ ((row>>1)&3); row>>1 parity key = (lr>>1)&3 for all fragment rows
    const int kbs = (((lane >> 4) ^ ((lr >> 1) & 3)) * 8);

    K7STAGE(0, 0);

    for (int t = 0; t < 24; ++t) {
        const int cur = t & 1;
        if (t < 23) {
            K7STAGE(cur ^ 1, (t + 1) * 32);
            asm volatile("s_waitcnt vmcnt(6)" ::: "memory");  // stage(t) landed; stage(t+1) in flight
        } else {
            asm volatile("s_waitcnt vmcnt(0)" ::: "memory");
        }
        __builtin_amdgcn_s_barrier();          // all waves' stage(t) visible

        bf16x8 ah[2], al[2], bh4[4], bl4[4];
        #pragma unroll
        for (int m = 0; m < 2; ++m) {
            ah[m] = *(const bf16x8*)&Ah[cur][(arow + m * 16) * 32 + kbs];
            al[m] = *(const bf16x8*)&Al[cur][(arow + m * 16) * 32 + kbs];
        }
        #pragma unroll
        for (int n = 0; n < 4; ++n) {
            bh4[n] = *(const bf16x8*)&Bh[cur][(brow + n * 16) * 32 + kbs];
            bl4[n] = *(const bf16x8*)&Bl[cur][(brow + n * 16) * 32 + kbs];
        }
        #pragma unroll
        for (int m = 0; m < 2; ++m)
            #pragma unroll
            for (int n = 0; n < 4; ++n) {
                acc[m][n] = __builtin_amdgcn_mfma_f32_16x16x32_bf16(ah[m], bh4[n], acc[m][n], 0, 0, 0);
                acc[m][n] = __builtin_amdgcn_mfma_f32_16x16x32_bf16(ah[m], bl4[n], acc[m][n], 0, 0, 0);
                acc[m][n] = __builtin_amdgcn_mfma_f32_16x16x32_bf16(al[m], bh4[n], acc[m][n], 0, 0, 0);
            }
        asm volatile("s_waitcnt lgkmcnt(0)" ::: "memory");   // this wave's ds_reads done
        __builtin_amdgcn_s_barrier();          // reads of buf[cur] complete before it is re-staged
    }

    const int ocol0 = j0 + wn * 64 + lr;
    const int orow0 = i0 + wm * 32 + (lane >> 4) * 4;
    #pragma unroll
    for (int n = 0; n < 4; ++n) {
        const float bv = bias[ocol0 + n * 16];
        #pragma unroll
        for (int m = 0; m < 2; ++m) {
            #pragma unroll
            for (int j = 0; j < 4; ++j) {
                out[(size_t)(orow0 + m * 16 + j) * ED + ocol0 + n * 16] = acc[m][n][j] + bv;
            }
        }
    }
}

extern "C" void kernel_launch(void* const* d_in, const int* in_sizes, int n_in,
                              void* d_out, int out_size, void* d_ws, size_t ws_size,
                              hipStream_t stream) {
    (void)in_sizes; (void)n_in; (void)out_size; (void)ws_size;
    const float* emb  = (const float*)d_in[0];   // [8,1024,768]
    const float* tp   = (const float*)d_in[1];   // [12,2047,64]
    const float* W    = (const float*)d_in[2];   // [768,768]
    const float* bias = (const float*)d_in[3];   // [768]

    float* out_conv = (float*)d_out;                             // 8*1024*768
    float* out_psf  = out_conv + (size_t)NB * SL * ED;           // 12*2047*64

    // workspace layout:
    float2* Pc = (float2*)d_ws;                                  // 12*33*1024 complex (dead after k3)
    float2* Pf = Pc + (size_t)NH * NF * SL;                      // 12*33*2048 complex
    float*  XcRe = (float*)(Pf + (size_t)NH * NF * NSEQ);        // 96*33*1024 f32
    float*  XcIm = XcRe + (size_t)NB * NH * NF * SL;             // 96*33*1024 f32
    ushort* Gh = (ushort*)(XcIm + (size_t)NB * NH * NF * SL);    // 8192*768 bf16
    ushort* Gl = Gh + (size_t)NB * SL * ED;                      // 8192*768 bf16
    // W hi/lo overlaid on Pc region (2.36 MB <= 3.24 MB), written after k3 consumes Pc
    ushort* Whh = (ushort*)Pc;
    ushort* Wll = Whh + (size_t)ED * ED;
    // softmax partials overlaid on Pf start (dead until k3 writes Pf)
    float* pMax = (float*)Pf;          // 12*32*64
    float* pSum = pMax + NH * 32 * 64; // 12*32*64
    float* Mf   = pSum + NH * 32 * 64; // 768
    float* Invf = Mf + NH * 64;        // 768

    k1a_partial<<<dim3(32, NH), dim3(256), 0, stream>>>(tp, pMax, pSum);
    k1b_fold<<<dim3(NH), dim3(64), 0, stream>>>(pMax, pSum, Mf, Invf);
    k1c_norm<<<dim3(32, NH), dim3(256), 0, stream>>>(tp, Mf, Invf, out_psf);
    k2_mfma<<<dim3(SL / 128, NH), dim3(256), 0, stream>>>(out_psf, Pc);
    k3_psf_fft<<<dim3(NH * NF), dim3(256), 0, stream>>>(Pc, Pf);
    k0_castW<<<dim3((ED * ED + 255) / 256), dim3(256), 0, stream>>>(W, Whh, Wll);
    k4_mfma<<<dim3(SL / 128, NB * NH), dim3(256), 0, stream>>>(emb, XcRe, XcIm);
    k5_seq_conv<<<dim3(NB * NH * NF), dim3(256), 0, stream>>>(XcRe, XcIm, Pf);
    k6_mfma<<<dim3(SL / 128, NB * NH), dim3(256), 0, stream>>>(XcRe, XcIm, Gh, Gl);
    k7_mfma<<<dim3(ED / 128, (NB * SL) / 64), dim3(256), 0, stream>>>(
        Gh, Gl, Whh, Wll, bias, out_conv);
}

// Round 10
// 113.835 us; speedup vs baseline: 1.6669x; 1.3676x over previous
//
#include <hip/hip_runtime.h>
#include <hip/hip_bf16.h>
#include <math.h>

#define NH 12
#define DH 64
#define SL 1024
#define NB 8
#define ED 768
#define NTAP 2047
#define NF 33
#define NSEQ 2048

typedef __attribute__((ext_vector_type(8))) short bf16x8;
typedef __attribute__((ext_vector_type(4))) float f32x4;

#define GLB_U32(p) ((const __attribute__((address_space(1))) unsigned int*)(p))
#define LDS_U32(p) ((__attribute__((address_space(3))) unsigned int*)(p))

__device__ __forceinline__ float2 cadd(float2 a, float2 b){ return make_float2(a.x+b.x, a.y+b.y); }
__device__ __forceinline__ float2 csub(float2 a, float2 b){ return make_float2(a.x-b.x, a.y-b.y); }
__device__ __forceinline__ float2 cmul(float2 a, float2 b){ return make_float2(a.x*b.x - a.y*b.y, a.x*b.y + a.y*b.x); }

__device__ __forceinline__ unsigned short bf16bits(float f) {
    __hip_bfloat16 hb = __float2bfloat16(f);
    return *reinterpret_cast<unsigned short*>(&hb);
}
// pack two fp32 -> two bf16 in one u32
__device__ __forceinline__ unsigned int pack2(float a, float b) {
    return (unsigned int)bf16bits(a) | ((unsigned int)bf16bits(b) << 16);
}

// ---------------- Stockham FFT pieces (N=2048 = 8*8*8*4, constant geometry) ----------------
#define FPAD(i) ((i) + ((i) >> 3))

template<int DIR>
__device__ __forceinline__ void dft4v(float2 v[4]) {
    float2 e0 = cadd(v[0], v[2]), e1 = csub(v[0], v[2]);
    float2 o0 = cadd(v[1], v[3]), o1 = csub(v[1], v[3]);
    float2 o1t = (DIR < 0) ? make_float2(o1.y, -o1.x) : make_float2(-o1.y, o1.x);
    v[0] = cadd(e0, o0);
    v[1] = cadd(e1, o1t);
    v[2] = csub(e0, o0);
    v[3] = csub(e1, o1t);
}

template<int DIR>
__device__ __forceinline__ void dft8v(float2 v[8]) {
    const float RS = 0.70710678118654752440f;
    float2 e[4] = { v[0], v[2], v[4], v[6] };
    float2 o[4] = { v[1], v[3], v[5], v[7] };
    dft4v<DIR>(e);
    dft4v<DIR>(o);
    float2 t1 = (DIR < 0) ? make_float2(RS * (o[1].x + o[1].y), RS * (o[1].y - o[1].x))
                          : make_float2(RS * (o[1].x - o[1].y), RS * (o[1].y + o[1].x));
    float2 t2 = (DIR < 0) ? make_float2(o[2].y, -o[2].x) : make_float2(-o[2].y, o[2].x);
    float2 t3 = (DIR < 0) ? make_float2(RS * (o[3].y - o[3].x), RS * (-o[3].x - o[3].y))
                          : make_float2(RS * (-o[3].x - o[3].y), RS * (o[3].x - o[3].y));
    v[0] = cadd(e[0], o[0]); v[4] = csub(e[0], o[0]);
    v[1] = cadd(e[1], t1);   v[5] = csub(e[1], t1);
    v[2] = cadd(e[2], t2);   v[6] = csub(e[2], t2);
    v[3] = cadd(e[3], t3);   v[7] = csub(e[3], t3);
}

template<int DIR, int L, int R>
__device__ __forceinline__ void fft_stage(const float* __restrict__ sr, const float* __restrict__ si,
                                          float* __restrict__ dr, float* __restrict__ di,
                                          const float2* __restrict__ twd, int tid) {
    const int T = 2048 / R;
    #pragma unroll
    for (int jj = 0; jj < T; jj += 256) {
        int j = tid + jj;
        int k = j & (L - 1);
        int blk = j / L;
        float2 v[R];
        #pragma unroll
        for (int r = 0; r < R; ++r) {
            int idx = FPAD(j + T * r);
            v[r] = make_float2(sr[idx], si[idx]);
        }
        if (L > 1) {
            const int c = 2048 / (R * L);
            float2 w1 = twd[c * k];
            if (DIR > 0) w1.y = -w1.y;
            float2 w = w1;
            v[1] = cmul(v[1], w);
            #pragma unroll
            for (int r = 2; r < R; ++r) { w = cmul(w, w1); v[r] = cmul(v[r], w); }
        }
        if (R == 8) dft8v<DIR>(v); else dft4v<DIR>(v);
        int base = blk * (R * L) + k;
        #pragma unroll
        for (int r = 0; r < R; ++r) {
            int idx = FPAD(base + L * r);
            dr[idx] = v[r].x; di[idx] = v[r].y;
        }
    }
}

// compute twiddle LUT W_2048^i (i<512) into LDS
__device__ __forceinline__ void gen_twd(float2* twd, int tid) {
    for (int i = tid; i < 512; i += 256) {
        float ang = -6.28318530717958647692f * (float)i / 2048.0f;
        twd[i] = make_float2(cosf(ang), sinf(ang));
    }
}

// ---------------- K1: 3-pass coalesced softmax over taps ----------------
__global__ void k1a_partial(const float* __restrict__ tp, float* __restrict__ pMax, float* __restrict__ pSum) {
    __shared__ float lm[4][64], ls[4][64];
    int c = blockIdx.x, h = blockIdx.y;
    int tid = threadIdx.x, w = tid >> 6, e = tid & 63;
    const float* base = tp + (size_t)h * NTAP * 64;
    float m = -1e30f, s = 0.f;
    #pragma unroll
    for (int i = 0; i < 16; ++i) {
        int row = c * 64 + w + 4 * i;
        if (row < NTAP) {
            float v = base[(size_t)row * 64 + e];
            float mn = fmaxf(m, v);
            s = s * expf(m - mn) + expf(v - mn);
            m = mn;
        }
    }
    lm[w][e] = m; ls[w][e] = s;
    __syncthreads();
    if (w == 0) {
        float M = m, S = s;
        #pragma unroll
        for (int i = 1; i < 4; ++i) {
            float mi = lm[i][e], si = ls[i][e];
            float mn = fmaxf(M, mi);
            S = S * expf(M - mn) + si * expf(mi - mn);
            M = mn;
        }
        pMax[(h * 32 + c) * 64 + e] = M;
        pSum[(h * 32 + c) * 64 + e] = S;
    }
}

__global__ void k1b_fold(const float* __restrict__ pMax, const float* __restrict__ pSum,
                         float* __restrict__ Mf, float* __restrict__ Invf) {
    int h = blockIdx.x, e = threadIdx.x;
    float M = -1e30f, S = 0.f;
    for (int c = 0; c < 32; ++c) {
        float mi = pMax[(h * 32 + c) * 64 + e], si = pSum[(h * 32 + c) * 64 + e];
        float mn = fmaxf(M, mi);
        S = S * expf(M - mn) + si * expf(mi - mn);
        M = mn;
    }
    Mf[h * 64 + e] = M;
    Invf[h * 64 + e] = 1.0f / S;
}

__global__ void k1c_norm(const float* __restrict__ tp, const float* __restrict__ Mf,
                         const float* __restrict__ Invf, float* __restrict__ psf_out) {
    int c = blockIdx.x, h = blockIdx.y;
    int tid = threadIdx.x, w = tid >> 6, e = tid & 63;
    float M = Mf[h * 64 + e], inv = Invf[h * 64 + e];
    const float* base = tp + (size_t)h * NTAP * 64;
    float* ob = psf_out + (size_t)h * NTAP * 64;
    #pragma unroll
    for (int i = 0; i < 16; ++i) {
        int row = c * 64 + w + 4 * i;
        if (row < NTAP) {
            float o = 0.f;
            if (row < SL) o = expf(base[(size_t)row * 64 + e] - M) * inv;
            ob[(size_t)row * 64 + e] = o;
        }
    }
}

// K2m: psf channel DFT-64 as single-pass bf16 MFMA.
__global__ __launch_bounds__(256) void k2_mfma(const float* __restrict__ psf, float2* __restrict__ Pc) {
    __shared__ union {
        struct { ushort EH[128][72]; ushort CH[80][72]; } s;
        float Dl[66][133];
    } u;
    const int t0 = blockIdx.x * 128;
    const int h = blockIdx.y;
    const int tid = threadIdx.x, lane = tid & 63, w = tid >> 6;

    for (int i = tid; i < 128 * 16; i += 256) {
        int r = i >> 4, q = i & 15;
        float4 v = *(const float4*)&psf[((size_t)h * NTAP + t0 + r) * 64 + q * 4];
        *(unsigned int*)&u.s.EH[r][q * 4]     = pack2(v.x, v.y);
        *(unsigned int*)&u.s.EH[r][q * 4 + 2] = pack2(v.z, v.w);
    }
    for (int i = tid; i < 80 * 32; i += 256) {
        int c = i >> 5, e2 = (i & 31) * 2;
        float v0 = 0.f, v1 = 0.f;
        if (c < 33) {
            v0 = cosf(0.09817477042468103870f * (float)((c * e2) & 63));
            v1 = cosf(0.09817477042468103870f * (float)((c * (e2 + 1)) & 63));
        } else if (c < 66) {
            v0 = -sinf(0.09817477042468103870f * (float)(((c - 33) * e2) & 63));
            v1 = -sinf(0.09817477042468103870f * (float)(((c - 33) * (e2 + 1)) & 63));
        }
        *(unsigned int*)&u.s.CH[c][e2] = pack2(v0, v1);
    }
    __syncthreads();

    f32x4 acc[2][5] = {};
    const int lr = lane & 15, lg = lane >> 4;
    #pragma unroll
    for (int ks = 0; ks < 64; ks += 32) {
        const int kg = ks + lg * 8;
        bf16x8 bh8[5];
        #pragma unroll
        for (int n = 0; n < 5; ++n) bh8[n] = *(const bf16x8*)&u.s.CH[n * 16 + lr][kg];
        #pragma unroll
        for (int m = 0; m < 2; ++m) {
            bf16x8 ah8 = *(const bf16x8*)&u.s.EH[w * 32 + m * 16 + lr][kg];
            #pragma unroll
            for (int n = 0; n < 5; ++n)
                acc[m][n] = __builtin_amdgcn_mfma_f32_16x16x32_bf16(ah8, bh8[n], acc[m][n], 0, 0, 0);
        }
    }
    __syncthreads();
    #pragma unroll
    for (int n = 0; n < 5; ++n) {
        int c = n * 16 + lr;
        if (c < 66) {
            #pragma unroll
            for (int m = 0; m < 2; ++m)
                #pragma unroll
                for (int j = 0; j < 4; ++j)
                    u.Dl[c][w * 32 + m * 16 + lg * 4 + j] = acc[m][n][j];
        }
    }
    __syncthreads();
    for (int i = tid; i < 33 * 128; i += 256) {
        int f = i >> 7, t = i & 127;
        Pc[(size_t)(h * NF + f) * SL + t0 + t] = make_float2(u.Dl[f][t], u.Dl[f + 33][t]);
    }
}

// K3: seq FFT-2048 of psf per (h,f), Stockham, natural order out.
__global__ __launch_bounds__(256) void k3_psf_fft(const float2* __restrict__ Pc, float2* __restrict__ Pf) {
    __shared__ float Ar[2304], Ai[2304], Br[2304], Bi[2304];
    __shared__ float2 twd[512];
    int h = blockIdx.x / NF, f = blockIdx.x % NF;
    int tid = threadIdx.x;
    gen_twd(twd, tid);
    const float2* src = Pc + (size_t)(h * NF + f) * SL;
    {
        float2 v[8];
        #pragma unroll
        for (int r = 0; r < 4; ++r) v[r] = src[tid + 256 * r];
        #pragma unroll
        for (int r = 4; r < 8; ++r) v[r] = make_float2(0.f, 0.f);
        dft8v<-1>(v);
        #pragma unroll
        for (int r = 0; r < 8; ++r) {
            int idx = FPAD(tid * 8 + r);
            Ar[idx] = v[r].x; Ai[idx] = v[r].y;
        }
    }
    __syncthreads();
    fft_stage<-1, 8, 8>(Ar, Ai, Br, Bi, twd, tid);  __syncthreads();
    fft_stage<-1, 64, 8>(Br, Bi, Ar, Ai, twd, tid); __syncthreads();
    float2* dst = Pf + (size_t)(h * NF + f) * NSEQ;
    #pragma unroll
    for (int jj = 0; jj < 512; jj += 256) {
        int j = tid + jj;
        float2 v[4];
        #pragma unroll
        for (int r = 0; r < 4; ++r) {
            int idx = FPAD(j + 512 * r);
            v[r] = make_float2(Ar[idx], Ai[idx]);
        }
        float2 w1 = twd[j];
        float2 w = w1;
        v[1] = cmul(v[1], w);
        w = cmul(w, w1); v[2] = cmul(v[2], w);
        w = cmul(w, w1); v[3] = cmul(v[3], w);
        dft4v<-1>(v);
        #pragma unroll
        for (int r = 0; r < 4; ++r) dst[j + 512 * r] = v[r];
    }
}

// K4m: channel DFT-64 as single-pass bf16 MFMA.
__global__ __launch_bounds__(256) void k4_mfma(const float* __restrict__ emb,
                                               float* __restrict__ XcRe, float* __restrict__ XcIm) {
    __shared__ union {
        struct { ushort EH[128][72]; ushort CH[80][72]; } s;
        float Dl[66][133];
    } u;
    const int t0 = blockIdx.x * 128;
    const int bh = blockIdx.y;
    const int b = bh / NH, h = bh % NH;
    const int tid = threadIdx.x, lane = tid & 63, w = tid >> 6;

    for (int i = tid; i < 128 * 16; i += 256) {
        int r = i >> 4, q = i & 15;
        float4 v = *(const float4*)&emb[((size_t)b * SL + t0 + r) * ED + h * 64 + q * 4];
        *(unsigned int*)&u.s.EH[r][q * 4]     = pack2(v.x, v.y);
        *(unsigned int*)&u.s.EH[r][q * 4 + 2] = pack2(v.z, v.w);
    }
    for (int i = tid; i < 80 * 32; i += 256) {
        int c = i >> 5, e2 = (i & 31) * 2;
        float v0 = 0.f, v1 = 0.f;
        if (c < 33) {
            v0 = cosf(0.09817477042468103870f * (float)((c * e2) & 63));
            v1 = cosf(0.09817477042468103870f * (float)((c * (e2 + 1)) & 63));
        } else if (c < 66) {
            v0 = -sinf(0.09817477042468103870f * (float)(((c - 33) * e2) & 63));
            v1 = -sinf(0.09817477042468103870f * (float)(((c - 33) * (e2 + 1)) & 63));
        }
        *(unsigned int*)&u.s.CH[c][e2] = pack2(v0, v1);
    }
    __syncthreads();

    f32x4 acc[2][5] = {};
    const int lr = lane & 15, lg = lane >> 4;
    #pragma unroll
    for (int ks = 0; ks < 64; ks += 32) {
        const int kg = ks + lg * 8;
        bf16x8 bh8[5];
        #pragma unroll
        for (int n = 0; n < 5; ++n) bh8[n] = *(const bf16x8*)&u.s.CH[n * 16 + lr][kg];
        #pragma unroll
        for (int m = 0; m < 2; ++m) {
            bf16x8 ah8 = *(const bf16x8*)&u.s.EH[w * 32 + m * 16 + lr][kg];
            #pragma unroll
            for (int n = 0; n < 5; ++n)
                acc[m][n] = __builtin_amdgcn_mfma_f32_16x16x32_bf16(ah8, bh8[n], acc[m][n], 0, 0, 0);
        }
    }
    __syncthreads();
    #pragma unroll
    for (int n = 0; n < 5; ++n) {
        int c = n * 16 + lr;
        if (c < 66) {
            #pragma unroll
            for (int m = 0; m < 2; ++m)
                #pragma unroll
                for (int j = 0; j < 4; ++j)
                    u.Dl[c][w * 32 + m * 16 + lg * 4 + j] = acc[m][n][j];
        }
    }
    __syncthreads();
    for (int i = tid; i < 66 * 128; i += 256) {
        int c = i >> 7, t = i & 127;
        float val = u.Dl[c][t];
        if (c < 33) XcRe[(size_t)(bh * NF + c) * SL + t0 + t] = val;
        else        XcIm[(size_t)(bh * NF + (c - 33)) * SL + t0 + t] = val;
    }
}

// K5: Stockham fwd FFT -> pointwise * Pf -> Stockham inv FFT, in-place on Xc planes.
__global__ __launch_bounds__(256) void k5_seq_conv(float* __restrict__ XcRe, float* __restrict__ XcIm,
                                                   const float2* __restrict__ Pf) {
    __shared__ float Ar[2304], Ai[2304], Br[2304], Bi[2304];
    __shared__ float2 twd[512];
    int f = blockIdx.x % NF;
    int bh = blockIdx.x / NF;
    int h = bh % NH;
    int tid = threadIdx.x;
    gen_twd(twd, tid);
    float* xre = XcRe + (size_t)(bh * NF + f) * SL;
    float* xim = XcIm + (size_t)(bh * NF + f) * SL;
    {
        float2 v[8];
        #pragma unroll
        for (int r = 0; r < 4; ++r) v[r] = make_float2(xre[tid + 256 * r], xim[tid + 256 * r]);
        #pragma unroll
        for (int r = 4; r < 8; ++r) v[r] = make_float2(0.f, 0.f);
        dft8v<-1>(v);
        #pragma unroll
        for (int r = 0; r < 8; ++r) {
            int idx = FPAD(tid * 8 + r);
            Ar[idx] = v[r].x; Ai[idx] = v[r].y;
        }
    }
    __syncthreads();
    fft_stage<-1, 8, 8>(Ar, Ai, Br, Bi, twd, tid);   __syncthreads();
    fft_stage<-1, 64, 8>(Br, Bi, Ar, Ai, twd, tid);  __syncthreads();
    fft_stage<-1, 512, 4>(Ar, Ai, Br, Bi, twd, tid); __syncthreads();
    const float2* pf = Pf + (size_t)(h * NF + f) * NSEQ;
    #pragma unroll
    for (int q = 0; q < 8; ++q) {
        int i = tid + 256 * q;
        int idx = FPAD(i);
        float2 a = make_float2(Br[idx], Bi[idx]);
        float2 p = cmul(a, pf[i]);
        Br[idx] = p.x; Bi[idx] = p.y;
    }
    __syncthreads();
    fft_stage<1, 1, 8>(Br, Bi, Ar, Ai, twd, tid);  __syncthreads();
    fft_stage<1, 8, 8>(Ar, Ai, Br, Bi, twd, tid);  __syncthreads();
    fft_stage<1, 64, 8>(Br, Bi, Ar, Ai, twd, tid); __syncthreads();
    const float sc = 1.0f / 2048.0f;
    #pragma unroll
    for (int jj = 0; jj < 512; jj += 256) {
        int j = tid + jj;
        float2 v[4];
        #pragma unroll
        for (int r = 0; r < 4; ++r) {
            int idx = FPAD(j + 512 * r);
            v[r] = make_float2(Ar[idx], Ai[idx]);
        }
        float2 w1 = twd[j];
        w1.y = -w1.y;
        float2 w = w1;
        v[1] = cmul(v[1], w);
        w = cmul(w, w1); v[2] = cmul(v[2], w);
        w = cmul(w, w1); v[3] = cmul(v[3], w);
        dft4v<1>(v);
        xre[j] = v[0].x * sc;        xim[j] = v[0].y * sc;
        xre[j + 512] = v[1].x * sc;  xim[j + 512] = v[1].y * sc;
    }
}

// K6m: inverse channel DFT-64 as single-pass bf16 MFMA + exact GELU -> Gh (bf16).
__global__ __launch_bounds__(256) void k6_mfma(const float* __restrict__ XcRe,
                                               const float* __restrict__ XcIm,
                                               ushort* __restrict__ Gh) {
    __shared__ union {
        float Y32[64][133];
        ushort CH[64][72];
    } uy;
    __shared__ ushort YH[128][72];
    const int t0 = blockIdx.x * 128;
    const int bh = blockIdx.y;
    const int b = bh / NH, h = bh % NH;
    const int tid = threadIdx.x, lane = tid & 63, w = tid >> 6;

    for (int i = tid; i < 64 * 32; i += 256) {
        int c = i >> 5, tq = i & 31;
        const float* src = (c < 33) ? XcRe + (size_t)(bh * NF + c) * SL
                                    : XcIm + (size_t)(bh * NF + (c - 32)) * SL;
        float4 v = *(const float4*)&src[t0 + tq * 4];
        uy.Y32[c][tq * 4 + 0] = v.x; uy.Y32[c][tq * 4 + 1] = v.y;
        uy.Y32[c][tq * 4 + 2] = v.z; uy.Y32[c][tq * 4 + 3] = v.w;
    }
    __syncthreads();
    for (int i = tid; i < 128 * 8; i += 256) {
        int t = i & 127, c0 = (i >> 7) * 8;
        float v[8];
        #pragma unroll
        for (int j = 0; j < 8; ++j) v[j] = uy.Y32[c0 + j][t];
        #pragma unroll
        for (int j = 0; j < 8; j += 2)
            *(unsigned int*)&YH[t][c0 + j] = pack2(v[j], v[j + 1]);
    }
    __syncthreads();
    for (int i = tid; i < 64 * 32; i += 256) {
        int e = i >> 5, c2 = (i & 31) * 2;
        float v[2];
        #pragma unroll
        for (int j = 0; j < 2; ++j) {
            int c = c2 + j;
            if (c <= 32) {
                float wt = (c == 0 || c == 32) ? (1.0f / 64.0f) : (2.0f / 64.0f);
                v[j] = wt * cosf(0.09817477042468103870f * (float)((c * e) & 63));
            } else {
                v[j] = -(2.0f / 64.0f) * sinf(0.09817477042468103870f * (float)(((c - 32) * e) & 63));
            }
        }
        *(unsigned int*)&uy.CH[e][c2] = pack2(v[0], v[1]);
    }
    __syncthreads();

    f32x4 acc[2][4] = {};
    const int lr = lane & 15, lg = lane >> 4;
    #pragma unroll
    for (int ks = 0; ks < 64; ks += 32) {
        const int kg = ks + lg * 8;
        bf16x8 bh8[4];
        #pragma unroll
        for (int n = 0; n < 4; ++n) bh8[n] = *(const bf16x8*)&uy.CH[n * 16 + lr][kg];
        #pragma unroll
        for (int m = 0; m < 2; ++m) {
            bf16x8 ah8 = *(const bf16x8*)&YH[w * 32 + m * 16 + lr][kg];
            #pragma unroll
            for (int n = 0; n < 4; ++n)
                acc[m][n] = __builtin_amdgcn_mfma_f32_16x16x32_bf16(ah8, bh8[n], acc[m][n], 0, 0, 0);
        }
    }
    #pragma unroll
    for (int n = 0; n < 4; ++n) {
        const int col = h * 64 + n * 16 + lr;
        #pragma unroll
        for (int m = 0; m < 2; ++m) {
            #pragma unroll
            for (int j = 0; j < 4; ++j) {
                int t = t0 + w * 32 + m * 16 + lg * 4 + j;
                float v = acc[m][n][j];
                float g = 0.5f * v * (1.0f + erff(v * 0.70710678118654752440f));
                Gh[((size_t)b * SL + t) * ED + col] = bf16bits(g);
            }
        }
    }
}

// K0b: cast W to bf16.
__global__ void k0_castW(const float* __restrict__ W, ushort* __restrict__ Wh) {
    int i = blockIdx.x * 256 + threadIdx.x;
    if (i < ED * ED) Wh[i] = bf16bits(W[i]);
}

// K7: projection GEMM, single-pass bf16 MFMA; 64x128 tile, BK=64, 48 KB dbuf,
// XOR bank swizzle (slot ^= row&7, source-side), counted vmcnt(6) pipeline.
#define K7STAGE(p, kk) do { \
    const ushort* gA_ = Gh + (size_t)(i0 + aRow) * ED + (kk) + stCol; \
    const ushort* gB_ = Wh + (size_t)(j0 + bRow) * ED + (kk) + stCol; \
    __builtin_amdgcn_global_load_lds(GLB_U32(gA_),           LDS_U32(&Ah[p][aBase]),        16, 0, 0); \
    __builtin_amdgcn_global_load_lds(GLB_U32(gA_ + 8 * ED),  LDS_U32(&Ah[p][aBase + 512]),  16, 0, 0); \
    __builtin_amdgcn_global_load_lds(GLB_U32(gB_),           LDS_U32(&Bh[p][bBase]),        16, 0, 0); \
    __builtin_amdgcn_global_load_lds(GLB_U32(gB_ + 8 * ED),  LDS_U32(&Bh[p][bBase + 512]),  16, 0, 0); \
    __builtin_amdgcn_global_load_lds(GLB_U32(gB_ + 16 * ED), LDS_U32(&Bh[p][bBase + 1024]), 16, 0, 0); \
    __builtin_amdgcn_global_load_lds(GLB_U32(gB_ + 24 * ED), LDS_U32(&Bh[p][bBase + 1536]), 16, 0, 0); \
} while (0)

__global__ __launch_bounds__(256) void k7_mfma(
        const ushort* __restrict__ Gh, const ushort* __restrict__ Wh,
        const float* __restrict__ bias, float* __restrict__ out) {
    __shared__ ushort Ah[2][64 * 64];    // 8 KB x2
    __shared__ ushort Bh[2][128 * 64];   // 16 KB x2 -> 48 KB total
    const int bid = blockIdx.y * gridDim.x + blockIdx.x;
    const int swz = (bid & 7) * 96 + (bid >> 3);      // 768 = 8 x 96, bijective
    const int j0 = (swz % 6) * 128;
    const int i0 = (swz / 6) * 64;
    const int tid = threadIdx.x;
    const int lane = tid & 63, wid = tid >> 6;
    const int wm = wid >> 1, wn = wid & 1;            // wave = 32x64 output

    // staging: row = base + (lane>>3); 8 lanes x16B cover a 128B row;
    // global k-chunk = (lane&7) ^ (row&7)  [row&7 == (lane>>3)&7 for all loads]
    const int aRow = wid * 16 + (lane >> 3);
    const int bRow = wid * 32 + (lane >> 3);
    const int stCol = (((lane & 7) ^ ((lane >> 3) & 7)) * 8);
    const int aBase = wid * 1024;   // 16 rows * 64
    const int bBase = wid * 2048;   // 32 rows * 64

    f32x4 acc[2][4] = {};

    const int lr = lane & 15, lg = lane >> 4;
    const int arow = wm * 32 + lr;
    const int brow = wn * 64 + lr;
    const int sw0 = ((lg ^ (lr & 7)) * 8);            // ks=0: slot lg
    const int sw1 = (((4 + lg) ^ (lr & 7)) * 8);      // ks=1: slot 4+lg

    K7STAGE(0, 0);

    for (int t = 0; t < 12; ++t) {
        const int cur = t & 1;
        if (t < 11) {
            K7STAGE(cur ^ 1, (t + 1) * 64);
            asm volatile("s_waitcnt vmcnt(6)" ::: "memory");  // stage(t) landed
        } else {
            asm volatile("s_waitcnt vmcnt(0)" ::: "memory");
        }
        __builtin_amdgcn_s_barrier();

        #pragma unroll
        for (int ks = 0; ks < 2; ++ks) {
            const int sw = ks ? sw1 : sw0;
            bf16x8 a0 = *(const bf16x8*)&Ah[cur][arow * 64 + sw];
            bf16x8 a1 = *(const bf16x8*)&Ah[cur][(arow + 16) * 64 + sw];
            bf16x8 b0 = *(const bf16x8*)&Bh[cur][brow * 64 + sw];
            bf16x8 b1 = *(const bf16x8*)&Bh[cur][(brow + 16) * 64 + sw];
            bf16x8 b2 = *(const bf16x8*)&Bh[cur][(brow + 32) * 64 + sw];
            bf16x8 b3 = *(const bf16x8*)&Bh[cur][(brow + 48) * 64 + sw];
            acc[0][0] = __builtin_amdgcn_mfma_f32_16x16x32_bf16(a0, b0, acc[0][0], 0, 0, 0);
            acc[0][1] = __builtin_amdgcn_mfma_f32_16x16x32_bf16(a0, b1, acc[0][1], 0, 0, 0);
            acc[0][2] = __builtin_amdgcn_mfma_f32_16x16x32_bf16(a0, b2, acc[0][2], 0, 0, 0);
            acc[0][3] = __builtin_amdgcn_mfma_f32_16x16x32_bf16(a0, b3, acc[0][3], 0, 0, 0);
            acc[1][0] = __builtin_amdgcn_mfma_f32_16x16x32_bf16(a1, b0, acc[1][0], 0, 0, 0);
            acc[1][1] = __builtin_amdgcn_mfma_f32_16x16x32_bf16(a1, b1, acc[1][1], 0, 0, 0);
            acc[1][2] = __builtin_amdgcn_mfma_f32_16x16x32_bf16(a1, b2, acc[1][2], 0, 0, 0);
            acc[1][3] = __builtin_amdgcn_mfma_f32_16x16x32_bf16(a1, b3, acc[1][3], 0, 0, 0);
        }
        asm volatile("s_waitcnt lgkmcnt(0)" ::: "memory");
        __builtin_amdgcn_s_barrier();
    }

    const int ocol0 = j0 + wn * 64 + lr;
    const int orow0 = i0 + wm * 32 + (lane >> 4) * 4;
    #pragma unroll
    for (int n = 0; n < 4; ++n) {
        const float bv = bias[ocol0 + n * 16];
        #pragma unroll
        for (int m = 0; m < 2; ++m) {
            #pragma unroll
            for (int j = 0; j < 4; ++j) {
                out[(size_t)(orow0 + m * 16 + j) * ED + ocol0 + n * 16] = acc[m][n][j] + bv;
            }
        }
    }
}

extern "C" void kernel_launch(void* const* d_in, const int* in_sizes, int n_in,
                              void* d_out, int out_size, void* d_ws, size_t ws_size,
                              hipStream_t stream) {
    (void)in_sizes; (void)n_in; (void)out_size; (void)ws_size;
    const float* emb  = (const float*)d_in[0];   // [8,1024,768]
    const float* tp   = (const float*)d_in[1];   // [12,2047,64]
    const float* W    = (const float*)d_in[2];   // [768,768]
    const float* bias = (const float*)d_in[3];   // [768]

    float* out_conv = (float*)d_out;                             // 8*1024*768
    float* out_psf  = out_conv + (size_t)NB * SL * ED;           // 12*2047*64

    // workspace layout:
    float2* Pc = (float2*)d_ws;                                  // 12*33*1024 complex (dead after k3)
    float2* Pf = Pc + (size_t)NH * NF * SL;                      // 12*33*2048 complex
    float*  XcRe = (float*)(Pf + (size_t)NH * NF * NSEQ);        // 96*33*1024 f32
    float*  XcIm = XcRe + (size_t)NB * NH * NF * SL;             // 96*33*1024 f32
    ushort* Gh = (ushort*)(XcIm + (size_t)NB * NH * NF * SL);    // 8192*768 bf16
    // W bf16 overlaid on Pc region (1.2 MB <= 3.24 MB), written after k2 consumes... (k3 reads Pc;
    // k0 launched after k3 to be safe)
    ushort* Whh = (ushort*)Pc;
    // softmax partials overlaid on Pf start (dead until k3 writes Pf)
    float* pMax = (float*)Pf;          // 12*32*64
    float* pSum = pMax + NH * 32 * 64; // 12*32*64
    float* Mf   = pSum + NH * 32 * 64; // 768
    float* Invf = Mf + NH * 64;        // 768

    k1a_partial<<<dim3(32, NH), dim3(256), 0, stream>>>(tp, pMax, pSum);
    k1b_fold<<<dim3(NH), dim3(64), 0, stream>>>(pMax, pSum, Mf, Invf);
    k1c_norm<<<dim3(32, NH), dim3(256), 0, stream>>>(tp, Mf, Invf, out_psf);
    k2_mfma<<<dim3(SL / 128, NH), dim3(256), 0, stream>>>(out_psf, Pc);
    k3_psf_fft<<<dim3(NH * NF), dim3(256), 0, stream>>>(Pc, Pf);
    k0_castW<<<dim3((ED * ED + 255) / 256), dim3(256), 0, stream>>>(W, Whh);
    k4_mfma<<<dim3(SL / 128, NB * NH), dim3(256), 0, stream>>>(emb, XcRe, XcIm);
    k5_seq_conv<<<dim3(NB * NH * NF), dim3(256), 0, stream>>>(XcRe, XcIm, Pf);
    k6_mfma<<<dim3(SL / 128, NB * NH), dim3(256), 0, stream>>>(XcRe, XcIm, Gh);
    k7_mfma<<<dim3(ED / 128, (NB * SL) / 64), dim3(256), 0, stream>>>(
        Gh, Whh, bias, out_conv);
}

// Round 11
// 108.330 us; speedup vs baseline: 1.7517x; 1.0508x over previous
//
#include <hip/hip_runtime.h>
#include <hip/hip_bf16.h>
#include <math.h>

#define NH 12
#define DH 64
#define SL 1024
#define NB 8
#define ED 768
#define NTAP 2047
#define NF 33
#define NSEQ 2048

typedef __attribute__((ext_vector_type(8))) short bf16x8;
typedef __attribute__((ext_vector_type(4))) float f32x4;
typedef __attribute__((ext_vector_type(4))) unsigned short ushort4v;

#define GLB_U32(p) ((const __attribute__((address_space(1))) unsigned int*)(p))
#define LDS_U32(p) ((__attribute__((address_space(3))) unsigned int*)(p))

__device__ __forceinline__ float2 cadd(float2 a, float2 b){ return make_float2(a.x+b.x, a.y+b.y); }
__device__ __forceinline__ float2 csub(float2 a, float2 b){ return make_float2(a.x-b.x, a.y-b.y); }
__device__ __forceinline__ float2 cmul(float2 a, float2 b){ return make_float2(a.x*b.x - a.y*b.y, a.x*b.y + a.y*b.x); }

__device__ __forceinline__ unsigned short bf16bits(float f) {
    __hip_bfloat16 hb = __float2bfloat16(f);
    return *reinterpret_cast<unsigned short*>(&hb);
}
__device__ __forceinline__ float bf16val(unsigned short u) {
    __hip_bfloat16 hb = *reinterpret_cast<__hip_bfloat16*>(&u);
    return __bfloat162float(hb);
}
// pack two fp32 -> two bf16 in one u32
__device__ __forceinline__ unsigned int pack2(float a, float b) {
    return (unsigned int)bf16bits(a) | ((unsigned int)bf16bits(b) << 16);
}

// ---------------- Stockham FFT pieces (N=2048 = 8*8*8*4, constant geometry) ----------------
#define FPAD(i) ((i) + ((i) >> 3))

template<int DIR>
__device__ __forceinline__ void dft4v(float2 v[4]) {
    float2 e0 = cadd(v[0], v[2]), e1 = csub(v[0], v[2]);
    float2 o0 = cadd(v[1], v[3]), o1 = csub(v[1], v[3]);
    float2 o1t = (DIR < 0) ? make_float2(o1.y, -o1.x) : make_float2(-o1.y, o1.x);
    v[0] = cadd(e0, o0);
    v[1] = cadd(e1, o1t);
    v[2] = csub(e0, o0);
    v[3] = csub(e1, o1t);
}

template<int DIR>
__device__ __forceinline__ void dft8v(float2 v[8]) {
    const float RS = 0.70710678118654752440f;
    float2 e[4] = { v[0], v[2], v[4], v[6] };
    float2 o[4] = { v[1], v[3], v[5], v[7] };
    dft4v<DIR>(e);
    dft4v<DIR>(o);
    float2 t1 = (DIR < 0) ? make_float2(RS * (o[1].x + o[1].y), RS * (o[1].y - o[1].x))
                          : make_float2(RS * (o[1].x - o[1].y), RS * (o[1].y + o[1].x));
    float2 t2 = (DIR < 0) ? make_float2(o[2].y, -o[2].x) : make_float2(-o[2].y, o[2].x);
    float2 t3 = (DIR < 0) ? make_float2(RS * (o[3].y - o[3].x), RS * (-o[3].x - o[3].y))
                          : make_float2(RS * (-o[3].x - o[3].y), RS * (o[3].x - o[3].y));
    v[0] = cadd(e[0], o[0]); v[4] = csub(e[0], o[0]);
    v[1] = cadd(e[1], t1);   v[5] = csub(e[1], t1);
    v[2] = cadd(e[2], t2);   v[6] = csub(e[2], t2);
    v[3] = cadd(e[3], t3);   v[7] = csub(e[3], t3);
}

template<int DIR, int L, int R>
__device__ __forceinline__ void fft_stage(const float* __restrict__ sr, const float* __restrict__ si,
                                          float* __restrict__ dr, float* __restrict__ di,
                                          const float2* __restrict__ twd, int tid) {
    const int T = 2048 / R;
    #pragma unroll
    for (int jj = 0; jj < T; jj += 256) {
        int j = tid + jj;
        int k = j & (L - 1);
        int blk = j / L;
        float2 v[R];
        #pragma unroll
        for (int r = 0; r < R; ++r) {
            int idx = FPAD(j + T * r);
            v[r] = make_float2(sr[idx], si[idx]);
        }
        if (L > 1) {
            const int c = 2048 / (R * L);
            float2 w1 = twd[c * k];
            if (DIR > 0) w1.y = -w1.y;
            float2 w = w1;
            v[1] = cmul(v[1], w);
            #pragma unroll
            for (int r = 2; r < R; ++r) { w = cmul(w, w1); v[r] = cmul(v[r], w); }
        }
        if (R == 8) dft8v<DIR>(v); else dft4v<DIR>(v);
        int base = blk * (R * L) + k;
        #pragma unroll
        for (int r = 0; r < R; ++r) {
            int idx = FPAD(base + L * r);
            dr[idx] = v[r].x; di[idx] = v[r].y;
        }
    }
}

// compute twiddle LUT W_2048^i (i<512) into LDS
__device__ __forceinline__ void gen_twd(float2* twd, int tid) {
    for (int i = tid; i < 512; i += 256) {
        float ang = -6.28318530717958647692f * (float)i / 2048.0f;
        twd[i] = make_float2(cosf(ang), sinf(ang));
    }
}

// ---------------- K1: coalesced softmax over taps (2 kernels) ----------------
__global__ void k1a_partial(const float* __restrict__ tp, float* __restrict__ pMax, float* __restrict__ pSum) {
    __shared__ float lm[4][64], ls[4][64];
    int c = blockIdx.x, h = blockIdx.y;
    int tid = threadIdx.x, w = tid >> 6, e = tid & 63;
    const float* base = tp + (size_t)h * NTAP * 64;
    float m = -1e30f, s = 0.f;
    #pragma unroll
    for (int i = 0; i < 16; ++i) {
        int row = c * 64 + w + 4 * i;
        if (row < NTAP) {
            float v = base[(size_t)row * 64 + e];
            float mn = fmaxf(m, v);
            s = s * expf(m - mn) + expf(v - mn);
            m = mn;
        }
    }
    lm[w][e] = m; ls[w][e] = s;
    __syncthreads();
    if (w == 0) {
        float M = m, S = s;
        #pragma unroll
        for (int i = 1; i < 4; ++i) {
            float mi = lm[i][e], si = ls[i][e];
            float mn = fmaxf(M, mi);
            S = S * expf(M - mn) + si * expf(mi - mn);
            M = mn;
        }
        pMax[(h * 32 + c) * 64 + e] = M;
        pSum[(h * 32 + c) * 64 + e] = S;
    }
}

// k1c: fold partials (redundant per block, L2-hot) + normalize + causal mask.
__global__ void k1c_norm(const float* __restrict__ tp, const float* __restrict__ pMax,
                         const float* __restrict__ pSum, float* __restrict__ psf_out) {
    __shared__ float sM[64], sI[64];
    int c = blockIdx.x, h = blockIdx.y;
    int tid = threadIdx.x, w = tid >> 6, e = tid & 63;
    if (tid < 64) {
        float M = -1e30f, S = 0.f;
        for (int cc = 0; cc < 32; ++cc) {
            float mi = pMax[(h * 32 + cc) * 64 + tid], si = pSum[(h * 32 + cc) * 64 + tid];
            float mn = fmaxf(M, mi);
            S = S * expf(M - mn) + si * expf(mi - mn);
            M = mn;
        }
        sM[tid] = M; sI[tid] = 1.0f / S;
    }
    __syncthreads();
    float M = sM[e], inv = sI[e];
    const float* base = tp + (size_t)h * NTAP * 64;
    float* ob = psf_out + (size_t)h * NTAP * 64;
    #pragma unroll
    for (int i = 0; i < 16; ++i) {
        int row = c * 64 + w + 4 * i;
        if (row < NTAP) {
            float o = 0.f;
            if (row < SL) o = expf(base[(size_t)row * 64 + e] - M) * inv;
            ob[(size_t)row * 64 + e] = o;
        }
    }
}

// K2m: psf channel DFT-64 as single-pass bf16 MFMA; Pc fp32 (read once by k3).
__global__ __launch_bounds__(256) void k2_mfma(const float* __restrict__ psf, float2* __restrict__ Pc) {
    __shared__ union {
        struct { ushort EH[128][72]; ushort CH[80][72]; } s;
        float Dl[66][133];
    } u;
    const int t0 = blockIdx.x * 128;
    const int h = blockIdx.y;
    const int tid = threadIdx.x, lane = tid & 63, w = tid >> 6;

    for (int i = tid; i < 128 * 16; i += 256) {
        int r = i >> 4, q = i & 15;
        float4 v = *(const float4*)&psf[((size_t)h * NTAP + t0 + r) * 64 + q * 4];
        *(unsigned int*)&u.s.EH[r][q * 4]     = pack2(v.x, v.y);
        *(unsigned int*)&u.s.EH[r][q * 4 + 2] = pack2(v.z, v.w);
    }
    for (int i = tid; i < 80 * 32; i += 256) {
        int c = i >> 5, e2 = (i & 31) * 2;
        float v0 = 0.f, v1 = 0.f;
        if (c < 33) {
            v0 = cosf(0.09817477042468103870f * (float)((c * e2) & 63));
            v1 = cosf(0.09817477042468103870f * (float)((c * (e2 + 1)) & 63));
        } else if (c < 66) {
            v0 = -sinf(0.09817477042468103870f * (float)(((c - 33) * e2) & 63));
            v1 = -sinf(0.09817477042468103870f * (float)(((c - 33) * (e2 + 1)) & 63));
        }
        *(unsigned int*)&u.s.CH[c][e2] = pack2(v0, v1);
    }
    __syncthreads();

    f32x4 acc[2][5] = {};
    const int lr = lane & 15, lg = lane >> 4;
    #pragma unroll
    for (int ks = 0; ks < 64; ks += 32) {
        const int kg = ks + lg * 8;
        bf16x8 bh8[5];
        #pragma unroll
        for (int n = 0; n < 5; ++n) bh8[n] = *(const bf16x8*)&u.s.CH[n * 16 + lr][kg];
        #pragma unroll
        for (int m = 0; m < 2; ++m) {
            bf16x8 ah8 = *(const bf16x8*)&u.s.EH[w * 32 + m * 16 + lr][kg];
            #pragma unroll
            for (int n = 0; n < 5; ++n)
                acc[m][n] = __builtin_amdgcn_mfma_f32_16x16x32_bf16(ah8, bh8[n], acc[m][n], 0, 0, 0);
        }
    }
    __syncthreads();
    #pragma unroll
    for (int n = 0; n < 5; ++n) {
        int c = n * 16 + lr;
        if (c < 66) {
            #pragma unroll
            for (int m = 0; m < 2; ++m)
                #pragma unroll
                for (int j = 0; j < 4; ++j)
                    u.Dl[c][w * 32 + m * 16 + lg * 4 + j] = acc[m][n][j];
        }
    }
    __syncthreads();
    for (int i = tid; i < 33 * 128; i += 256) {
        int f = i >> 7, t = i & 127;
        Pc[(size_t)(h * NF + f) * SL + t0 + t] = make_float2(u.Dl[f][t], u.Dl[f + 33][t]);
    }
}

// K3: seq FFT-2048 of psf per (h,f), Stockham, natural order; Pf packed bf16 (Re,Im).
__global__ __launch_bounds__(256) void k3_psf_fft(const float2* __restrict__ Pc, unsigned int* __restrict__ Pf) {
    __shared__ float Ar[2304], Ai[2304], Br[2304], Bi[2304];
    __shared__ float2 twd[512];
    int h = blockIdx.x / NF, f = blockIdx.x % NF;
    int tid = threadIdx.x;
    gen_twd(twd, tid);
    const float2* src = Pc + (size_t)(h * NF + f) * SL;
    {
        float2 v[8];
        #pragma unroll
        for (int r = 0; r < 4; ++r) v[r] = src[tid + 256 * r];
        #pragma unroll
        for (int r = 4; r < 8; ++r) v[r] = make_float2(0.f, 0.f);
        dft8v<-1>(v);
        #pragma unroll
        for (int r = 0; r < 8; ++r) {
            int idx = FPAD(tid * 8 + r);
            Ar[idx] = v[r].x; Ai[idx] = v[r].y;
        }
    }
    __syncthreads();
    fft_stage<-1, 8, 8>(Ar, Ai, Br, Bi, twd, tid);  __syncthreads();
    fft_stage<-1, 64, 8>(Br, Bi, Ar, Ai, twd, tid); __syncthreads();
    unsigned int* dst = Pf + (size_t)(h * NF + f) * NSEQ;
    #pragma unroll
    for (int jj = 0; jj < 512; jj += 256) {
        int j = tid + jj;
        float2 v[4];
        #pragma unroll
        for (int r = 0; r < 4; ++r) {
            int idx = FPAD(j + 512 * r);
            v[r] = make_float2(Ar[idx], Ai[idx]);
        }
        float2 w1 = twd[j];
        float2 w = w1;
        v[1] = cmul(v[1], w);
        w = cmul(w, w1); v[2] = cmul(v[2], w);
        w = cmul(w, w1); v[3] = cmul(v[3], w);
        dft4v<-1>(v);
        #pragma unroll
        for (int r = 0; r < 4; ++r) dst[j + 512 * r] = pack2(v[r].x, v[r].y);
    }
}

// K4m: channel DFT-64 as single-pass bf16 MFMA; Xc planes stored bf16.
__global__ __launch_bounds__(256) void k4_mfma(const float* __restrict__ emb,
                                               ushort* __restrict__ XcRe, ushort* __restrict__ XcIm) {
    __shared__ union {
        struct { ushort EH[128][72]; ushort CH[80][72]; } s;
        float Dl[66][133];
    } u;
    const int t0 = blockIdx.x * 128;
    const int bh = blockIdx.y;
    const int b = bh / NH, h = bh % NH;
    const int tid = threadIdx.x, lane = tid & 63, w = tid >> 6;

    for (int i = tid; i < 128 * 16; i += 256) {
        int r = i >> 4, q = i & 15;
        float4 v = *(const float4*)&emb[((size_t)b * SL + t0 + r) * ED + h * 64 + q * 4];
        *(unsigned int*)&u.s.EH[r][q * 4]     = pack2(v.x, v.y);
        *(unsigned int*)&u.s.EH[r][q * 4 + 2] = pack2(v.z, v.w);
    }
    for (int i = tid; i < 80 * 32; i += 256) {
        int c = i >> 5, e2 = (i & 31) * 2;
        float v0 = 0.f, v1 = 0.f;
        if (c < 33) {
            v0 = cosf(0.09817477042468103870f * (float)((c * e2) & 63));
            v1 = cosf(0.09817477042468103870f * (float)((c * (e2 + 1)) & 63));
        } else if (c < 66) {
            v0 = -sinf(0.09817477042468103870f * (float)(((c - 33) * e2) & 63));
            v1 = -sinf(0.09817477042468103870f * (float)(((c - 33) * (e2 + 1)) & 63));
        }
        *(unsigned int*)&u.s.CH[c][e2] = pack2(v0, v1);
    }
    __syncthreads();

    f32x4 acc[2][5] = {};
    const int lr = lane & 15, lg = lane >> 4;
    #pragma unroll
    for (int ks = 0; ks < 64; ks += 32) {
        const int kg = ks + lg * 8;
        bf16x8 bh8[5];
        #pragma unroll
        for (int n = 0; n < 5; ++n) bh8[n] = *(const bf16x8*)&u.s.CH[n * 16 + lr][kg];
        #pragma unroll
        for (int m = 0; m < 2; ++m) {
            bf16x8 ah8 = *(const bf16x8*)&u.s.EH[w * 32 + m * 16 + lr][kg];
            #pragma unroll
            for (int n = 0; n < 5; ++n)
                acc[m][n] = __builtin_amdgcn_mfma_f32_16x16x32_bf16(ah8, bh8[n], acc[m][n], 0, 0, 0);
        }
    }
    __syncthreads();
    #pragma unroll
    for (int n = 0; n < 5; ++n) {
        int c = n * 16 + lr;
        if (c < 66) {
            #pragma unroll
            for (int m = 0; m < 2; ++m)
                #pragma unroll
                for (int j = 0; j < 4; ++j)
                    u.Dl[c][w * 32 + m * 16 + lg * 4 + j] = acc[m][n][j];
        }
    }
    __syncthreads();
    for (int i = tid; i < 66 * 128; i += 256) {
        int c = i >> 7, t = i & 127;
        unsigned short val = bf16bits(u.Dl[c][t]);
        if (c < 33) XcRe[(size_t)(bh * NF + c) * SL + t0 + t] = val;
        else        XcIm[(size_t)(bh * NF + (c - 33)) * SL + t0 + t] = val;
    }
}

// K5: Stockham fwd FFT (pointwise * Pf fused into last fwd stage) -> inv FFT; Xc bf16 in/out.
__global__ __launch_bounds__(256) void k5_seq_conv(ushort* __restrict__ XcRe, ushort* __restrict__ XcIm,
                                                   const unsigned int* __restrict__ Pf) {
    __shared__ float Ar[2304], Ai[2304], Br[2304], Bi[2304];
    __shared__ float2 twd[512];
    int f = blockIdx.x % NF;
    int bh = blockIdx.x / NF;
    int h = bh % NH;
    int tid = threadIdx.x;
    gen_twd(twd, tid);
    ushort* xre = XcRe + (size_t)(bh * NF + f) * SL;
    ushort* xim = XcIm + (size_t)(bh * NF + f) * SL;
    {
        float2 v[8];
        #pragma unroll
        for (int r = 0; r < 4; ++r)
            v[r] = make_float2(bf16val(xre[tid + 256 * r]), bf16val(xim[tid + 256 * r]));
        #pragma unroll
        for (int r = 4; r < 8; ++r) v[r] = make_float2(0.f, 0.f);
        dft8v<-1>(v);
        #pragma unroll
        for (int r = 0; r < 8; ++r) {
            int idx = FPAD(tid * 8 + r);
            Ar[idx] = v[r].x; Ai[idx] = v[r].y;
        }
    }
    __syncthreads();
    fft_stage<-1, 8, 8>(Ar, Ai, Br, Bi, twd, tid);   __syncthreads();
    fft_stage<-1, 64, 8>(Br, Bi, Ar, Ai, twd, tid);  __syncthreads();
    // fwd last stage (L=512,R=4) with pointwise *Pf fused; Ar -> Br (natural-order spectrum)
    {
        const unsigned int* pf = Pf + (size_t)(h * NF + f) * NSEQ;
        #pragma unroll
        for (int jj = 0; jj < 512; jj += 256) {
            int j = tid + jj;
            float2 v[4];
            #pragma unroll
            for (int r = 0; r < 4; ++r) {
                int idx = FPAD(j + 512 * r);
                v[r] = make_float2(Ar[idx], Ai[idx]);
            }
            float2 w1 = twd[j];
            float2 w = w1;
            v[1] = cmul(v[1], w);
            w = cmul(w, w1); v[2] = cmul(v[2], w);
            w = cmul(w, w1); v[3] = cmul(v[3], w);
            dft4v<-1>(v);
            #pragma unroll
            for (int r = 0; r < 4; ++r) {
                unsigned int p = pf[j + 512 * r];
                float2 pv = make_float2(bf16val((unsigned short)(p & 0xFFFF)),
                                        bf16val((unsigned short)(p >> 16)));
                float2 m = cmul(v[r], pv);
                int idx = FPAD(j + 512 * r);
                Br[idx] = m.x; Bi[idx] = m.y;
            }
        }
    }
    __syncthreads();
    fft_stage<1, 1, 8>(Br, Bi, Ar, Ai, twd, tid);  __syncthreads();
    fft_stage<1, 8, 8>(Ar, Ai, Br, Bi, twd, tid);  __syncthreads();
    fft_stage<1, 64, 8>(Br, Bi, Ar, Ai, twd, tid); __syncthreads();
    const float sc = 1.0f / 2048.0f;
    #pragma unroll
    for (int jj = 0; jj < 512; jj += 256) {
        int j = tid + jj;
        float2 v[4];
        #pragma unroll
        for (int r = 0; r < 4; ++r) {
            int idx = FPAD(j + 512 * r);
            v[r] = make_float2(Ar[idx], Ai[idx]);
        }
        float2 w1 = twd[j];
        w1.y = -w1.y;
        float2 w = w1;
        v[1] = cmul(v[1], w);
        w = cmul(w, w1); v[2] = cmul(v[2], w);
        w = cmul(w, w1); v[3] = cmul(v[3], w);
        dft4v<1>(v);
        xre[j] = bf16bits(v[0].x * sc);        xim[j] = bf16bits(v[0].y * sc);
        xre[j + 512] = bf16bits(v[1].x * sc);  xim[j + 512] = bf16bits(v[1].y * sc);
    }
}

// K6m: inverse channel DFT-64 as single-pass bf16 MFMA + exact GELU -> Gh (bf16); Xc bf16 in.
__global__ __launch_bounds__(256) void k6_mfma(const ushort* __restrict__ XcRe,
                                               const ushort* __restrict__ XcIm,
                                               ushort* __restrict__ Gh) {
    __shared__ union {
        float Y32[64][133];
        ushort CH[64][72];
    } uy;
    __shared__ ushort YH[128][72];
    const int t0 = blockIdx.x * 128;
    const int bh = blockIdx.y;
    const int b = bh / NH, h = bh % NH;
    const int tid = threadIdx.x, lane = tid & 63, w = tid >> 6;

    for (int i = tid; i < 64 * 32; i += 256) {
        int c = i >> 5, tq = i & 31;
        const ushort* src = (c < 33) ? XcRe + (size_t)(bh * NF + c) * SL
                                     : XcIm + (size_t)(bh * NF + (c - 32)) * SL;
        ushort4v v = *(const ushort4v*)&src[t0 + tq * 4];
        uy.Y32[c][tq * 4 + 0] = bf16val(v.x); uy.Y32[c][tq * 4 + 1] = bf16val(v.y);
        uy.Y32[c][tq * 4 + 2] = bf16val(v.z); uy.Y32[c][tq * 4 + 3] = bf16val(v.w);
    }
    __syncthreads();
    for (int i = tid; i < 128 * 8; i += 256) {
        int t = i & 127, c0 = (i >> 7) * 8;
        float v[8];
        #pragma unroll
        for (int j = 0; j < 8; ++j) v[j] = uy.Y32[c0 + j][t];
        #pragma unroll
        for (int j = 0; j < 8; j += 2)
            *(unsigned int*)&YH[t][c0 + j] = pack2(v[j], v[j + 1]);
    }
    __syncthreads();
    for (int i = tid; i < 64 * 32; i += 256) {
        int e = i >> 5, c2 = (i & 31) * 2;
        float v[2];
        #pragma unroll
        for (int j = 0; j < 2; ++j) {
            int c = c2 + j;
            if (c <= 32) {
                float wt = (c == 0 || c == 32) ? (1.0f / 64.0f) : (2.0f / 64.0f);
                v[j] = wt * cosf(0.09817477042468103870f * (float)((c * e) & 63));
            } else {
                v[j] = -(2.0f / 64.0f) * sinf(0.09817477042468103870f * (float)(((c - 32) * e) & 63));
            }
        }
        *(unsigned int*)&uy.CH[e][c2] = pack2(v[0], v[1]);
    }
    __syncthreads();

    f32x4 acc[2][4] = {};
    const int lr = lane & 15, lg = lane >> 4;
    #pragma unroll
    for (int ks = 0; ks < 64; ks += 32) {
        const int kg = ks + lg * 8;
        bf16x8 bh8[4];
        #pragma unroll
        for (int n = 0; n < 4; ++n) bh8[n] = *(const bf16x8*)&uy.CH[n * 16 + lr][kg];
        #pragma unroll
        for (int m = 0; m < 2; ++m) {
            bf16x8 ah8 = *(const bf16x8*)&YH[w * 32 + m * 16 + lr][kg];
            #pragma unroll
            for (int n = 0; n < 4; ++n)
                acc[m][n] = __builtin_amdgcn_mfma_f32_16x16x32_bf16(ah8, bh8[n], acc[m][n], 0, 0, 0);
        }
    }
    #pragma unroll
    for (int n = 0; n < 4; ++n) {
        const int col = h * 64 + n * 16 + lr;
        #pragma unroll
        for (int m = 0; m < 2; ++m) {
            #pragma unroll
            for (int j = 0; j < 4; ++j) {
                int t = t0 + w * 32 + m * 16 + lg * 4 + j;
                float v = acc[m][n][j];
                float g = 0.5f * v * (1.0f + erff(v * 0.70710678118654752440f));
                Gh[((size_t)b * SL + t) * ED + col] = bf16bits(g);
            }
        }
    }
}

// K0b: cast W to bf16.
__global__ void k0_castW(const float* __restrict__ W, ushort* __restrict__ Wh) {
    int i = blockIdx.x * 256 + threadIdx.x;
    if (i < ED * ED) Wh[i] = bf16bits(W[i]);
}

// K7: projection GEMM, single-pass bf16 MFMA; 64x128 tile, BK=64, 48 KB dbuf,
// XOR bank swizzle (slot ^= row&7, source-side), counted vmcnt(6) pipeline.
#define K7STAGE(p, kk) do { \
    const ushort* gA_ = Gh + (size_t)(i0 + aRow) * ED + (kk) + stCol; \
    const ushort* gB_ = Wh + (size_t)(j0 + bRow) * ED + (kk) + stCol; \
    __builtin_amdgcn_global_load_lds(GLB_U32(gA_),           LDS_U32(&Ah[p][aBase]),        16, 0, 0); \
    __builtin_amdgcn_global_load_lds(GLB_U32(gA_ + 8 * ED),  LDS_U32(&Ah[p][aBase + 512]),  16, 0, 0); \
    __builtin_amdgcn_global_load_lds(GLB_U32(gB_),           LDS_U32(&Bh[p][bBase]),        16, 0, 0); \
    __builtin_amdgcn_global_load_lds(GLB_U32(gB_ + 8 * ED),  LDS_U32(&Bh[p][bBase + 512]),  16, 0, 0); \
    __builtin_amdgcn_global_load_lds(GLB_U32(gB_ + 16 * ED), LDS_U32(&Bh[p][bBase + 1024]), 16, 0, 0); \
    __builtin_amdgcn_global_load_lds(GLB_U32(gB_ + 24 * ED), LDS_U32(&Bh[p][bBase + 1536]), 16, 0, 0); \
} while (0)

__global__ __launch_bounds__(256) void k7_mfma(
        const ushort* __restrict__ Gh, const ushort* __restrict__ Wh,
        const float* __restrict__ bias, float* __restrict__ out) {
    __shared__ ushort Ah[2][64 * 64];    // 8 KB x2
    __shared__ ushort Bh[2][128 * 64];   // 16 KB x2 -> 48 KB total
    const int bid = blockIdx.y * gridDim.x + blockIdx.x;
    const int swz = (bid & 7) * 96 + (bid >> 3);      // 768 = 8 x 96, bijective
    const int j0 = (swz % 6) * 128;
    const int i0 = (swz / 6) * 64;
    const int tid = threadIdx.x;
    const int lane = tid & 63, wid = tid >> 6;
    const int wm = wid >> 1, wn = wid & 1;            // wave = 32x64 output

    const int aRow = wid * 16 + (lane >> 3);
    const int bRow = wid * 32 + (lane >> 3);
    const int stCol = (((lane & 7) ^ ((lane >> 3) & 7)) * 8);
    const int aBase = wid * 1024;   // 16 rows * 64
    const int bBase = wid * 2048;   // 32 rows * 64

    f32x4 acc[2][4] = {};

    const int lr = lane & 15, lg = lane >> 4;
    const int arow = wm * 32 + lr;
    const int brow = wn * 64 + lr;
    const int sw0 = ((lg ^ (lr & 7)) * 8);            // ks=0: slot lg
    const int sw1 = (((4 + lg) ^ (lr & 7)) * 8);      // ks=1: slot 4+lg

    K7STAGE(0, 0);

    for (int t = 0; t < 12; ++t) {
        const int cur = t & 1;
        if (t < 11) {
            K7STAGE(cur ^ 1, (t + 1) * 64);
            asm volatile("s_waitcnt vmcnt(6)" ::: "memory");  // stage(t) landed
        } else {
            asm volatile("s_waitcnt vmcnt(0)" ::: "memory");
        }
        __builtin_amdgcn_s_barrier();

        #pragma unroll
        for (int ks = 0; ks < 2; ++ks) {
            const int sw = ks ? sw1 : sw0;
            bf16x8 a0 = *(const bf16x8*)&Ah[cur][arow * 64 + sw];
            bf16x8 a1 = *(const bf16x8*)&Ah[cur][(arow + 16) * 64 + sw];
            bf16x8 b0 = *(const bf16x8*)&Bh[cur][brow * 64 + sw];
            bf16x8 b1 = *(const bf16x8*)&Bh[cur][(brow + 16) * 64 + sw];
            bf16x8 b2 = *(const bf16x8*)&Bh[cur][(brow + 32) * 64 + sw];
            bf16x8 b3 = *(const bf16x8*)&Bh[cur][(brow + 48) * 64 + sw];
            acc[0][0] = __builtin_amdgcn_mfma_f32_16x16x32_bf16(a0, b0, acc[0][0], 0, 0, 0);
            acc[0][1] = __builtin_amdgcn_mfma_f32_16x16x32_bf16(a0, b1, acc[0][1], 0, 0, 0);
            acc[0][2] = __builtin_amdgcn_mfma_f32_16x16x32_bf16(a0, b2, acc[0][2], 0, 0, 0);
            acc[0][3] = __builtin_amdgcn_mfma_f32_16x16x32_bf16(a0, b3, acc[0][3], 0, 0, 0);
            acc[1][0] = __builtin_amdgcn_mfma_f32_16x16x32_bf16(a1, b0, acc[1][0], 0, 0, 0);
            acc[1][1] = __builtin_amdgcn_mfma_f32_16x16x32_bf16(a1, b1, acc[1][1], 0, 0, 0);
            acc[1][2] = __builtin_amdgcn_mfma_f32_16x16x32_bf16(a1, b2, acc[1][2], 0, 0, 0);
            acc[1][3] = __builtin_amdgcn_mfma_f32_16x16x32_bf16(a1, b3, acc[1][3], 0, 0, 0);
        }
        asm volatile("s_waitcnt lgkmcnt(0)" ::: "memory");
        __builtin_amdgcn_s_barrier();
    }

    const int ocol0 = j0 + wn * 64 + lr;
    const int orow0 = i0 + wm * 32 + (lane >> 4) * 4;
    #pragma unroll
    for (int n = 0; n < 4; ++n) {
        const float bv = bias[ocol0 + n * 16];
        #pragma unroll
        for (int m = 0; m < 2; ++m) {
            #pragma unroll
            for (int j = 0; j < 4; ++j) {
                out[(size_t)(orow0 + m * 16 + j) * ED + ocol0 + n * 16] = acc[m][n][j] + bv;
            }
        }
    }
}

extern "C" void kernel_launch(void* const* d_in, const int* in_sizes, int n_in,
                              void* d_out, int out_size, void* d_ws, size_t ws_size,
                              hipStream_t stream) {
    (void)in_sizes; (void)n_in; (void)out_size; (void)ws_size;
    const float* emb  = (const float*)d_in[0];   // [8,1024,768]
    const float* tp   = (const float*)d_in[1];   // [12,2047,64]
    const float* W    = (const float*)d_in[2];   // [768,768]
    const float* bias = (const float*)d_in[3];   // [768]

    float* out_conv = (float*)d_out;                             // 8*1024*768
    float* out_psf  = out_conv + (size_t)NB * SL * ED;           // 12*2047*64

    // workspace layout:
    float2*       Pc = (float2*)d_ws;                            // 12*33*1024 complex fp32 (dead after k3)
    unsigned int* Pf = (unsigned int*)(Pc + (size_t)NH * NF * SL);  // 12*33*2048 packed bf16x2
    ushort* XcRe = (ushort*)(Pf + (size_t)NH * NF * NSEQ);       // 96*33*1024 bf16
    ushort* XcIm = XcRe + (size_t)NB * NH * NF * SL;             // 96*33*1024 bf16
    ushort* Gh   = XcIm + (size_t)NB * NH * NF * SL;             // 8192*768 bf16
    // W bf16 overlaid on Pc region (1.2 MB <= 3.24 MB), written after k3 consumes Pc
    ushort* Whh = (ushort*)Pc;
    // softmax partials overlaid on Pf start (dead until k3 writes Pf): 400 KB < 3.2 MB
    float* pMax = (float*)Pf;          // 12*32*64
    float* pSum = pMax + NH * 32 * 64; // 12*32*64

    k1a_partial<<<dim3(32, NH), dim3(256), 0, stream>>>(tp, pMax, pSum);
    k1c_norm<<<dim3(32, NH), dim3(256), 0, stream>>>(tp, pMax, pSum, out_psf);
    k2_mfma<<<dim3(SL / 128, NH), dim3(256), 0, stream>>>(out_psf, Pc);
    k3_psf_fft<<<dim3(NH * NF), dim3(256), 0, stream>>>(Pc, Pf);
    k0_castW<<<dim3((ED * ED + 255) / 256), dim3(256), 0, stream>>>(W, Whh);
    k4_mfma<<<dim3(SL / 128, NB * NH), dim3(256), 0, stream>>>(emb, XcRe, XcIm);
    k5_seq_conv<<<dim3(NB * NH * NF), dim3(256), 0, stream>>>(XcRe, XcIm, Pf);
    k6_mfma<<<dim3(SL / 128, NB * NH), dim3(256), 0, stream>>>(XcRe, XcIm, Gh);
    k7_mfma<<<dim3(ED / 128, (NB * SL) / 64), dim3(256), 0, stream>>>(
        Gh, Whh, bias, out_conv);
}

// Round 12
// 98.033 us; speedup vs baseline: 1.9356x; 1.1050x over previous
//
#include <hip/hip_runtime.h>
#include <hip/hip_bf16.h>
#include <math.h>

#define NH 12
#define DH 64
#define SL 1024
#define NB 8
#define ED 768
#define NTAP 2047
#define NF 33
#define NSEQ 2048

typedef __attribute__((ext_vector_type(8))) short bf16x8;
typedef __attribute__((ext_vector_type(4))) float f32x4;
typedef __attribute__((ext_vector_type(4))) unsigned short ushort4v;

#define GLB_U32(p) ((const __attribute__((address_space(1))) unsigned int*)(p))
#define LDS_U32(p) ((__attribute__((address_space(3))) unsigned int*)(p))

__device__ __forceinline__ float2 cadd(float2 a, float2 b){ return make_float2(a.x+b.x, a.y+b.y); }
__device__ __forceinline__ float2 csub(float2 a, float2 b){ return make_float2(a.x-b.x, a.y-b.y); }
__device__ __forceinline__ float2 cmul(float2 a, float2 b){ return make_float2(a.x*b.x - a.y*b.y, a.x*b.y + a.y*b.x); }

__device__ __forceinline__ unsigned short bf16bits(float f) {
    __hip_bfloat16 hb = __float2bfloat16(f);
    return *reinterpret_cast<unsigned short*>(&hb);
}
__device__ __forceinline__ float bf16val(unsigned short u) {
    __hip_bfloat16 hb = *reinterpret_cast<__hip_bfloat16*>(&u);
    return __bfloat162float(hb);
}
// pack two fp32 -> two bf16 in one u32
__device__ __forceinline__ unsigned int pack2(float a, float b) {
    return (unsigned int)bf16bits(a) | ((unsigned int)bf16bits(b) << 16);
}

// ---------------- Stockham FFT pieces (N=2048 = 8*8*8*4, constant geometry) ----------------
#define FPAD(i) ((i) + ((i) >> 3))

template<int DIR>
__device__ __forceinline__ void dft4v(float2 v[4]) {
    float2 e0 = cadd(v[0], v[2]), e1 = csub(v[0], v[2]);
    float2 o0 = cadd(v[1], v[3]), o1 = csub(v[1], v[3]);
    float2 o1t = (DIR < 0) ? make_float2(o1.y, -o1.x) : make_float2(-o1.y, o1.x);
    v[0] = cadd(e0, o0);
    v[1] = cadd(e1, o1t);
    v[2] = csub(e0, o0);
    v[3] = csub(e1, o1t);
}

template<int DIR>
__device__ __forceinline__ void dft8v(float2 v[8]) {
    const float RS = 0.70710678118654752440f;
    float2 e[4] = { v[0], v[2], v[4], v[6] };
    float2 o[4] = { v[1], v[3], v[5], v[7] };
    dft4v<DIR>(e);
    dft4v<DIR>(o);
    float2 t1 = (DIR < 0) ? make_float2(RS * (o[1].x + o[1].y), RS * (o[1].y - o[1].x))
                          : make_float2(RS * (o[1].x - o[1].y), RS * (o[1].y + o[1].x));
    float2 t2 = (DIR < 0) ? make_float2(o[2].y, -o[2].x) : make_float2(-o[2].y, o[2].x);
    float2 t3 = (DIR < 0) ? make_float2(RS * (o[3].y - o[3].x), RS * (-o[3].x - o[3].y))
                          : make_float2(RS * (-o[3].x - o[3].y), RS * (o[3].x - o[3].y));
    v[0] = cadd(e[0], o[0]); v[4] = csub(e[0], o[0]);
    v[1] = cadd(e[1], t1);   v[5] = csub(e[1], t1);
    v[2] = cadd(e[2], t2);   v[6] = csub(e[2], t2);
    v[3] = cadd(e[3], t3);   v[7] = csub(e[3], t3);
}

template<int DIR, int L, int R>
__device__ __forceinline__ void fft_stage(const float* __restrict__ sr, const float* __restrict__ si,
                                          float* __restrict__ dr, float* __restrict__ di,
                                          const float2* __restrict__ twd, int tid) {
    const int T = 2048 / R;
    #pragma unroll
    for (int jj = 0; jj < T; jj += 256) {
        int j = tid + jj;
        int k = j & (L - 1);
        int blk = j / L;
        float2 v[R];
        #pragma unroll
        for (int r = 0; r < R; ++r) {
            int idx = FPAD(j + T * r);
            v[r] = make_float2(sr[idx], si[idx]);
        }
        if (L > 1) {
            const int c = 2048 / (R * L);
            float2 w1 = twd[c * k];
            if (DIR > 0) w1.y = -w1.y;
            float2 w = w1;
            v[1] = cmul(v[1], w);
            #pragma unroll
            for (int r = 2; r < R; ++r) { w = cmul(w, w1); v[r] = cmul(v[r], w); }
        }
        if (R == 8) dft8v<DIR>(v); else dft4v<DIR>(v);
        int base = blk * (R * L) + k;
        #pragma unroll
        for (int r = 0; r < R; ++r) {
            int idx = FPAD(base + L * r);
            dr[idx] = v[r].x; di[idx] = v[r].y;
        }
    }
}

// compute twiddle LUT W_2048^i (i<512) into LDS
__device__ __forceinline__ void gen_twd(float2* twd, int tid) {
    for (int i = tid; i < 512; i += 256) {
        float ang = -6.28318530717958647692f * (float)i / 2048.0f;
        twd[i] = make_float2(cosf(ang), sinf(ang));
    }
}

// ---------------- K1a: softmax partial sums (M=1 fixed: tp in [0,1)) + zero-tail + castW ----
__global__ void k1a_partial(const float* __restrict__ tp, const float* __restrict__ W,
                            float* __restrict__ pSum, float* __restrict__ psf_out,
                            ushort* __restrict__ Wh) {
    __shared__ float ls[4][64];
    int c = blockIdx.x, h = blockIdx.y;
    int tid = threadIdx.x, w = tid >> 6, e = tid & 63;
    const float* base = tp + (size_t)h * NTAP * 64;
    float* ob = psf_out + (size_t)h * NTAP * 64;
    float s = 0.f;
    #pragma unroll
    for (int i = 0; i < 16; ++i) {
        int row = c * 64 + w + 4 * i;
        if (row < NTAP) {
            float v = base[(size_t)row * 64 + e];
            s += expf(v - 1.0f);
            if (row >= SL) ob[(size_t)row * 64 + e] = 0.0f;   // causal-masked tail
        }
    }
    ls[w][e] = s;
    __syncthreads();
    if (w == 0) {
        float S = s + ls[1][e] + ls[2][e] + ls[3][e];
        pSum[(h * 32 + c) * 64 + e] = S;
    }
    // castW: 384 blocks x 1536 elements cover 768*768
    int bb = h * 32 + c;
    int base_w = bb * 1536;
    #pragma unroll
    for (int i = 0; i < 6; ++i) {
        int j = base_w + tid + i * 256;
        Wh[j] = bf16bits(W[j]);
    }
}

// K2m: fold partials -> 1/S; softmax-normalize inline; write psf rows<1024; cDFT-64 MFMA -> Pc.
__global__ __launch_bounds__(256) void k2_mfma(const float* __restrict__ tp,
                                               const float* __restrict__ pSum,
                                               float* __restrict__ psf_out,
                                               float2* __restrict__ Pc) {
    __shared__ union {
        struct { ushort EH[128][72]; ushort CH[80][72]; } s;
        float Dl[66][133];
    } u;
    __shared__ float sInv[64];
    const int t0 = blockIdx.x * 128;
    const int h = blockIdx.y;
    const int tid = threadIdx.x, lane = tid & 63, w = tid >> 6;

    if (tid < 64) {
        float S = 0.f;
        #pragma unroll
        for (int cc = 0; cc < 32; ++cc) S += pSum[(h * 32 + cc) * 64 + tid];
        sInv[tid] = 1.0f / S;
    }
    __syncthreads();

    // stage: read tp rows<1024, softmax-normalize, write psf_out + pack bf16 into EH
    for (int i = tid; i < 128 * 16; i += 256) {
        int r = i >> 4, q = i & 15;
        float4 v = *(const float4*)&tp[((size_t)h * NTAP + t0 + r) * 64 + q * 4];
        float p0 = expf(v.x - 1.0f) * sInv[q * 4 + 0];
        float p1 = expf(v.y - 1.0f) * sInv[q * 4 + 1];
        float p2 = expf(v.z - 1.0f) * sInv[q * 4 + 2];
        float p3 = expf(v.w - 1.0f) * sInv[q * 4 + 3];
        *(float4*)&psf_out[((size_t)h * NTAP + t0 + r) * 64 + q * 4] = make_float4(p0, p1, p2, p3);
        *(unsigned int*)&u.s.EH[r][q * 4]     = pack2(p0, p1);
        *(unsigned int*)&u.s.EH[r][q * 4 + 2] = pack2(p2, p3);
    }
    for (int i = tid; i < 80 * 32; i += 256) {
        int c = i >> 5, e2 = (i & 31) * 2;
        float v0 = 0.f, v1 = 0.f;
        if (c < 33) {
            v0 = cosf(0.09817477042468103870f * (float)((c * e2) & 63));
            v1 = cosf(0.09817477042468103870f * (float)((c * (e2 + 1)) & 63));
        } else if (c < 66) {
            v0 = -sinf(0.09817477042468103870f * (float)(((c - 33) * e2) & 63));
            v1 = -sinf(0.09817477042468103870f * (float)(((c - 33) * (e2 + 1)) & 63));
        }
        *(unsigned int*)&u.s.CH[c][e2] = pack2(v0, v1);
    }
    __syncthreads();

    f32x4 acc[2][5] = {};
    const int lr = lane & 15, lg = lane >> 4;
    #pragma unroll
    for (int ks = 0; ks < 64; ks += 32) {
        const int kg = ks + lg * 8;
        bf16x8 bh8[5];
        #pragma unroll
        for (int n = 0; n < 5; ++n) bh8[n] = *(const bf16x8*)&u.s.CH[n * 16 + lr][kg];
        #pragma unroll
        for (int m = 0; m < 2; ++m) {
            bf16x8 ah8 = *(const bf16x8*)&u.s.EH[w * 32 + m * 16 + lr][kg];
            #pragma unroll
            for (int n = 0; n < 5; ++n)
                acc[m][n] = __builtin_amdgcn_mfma_f32_16x16x32_bf16(ah8, bh8[n], acc[m][n], 0, 0, 0);
        }
    }
    __syncthreads();
    #pragma unroll
    for (int n = 0; n < 5; ++n) {
        int c = n * 16 + lr;
        if (c < 66) {
            #pragma unroll
            for (int m = 0; m < 2; ++m)
                #pragma unroll
                for (int j = 0; j < 4; ++j)
                    u.Dl[c][w * 32 + m * 16 + lg * 4 + j] = acc[m][n][j];
        }
    }
    __syncthreads();
    for (int i = tid; i < 33 * 128; i += 256) {
        int f = i >> 7, t = i & 127;
        Pc[(size_t)(h * NF + f) * SL + t0 + t] = make_float2(u.Dl[f][t], u.Dl[f + 33][t]);
    }
}

// K3: seq FFT-2048 of psf per (h,f), Stockham, natural order; Pf packed bf16 (Re,Im).
__global__ __launch_bounds__(256) void k3_psf_fft(const float2* __restrict__ Pc, unsigned int* __restrict__ Pf) {
    __shared__ float Ar[2304], Ai[2304], Br[2304], Bi[2304];
    __shared__ float2 twd[512];
    int h = blockIdx.x / NF, f = blockIdx.x % NF;
    int tid = threadIdx.x;
    gen_twd(twd, tid);
    const float2* src = Pc + (size_t)(h * NF + f) * SL;
    {
        float2 v[8];
        #pragma unroll
        for (int r = 0; r < 4; ++r) v[r] = src[tid + 256 * r];
        #pragma unroll
        for (int r = 4; r < 8; ++r) v[r] = make_float2(0.f, 0.f);
        dft8v<-1>(v);
        #pragma unroll
        for (int r = 0; r < 8; ++r) {
            int idx = FPAD(tid * 8 + r);
            Ar[idx] = v[r].x; Ai[idx] = v[r].y;
        }
    }
    __syncthreads();
    fft_stage<-1, 8, 8>(Ar, Ai, Br, Bi, twd, tid);  __syncthreads();
    fft_stage<-1, 64, 8>(Br, Bi, Ar, Ai, twd, tid); __syncthreads();
    unsigned int* dst = Pf + (size_t)(h * NF + f) * NSEQ;
    #pragma unroll
    for (int jj = 0; jj < 512; jj += 256) {
        int j = tid + jj;
        float2 v[4];
        #pragma unroll
        for (int r = 0; r < 4; ++r) {
            int idx = FPAD(j + 512 * r);
            v[r] = make_float2(Ar[idx], Ai[idx]);
        }
        float2 w1 = twd[j];
        float2 w = w1;
        v[1] = cmul(v[1], w);
        w = cmul(w, w1); v[2] = cmul(v[2], w);
        w = cmul(w, w1); v[3] = cmul(v[3], w);
        dft4v<-1>(v);
        #pragma unroll
        for (int r = 0; r < 4; ++r) dst[j + 512 * r] = pack2(v[r].x, v[r].y);
    }
}

// K4m: channel DFT-64 as single-pass bf16 MFMA; Xc planes stored bf16.
__global__ __launch_bounds__(256) void k4_mfma(const float* __restrict__ emb,
                                               ushort* __restrict__ XcRe, ushort* __restrict__ XcIm) {
    __shared__ union {
        struct { ushort EH[128][72]; ushort CH[80][72]; } s;
        float Dl[66][133];
    } u;
    const int t0 = blockIdx.x * 128;
    const int bh = blockIdx.y;
    const int b = bh / NH, h = bh % NH;
    const int tid = threadIdx.x, lane = tid & 63, w = tid >> 6;

    for (int i = tid; i < 128 * 16; i += 256) {
        int r = i >> 4, q = i & 15;
        float4 v = *(const float4*)&emb[((size_t)b * SL + t0 + r) * ED + h * 64 + q * 4];
        *(unsigned int*)&u.s.EH[r][q * 4]     = pack2(v.x, v.y);
        *(unsigned int*)&u.s.EH[r][q * 4 + 2] = pack2(v.z, v.w);
    }
    for (int i = tid; i < 80 * 32; i += 256) {
        int c = i >> 5, e2 = (i & 31) * 2;
        float v0 = 0.f, v1 = 0.f;
        if (c < 33) {
            v0 = cosf(0.09817477042468103870f * (float)((c * e2) & 63));
            v1 = cosf(0.09817477042468103870f * (float)((c * (e2 + 1)) & 63));
        } else if (c < 66) {
            v0 = -sinf(0.09817477042468103870f * (float)(((c - 33) * e2) & 63));
            v1 = -sinf(0.09817477042468103870f * (float)(((c - 33) * (e2 + 1)) & 63));
        }
        *(unsigned int*)&u.s.CH[c][e2] = pack2(v0, v1);
    }
    __syncthreads();

    f32x4 acc[2][5] = {};
    const int lr = lane & 15, lg = lane >> 4;
    #pragma unroll
    for (int ks = 0; ks < 64; ks += 32) {
        const int kg = ks + lg * 8;
        bf16x8 bh8[5];
        #pragma unroll
        for (int n = 0; n < 5; ++n) bh8[n] = *(const bf16x8*)&u.s.CH[n * 16 + lr][kg];
        #pragma unroll
        for (int m = 0; m < 2; ++m) {
            bf16x8 ah8 = *(const bf16x8*)&u.s.EH[w * 32 + m * 16 + lr][kg];
            #pragma unroll
            for (int n = 0; n < 5; ++n)
                acc[m][n] = __builtin_amdgcn_mfma_f32_16x16x32_bf16(ah8, bh8[n], acc[m][n], 0, 0, 0);
        }
    }
    __syncthreads();
    #pragma unroll
    for (int n = 0; n < 5; ++n) {
        int c = n * 16 + lr;
        if (c < 66) {
            #pragma unroll
            for (int m = 0; m < 2; ++m)
                #pragma unroll
                for (int j = 0; j < 4; ++j)
                    u.Dl[c][w * 32 + m * 16 + lg * 4 + j] = acc[m][n][j];
        }
    }
    __syncthreads();
    for (int i = tid; i < 66 * 128; i += 256) {
        int c = i >> 7, t = i & 127;
        unsigned short val = bf16bits(u.Dl[c][t]);
        if (c < 33) XcRe[(size_t)(bh * NF + c) * SL + t0 + t] = val;
        else        XcIm[(size_t)(bh * NF + (c - 33)) * SL + t0 + t] = val;
    }
}

// K5: Stockham fwd FFT (pointwise * Pf fused into last fwd stage) -> inv FFT; Xc bf16 in/out.
__global__ __launch_bounds__(256) void k5_seq_conv(ushort* __restrict__ XcRe, ushort* __restrict__ XcIm,
                                                   const unsigned int* __restrict__ Pf) {
    __shared__ float Ar[2304], Ai[2304], Br[2304], Bi[2304];
    __shared__ float2 twd[512];
    int f = blockIdx.x % NF;
    int bh = blockIdx.x / NF;
    int h = bh % NH;
    int tid = threadIdx.x;
    gen_twd(twd, tid);
    ushort* xre = XcRe + (size_t)(bh * NF + f) * SL;
    ushort* xim = XcIm + (size_t)(bh * NF + f) * SL;
    {
        float2 v[8];
        #pragma unroll
        for (int r = 0; r < 4; ++r)
            v[r] = make_float2(bf16val(xre[tid + 256 * r]), bf16val(xim[tid + 256 * r]));
        #pragma unroll
        for (int r = 4; r < 8; ++r) v[r] = make_float2(0.f, 0.f);
        dft8v<-1>(v);
        #pragma unroll
        for (int r = 0; r < 8; ++r) {
            int idx = FPAD(tid * 8 + r);
            Ar[idx] = v[r].x; Ai[idx] = v[r].y;
        }
    }
    __syncthreads();
    fft_stage<-1, 8, 8>(Ar, Ai, Br, Bi, twd, tid);   __syncthreads();
    fft_stage<-1, 64, 8>(Br, Bi, Ar, Ai, twd, tid);  __syncthreads();
    {
        const unsigned int* pf = Pf + (size_t)(h * NF + f) * NSEQ;
        #pragma unroll
        for (int jj = 0; jj < 512; jj += 256) {
            int j = tid + jj;
            float2 v[4];
            #pragma unroll
            for (int r = 0; r < 4; ++r) {
                int idx = FPAD(j + 512 * r);
                v[r] = make_float2(Ar[idx], Ai[idx]);
            }
            float2 w1 = twd[j];
            float2 w = w1;
            v[1] = cmul(v[1], w);
            w = cmul(w, w1); v[2] = cmul(v[2], w);
            w = cmul(w, w1); v[3] = cmul(v[3], w);
            dft4v<-1>(v);
            #pragma unroll
            for (int r = 0; r < 4; ++r) {
                unsigned int p = pf[j + 512 * r];
                float2 pv = make_float2(bf16val((unsigned short)(p & 0xFFFF)),
                                        bf16val((unsigned short)(p >> 16)));
                float2 m = cmul(v[r], pv);
                int idx = FPAD(j + 512 * r);
                Br[idx] = m.x; Bi[idx] = m.y;
            }
        }
    }
    __syncthreads();
    fft_stage<1, 1, 8>(Br, Bi, Ar, Ai, twd, tid);  __syncthreads();
    fft_stage<1, 8, 8>(Ar, Ai, Br, Bi, twd, tid);  __syncthreads();
    fft_stage<1, 64, 8>(Br, Bi, Ar, Ai, twd, tid); __syncthreads();
    const float sc = 1.0f / 2048.0f;
    #pragma unroll
    for (int jj = 0; jj < 512; jj += 256) {
        int j = tid + jj;
        float2 v[4];
        #pragma unroll
        for (int r = 0; r < 4; ++r) {
            int idx = FPAD(j + 512 * r);
            v[r] = make_float2(Ar[idx], Ai[idx]);
        }
        float2 w1 = twd[j];
        w1.y = -w1.y;
        float2 w = w1;
        v[1] = cmul(v[1], w);
        w = cmul(w, w1); v[2] = cmul(v[2], w);
        w = cmul(w, w1); v[3] = cmul(v[3], w);
        dft4v<1>(v);
        xre[j] = bf16bits(v[0].x * sc);        xim[j] = bf16bits(v[0].y * sc);
        xre[j + 512] = bf16bits(v[1].x * sc);  xim[j + 512] = bf16bits(v[1].y * sc);
    }
}

// K6m: inverse channel DFT-64 as single-pass bf16 MFMA + exact GELU -> Gh (bf16); Xc bf16 in.
__global__ __launch_bounds__(256) void k6_mfma(const ushort* __restrict__ XcRe,
                                               const ushort* __restrict__ XcIm,
                                               ushort* __restrict__ Gh) {
    __shared__ union {
        float Y32[64][133];
        ushort CH[64][72];
    } uy;
    __shared__ ushort YH[128][72];
    const int t0 = blockIdx.x * 128;
    const int bh = blockIdx.y;
    const int b = bh / NH, h = bh % NH;
    const int tid = threadIdx.x, lane = tid & 63, w = tid >> 6;

    for (int i = tid; i < 64 * 32; i += 256) {
        int c = i >> 5, tq = i & 31;
        const ushort* src = (c < 33) ? XcRe + (size_t)(bh * NF + c) * SL
                                     : XcIm + (size_t)(bh * NF + (c - 32)) * SL;
        ushort4v v = *(const ushort4v*)&src[t0 + tq * 4];
        uy.Y32[c][tq * 4 + 0] = bf16val(v.x); uy.Y32[c][tq * 4 + 1] = bf16val(v.y);
        uy.Y32[c][tq * 4 + 2] = bf16val(v.z); uy.Y32[c][tq * 4 + 3] = bf16val(v.w);
    }
    __syncthreads();
    for (int i = tid; i < 128 * 8; i += 256) {
        int t = i & 127, c0 = (i >> 7) * 8;
        float v[8];
        #pragma unroll
        for (int j = 0; j < 8; ++j) v[j] = uy.Y32[c0 + j][t];
        #pragma unroll
        for (int j = 0; j < 8; j += 2)
            *(unsigned int*)&YH[t][c0 + j] = pack2(v[j], v[j + 1]);
    }
    __syncthreads();
    for (int i = tid; i < 64 * 32; i += 256) {
        int e = i >> 5, c2 = (i & 31) * 2;
        float v[2];
        #pragma unroll
        for (int j = 0; j < 2; ++j) {
            int c = c2 + j;
            if (c <= 32) {
                float wt = (c == 0 || c == 32) ? (1.0f / 64.0f) : (2.0f / 64.0f);
                v[j] = wt * cosf(0.09817477042468103870f * (float)((c * e) & 63));
            } else {
                v[j] = -(2.0f / 64.0f) * sinf(0.09817477042468103870f * (float)(((c - 32) * e) & 63));
            }
        }
        *(unsigned int*)&uy.CH[e][c2] = pack2(v[0], v[1]);
    }
    __syncthreads();

    f32x4 acc[2][4] = {};
    const int lr = lane & 15, lg = lane >> 4;
    #pragma unroll
    for (int ks = 0; ks < 64; ks += 32) {
        const int kg = ks + lg * 8;
        bf16x8 bh8[4];
        #pragma unroll
        for (int n = 0; n < 4; ++n) bh8[n] = *(const bf16x8*)&uy.CH[n * 16 + lr][kg];
        #pragma unroll
        for (int m = 0; m < 2; ++m) {
            bf16x8 ah8 = *(const bf16x8*)&YH[w * 32 + m * 16 + lr][kg];
            #pragma unroll
            for (int n = 0; n < 4; ++n)
                acc[m][n] = __builtin_amdgcn_mfma_f32_16x16x32_bf16(ah8, bh8[n], acc[m][n], 0, 0, 0);
        }
    }
    #pragma unroll
    for (int n = 0; n < 4; ++n) {
        const int col = h * 64 + n * 16 + lr;
        #pragma unroll
        for (int m = 0; m < 2; ++m) {
            #pragma unroll
            for (int j = 0; j < 4; ++j) {
                int t = t0 + w * 32 + m * 16 + lg * 4 + j;
                float v = acc[m][n][j];
                float g = 0.5f * v * (1.0f + erff(v * 0.70710678118654752440f));
                Gh[((size_t)b * SL + t) * ED + col] = bf16bits(g);
            }
        }
    }
}

// K7: projection GEMM, single-pass bf16 MFMA; 64x128 tile, BK=64, 48 KB dbuf,
// XOR bank swizzle (slot ^= row&7, source-side), counted vmcnt(6) pipeline.
#define K7STAGE(p, kk) do { \
    const ushort* gA_ = Gh + (size_t)(i0 + aRow) * ED + (kk) + stCol; \
    const ushort* gB_ = Wh + (size_t)(j0 + bRow) * ED + (kk) + stCol; \
    __builtin_amdgcn_global_load_lds(GLB_U32(gA_),           LDS_U32(&Ah[p][aBase]),        16, 0, 0); \
    __builtin_amdgcn_global_load_lds(GLB_U32(gA_ + 8 * ED),  LDS_U32(&Ah[p][aBase + 512]),  16, 0, 0); \
    __builtin_amdgcn_global_load_lds(GLB_U32(gB_),           LDS_U32(&Bh[p][bBase]),        16, 0, 0); \
    __builtin_amdgcn_global_load_lds(GLB_U32(gB_ + 8 * ED),  LDS_U32(&Bh[p][bBase + 512]),  16, 0, 0); \
    __builtin_amdgcn_global_load_lds(GLB_U32(gB_ + 16 * ED), LDS_U32(&Bh[p][bBase + 1024]), 16, 0, 0); \
    __builtin_amdgcn_global_load_lds(GLB_U32(gB_ + 24 * ED), LDS_U32(&Bh[p][bBase + 1536]), 16, 0, 0); \
} while (0)

__global__ __launch_bounds__(256) void k7_mfma(
        const ushort* __restrict__ Gh, const ushort* __restrict__ Wh,
        const float* __restrict__ bias, float* __restrict__ out) {
    __shared__ ushort Ah[2][64 * 64];    // 8 KB x2
    __shared__ ushort Bh[2][128 * 64];   // 16 KB x2 -> 48 KB total
    const int bid = blockIdx.y * gridDim.x + blockIdx.x;
    const int swz = (bid & 7) * 96 + (bid >> 3);      // 768 = 8 x 96, bijective
    const int j0 = (swz % 6) * 128;
    const int i0 = (swz / 6) * 64;
    const int tid = threadIdx.x;
    const int lane = tid & 63, wid = tid >> 6;
    const int wm = wid >> 1, wn = wid & 1;            // wave = 32x64 output

    const int aRow = wid * 16 + (lane >> 3);
    const int bRow = wid * 32 + (lane >> 3);
    const int stCol = (((lane & 7) ^ ((lane >> 3) & 7)) * 8);
    const int aBase = wid * 1024;   // 16 rows * 64
    const int bBase = wid * 2048;   // 32 rows * 64

    f32x4 acc[2][4] = {};

    const int lr = lane & 15, lg = lane >> 4;
    const int arow = wm * 32 + lr;
    const int brow = wn * 64 + lr;
    const int sw0 = ((lg ^ (lr & 7)) * 8);            // ks=0: slot lg
    const int sw1 = (((4 + lg) ^ (lr & 7)) * 8);      // ks=1: slot 4+lg

    K7STAGE(0, 0);

    for (int t = 0; t < 12; ++t) {
        const int cur = t & 1;
        if (t < 11) {
            K7STAGE(cur ^ 1, (t + 1) * 64);
            asm volatile("s_waitcnt vmcnt(6)" ::: "memory");  // stage(t) landed
        } else {
            asm volatile("s_waitcnt vmcnt(0)" ::: "memory");
        }
        __builtin_amdgcn_s_barrier();

        #pragma unroll
        for (int ks = 0; ks < 2; ++ks) {
            const int sw = ks ? sw1 : sw0;
            bf16x8 a0 = *(const bf16x8*)&Ah[cur][arow * 64 + sw];
            bf16x8 a1 = *(const bf16x8*)&Ah[cur][(arow + 16) * 64 + sw];
            bf16x8 b0 = *(const bf16x8*)&Bh[cur][brow * 64 + sw];
            bf16x8 b1 = *(const bf16x8*)&Bh[cur][(brow + 16) * 64 + sw];
            bf16x8 b2 = *(const bf16x8*)&Bh[cur][(brow + 32) * 64 + sw];
            bf16x8 b3 = *(const bf16x8*)&Bh[cur][(brow + 48) * 64 + sw];
            acc[0][0] = __builtin_amdgcn_mfma_f32_16x16x32_bf16(a0, b0, acc[0][0], 0, 0, 0);
            acc[0][1] = __builtin_amdgcn_mfma_f32_16x16x32_bf16(a0, b1, acc[0][1], 0, 0, 0);
            acc[0][2] = __builtin_amdgcn_mfma_f32_16x16x32_bf16(a0, b2, acc[0][2], 0, 0, 0);
            acc[0][3] = __builtin_amdgcn_mfma_f32_16x16x32_bf16(a0, b3, acc[0][3], 0, 0, 0);
            acc[1][0] = __builtin_amdgcn_mfma_f32_16x16x32_bf16(a1, b0, acc[1][0], 0, 0, 0);
            acc[1][1] = __builtin_amdgcn_mfma_f32_16x16x32_bf16(a1, b1, acc[1][1], 0, 0, 0);
            acc[1][2] = __builtin_amdgcn_mfma_f32_16x16x32_bf16(a1, b2, acc[1][2], 0, 0, 0);
            acc[1][3] = __builtin_amdgcn_mfma_f32_16x16x32_bf16(a1, b3, acc[1][3], 0, 0, 0);
        }
        asm volatile("s_waitcnt lgkmcnt(0)" ::: "memory");
        __builtin_amdgcn_s_barrier();
    }

    const int ocol0 = j0 + wn * 64 + lr;
    const int orow0 = i0 + wm * 32 + (lane >> 4) * 4;
    #pragma unroll
    for (int n = 0; n < 4; ++n) {
        const float bv = bias[ocol0 + n * 16];
        #pragma unroll
        for (int m = 0; m < 2; ++m) {
            #pragma unroll
            for (int j = 0; j < 4; ++j) {
                out[(size_t)(orow0 + m * 16 + j) * ED + ocol0 + n * 16] = acc[m][n][j] + bv;
            }
        }
    }
}

extern "C" void kernel_launch(void* const* d_in, const int* in_sizes, int n_in,
                              void* d_out, int out_size, void* d_ws, size_t ws_size,
                              hipStream_t stream) {
    (void)in_sizes; (void)n_in; (void)out_size; (void)ws_size;
    const float* emb  = (const float*)d_in[0];   // [8,1024,768]
    const float* tp   = (const float*)d_in[1];   // [12,2047,64]
    const float* W    = (const float*)d_in[2];   // [768,768]
    const float* bias = (const float*)d_in[3];   // [768]

    float* out_conv = (float*)d_out;                             // 8*1024*768
    float* out_psf  = out_conv + (size_t)NB * SL * ED;           // 12*2047*64

    // workspace layout:
    float2*       Pc = (float2*)d_ws;                            // 12*33*1024 complex fp32 (dead after k3)
    unsigned int* Pf = (unsigned int*)(Pc + (size_t)NH * NF * SL);  // 12*33*2048 packed bf16x2
    ushort* XcRe = (ushort*)(Pf + (size_t)NH * NF * NSEQ);       // 96*33*1024 bf16
    ushort* XcIm = XcRe + (size_t)NB * NH * NF * SL;             // 96*33*1024 bf16
    ushort* Gh   = XcIm + (size_t)NB * NH * NF * SL;             // 8192*768 bf16
    ushort* Whh  = Gh + (size_t)NB * SL * ED;                    // 768*768 bf16 (no overlay)
    // softmax partial sums overlaid on Pf start (dead until k3 writes Pf): 98 KB < 3.2 MB
    float* pSum = (float*)Pf;          // 12*32*64

    k1a_partial<<<dim3(32, NH), dim3(256), 0, stream>>>(tp, W, pSum, out_psf, Whh);
    k2_mfma<<<dim3(SL / 128, NH), dim3(256), 0, stream>>>(tp, pSum, out_psf, Pc);
    k3_psf_fft<<<dim3(NH * NF), dim3(256), 0, stream>>>(Pc, Pf);
    k4_mfma<<<dim3(SL / 128, NB * NH), dim3(256), 0, stream>>>(emb, XcRe, XcIm);
    k5_seq_conv<<<dim3(NB * NH * NF), dim3(256), 0, stream>>>(XcRe, XcIm, Pf);
    k6_mfma<<<dim3(SL / 128, NB * NH), dim3(256), 0, stream>>>(XcRe, XcIm, Gh);
    k7_mfma<<<dim3(ED / 128, (NB * SL) / 64), dim3(256), 0, stream>>>(
        Gh, Whh, bias, out_conv);
}

// Round 13
// 89.454 us; speedup vs baseline: 2.1213x; 1.0959x over previous
//
#include <hip/hip_runtime.h>
#include <hip/hip_bf16.h>
#include <hip/hip_fp16.h>
#include <math.h>

#define NH 12
#define DH 64
#define SL 1024
#define NB 8
#define ED 768
#define NTAP 2047
#define NF 33
#define NSEQ 2048

typedef __attribute__((ext_vector_type(8))) short bf16x8;
typedef __attribute__((ext_vector_type(4))) float f32x4;
typedef __attribute__((ext_vector_type(4))) unsigned short ushort4v;

#define GLB_U32(p) ((const __attribute__((address_space(1))) unsigned int*)(p))
#define LDS_U32(p) ((__attribute__((address_space(3))) unsigned int*)(p))

__device__ __forceinline__ float2 cadd(float2 a, float2 b){ return make_float2(a.x+b.x, a.y+b.y); }
__device__ __forceinline__ float2 csub(float2 a, float2 b){ return make_float2(a.x-b.x, a.y-b.y); }
__device__ __forceinline__ float2 cmul(float2 a, float2 b){ return make_float2(a.x*b.x - a.y*b.y, a.x*b.y + a.y*b.x); }

__device__ __forceinline__ unsigned short bf16bits(float f) {
    __hip_bfloat16 hb = __float2bfloat16(f);
    return *reinterpret_cast<unsigned short*>(&hb);
}
__device__ __forceinline__ float bf16val(unsigned short u) {
    __hip_bfloat16 hb = *reinterpret_cast<__hip_bfloat16*>(&u);
    return __bfloat162float(hb);
}
__device__ __forceinline__ unsigned int pack2(float a, float b) {
    return (unsigned int)bf16bits(a) | ((unsigned int)bf16bits(b) << 16);
}
// fp16 packed-complex helpers (one u32 = half Re | half Im)
__device__ __forceinline__ unsigned short h16(float f) {
    __half h = __float2half_rn(f);
    return *reinterpret_cast<unsigned short*>(&h);
}
__device__ __forceinline__ float h2f(unsigned short u) {
    __half h = *reinterpret_cast<__half*>(&u);
    return __half2float(h);
}
__device__ __forceinline__ unsigned int hpk(float2 v) {
    return (unsigned int)h16(v.x) | ((unsigned int)h16(v.y) << 16);
}
__device__ __forceinline__ float2 hup(unsigned int u) {
    return make_float2(h2f((unsigned short)(u & 0xFFFF)), h2f((unsigned short)(u >> 16)));
}

// ---------------- Stockham FFT pieces (N=2048 = 8*8*8*4, constant geometry) ----------------
#define FPAD(i) ((i) + ((i) >> 3))

template<int DIR>
__device__ __forceinline__ void dft4v(float2 v[4]) {
    float2 e0 = cadd(v[0], v[2]), e1 = csub(v[0], v[2]);
    float2 o0 = cadd(v[1], v[3]), o1 = csub(v[1], v[3]);
    float2 o1t = (DIR < 0) ? make_float2(o1.y, -o1.x) : make_float2(-o1.y, o1.x);
    v[0] = cadd(e0, o0);
    v[1] = cadd(e1, o1t);
    v[2] = csub(e0, o0);
    v[3] = csub(e1, o1t);
}

template<int DIR>
__device__ __forceinline__ void dft8v(float2 v[8]) {
    const float RS = 0.70710678118654752440f;
    float2 e[4] = { v[0], v[2], v[4], v[6] };
    float2 o[4] = { v[1], v[3], v[5], v[7] };
    dft4v<DIR>(e);
    dft4v<DIR>(o);
    float2 t1 = (DIR < 0) ? make_float2(RS * (o[1].x + o[1].y), RS * (o[1].y - o[1].x))
                          : make_float2(RS * (o[1].x - o[1].y), RS * (o[1].y + o[1].x));
    float2 t2 = (DIR < 0) ? make_float2(o[2].y, -o[2].x) : make_float2(-o[2].y, o[2].x);
    float2 t3 = (DIR < 0) ? make_float2(RS * (o[3].y - o[3].x), RS * (-o[3].x - o[3].y))
                          : make_float2(RS * (-o[3].x - o[3].y), RS * (o[3].x - o[3].y));
    v[0] = cadd(e[0], o[0]); v[4] = csub(e[0], o[0]);
    v[1] = cadd(e[1], t1);   v[5] = csub(e[1], t1);
    v[2] = cadd(e[2], t2);   v[6] = csub(e[2], t2);
    v[3] = cadd(e[3], t3);   v[7] = csub(e[3], t3);
}

// packed-fp16 Stockham stage: src/dst are u32 LDS arrays of packed complex
template<int DIR, int L, int R>
__device__ __forceinline__ void fft_stage_h(const unsigned int* __restrict__ s,
                                            unsigned int* __restrict__ d,
                                            const float2* __restrict__ twd, int tid) {
    const int T = 2048 / R;
    #pragma unroll
    for (int jj = 0; jj < T; jj += 256) {
        int j = tid + jj;
        int k = j & (L - 1);
        int blk = j / L;
        float2 v[R];
        #pragma unroll
        for (int r = 0; r < R; ++r) v[r] = hup(s[FPAD(j + T * r)]);
        if (L > 1) {
            const int c = 2048 / (R * L);
            float2 w1 = twd[c * k];
            if (DIR > 0) w1.y = -w1.y;
            float2 w = w1;
            v[1] = cmul(v[1], w);
            #pragma unroll
            for (int r = 2; r < R; ++r) { w = cmul(w, w1); v[r] = cmul(v[r], w); }
        }
        if (R == 8) dft8v<DIR>(v); else dft4v<DIR>(v);
        int base = blk * (R * L) + k;
        #pragma unroll
        for (int r = 0; r < R; ++r) d[FPAD(base + L * r)] = hpk(v[r]);
    }
}

// compute twiddle LUT W_2048^i (i<512) into LDS
__device__ __forceinline__ void gen_twd(float2* twd, int tid) {
    for (int i = tid; i < 512; i += 256) {
        float ang = -6.28318530717958647692f * (float)i / 2048.0f;
        twd[i] = make_float2(cosf(ang), sinf(ang));
    }
}

// ---------------- K4fat: emb channel DFT-64 (768 blocks) + k1a softmax-partials/castW (384) ----
__global__ __launch_bounds__(256) void k4_fat(const float* __restrict__ emb,
                                              const float* __restrict__ tp,
                                              const float* __restrict__ W,
                                              float* __restrict__ pSum,
                                              float* __restrict__ psf_out,
                                              ushort* __restrict__ Wh,
                                              ushort* __restrict__ XcRe, ushort* __restrict__ XcIm) {
    __shared__ union {
        struct { ushort EH[128][72]; ushort CH[80][72]; } s;
        float Dl[66][133];
    } u;
    __shared__ float ls[4][64];
    const int tid = threadIdx.x, lane = tid & 63, w = tid >> 6;

    if (blockIdx.x >= 768) {
        // ---- k1a branch: softmax partial sums (M=1 fixed: tp in [0,1)) + zero tail + castW ----
        int idx = blockIdx.x - 768;           // 0..383
        int c = idx & 31, h = idx >> 5;
        const float* base = tp + (size_t)h * NTAP * 64;
        float* ob = psf_out + (size_t)h * NTAP * 64;
        int e = lane;
        float s = 0.f;
        #pragma unroll
        for (int i = 0; i < 16; ++i) {
            int row = c * 64 + w + 4 * i;
            if (row < NTAP) {
                float v = base[(size_t)row * 64 + e];
                s += expf(v - 1.0f);
                if (row >= SL) ob[(size_t)row * 64 + e] = 0.0f;
            }
        }
        ls[w][e] = s;
        __syncthreads();
        if (w == 0) {
            float S = s + ls[1][e] + ls[2][e] + ls[3][e];
            pSum[(h * 32 + c) * 64 + e] = S;
        }
        int base_w = idx * 1536;
        #pragma unroll
        for (int i = 0; i < 6; ++i) {
            int j = base_w + tid + i * 256;
            Wh[j] = bf16bits(W[j]);
        }
        return;
    }

    // ---- k4 branch: channel DFT-64 as single-pass bf16 MFMA; Xc planes bf16 ----
    const int t0 = (blockIdx.x & 7) * 128;
    const int bh = blockIdx.x >> 3;
    const int b = bh / NH, h = bh % NH;

    for (int i = tid; i < 128 * 16; i += 256) {
        int r = i >> 4, q = i & 15;
        float4 v = *(const float4*)&emb[((size_t)b * SL + t0 + r) * ED + h * 64 + q * 4];
        *(unsigned int*)&u.s.EH[r][q * 4]     = pack2(v.x, v.y);
        *(unsigned int*)&u.s.EH[r][q * 4 + 2] = pack2(v.z, v.w);
    }
    for (int i = tid; i < 80 * 32; i += 256) {
        int c = i >> 5, e2 = (i & 31) * 2;
        float v0 = 0.f, v1 = 0.f;
        if (c < 33) {
            v0 = cosf(0.09817477042468103870f * (float)((c * e2) & 63));
            v1 = cosf(0.09817477042468103870f * (float)((c * (e2 + 1)) & 63));
        } else if (c < 66) {
            v0 = -sinf(0.09817477042468103870f * (float)(((c - 33) * e2) & 63));
            v1 = -sinf(0.09817477042468103870f * (float)(((c - 33) * (e2 + 1)) & 63));
        }
        *(unsigned int*)&u.s.CH[c][e2] = pack2(v0, v1);
    }
    __syncthreads();

    f32x4 acc[2][5] = {};
    const int lr = lane & 15, lg = lane >> 4;
    #pragma unroll
    for (int ks = 0; ks < 64; ks += 32) {
        const int kg = ks + lg * 8;
        bf16x8 bh8[5];
        #pragma unroll
        for (int n = 0; n < 5; ++n) bh8[n] = *(const bf16x8*)&u.s.CH[n * 16 + lr][kg];
        #pragma unroll
        for (int m = 0; m < 2; ++m) {
            bf16x8 ah8 = *(const bf16x8*)&u.s.EH[w * 32 + m * 16 + lr][kg];
            #pragma unroll
            for (int n = 0; n < 5; ++n)
                acc[m][n] = __builtin_amdgcn_mfma_f32_16x16x32_bf16(ah8, bh8[n], acc[m][n], 0, 0, 0);
        }
    }
    __syncthreads();
    #pragma unroll
    for (int n = 0; n < 5; ++n) {
        int c = n * 16 + lr;
        if (c < 66) {
            #pragma unroll
            for (int m = 0; m < 2; ++m)
                #pragma unroll
                for (int j = 0; j < 4; ++j)
                    u.Dl[c][w * 32 + m * 16 + lg * 4 + j] = acc[m][n][j];
        }
    }
    __syncthreads();
    for (int i = tid; i < 66 * 128; i += 256) {
        int c = i >> 7, t = i & 127;
        unsigned short val = bf16bits(u.Dl[c][t]);
        if (c < 33) XcRe[(size_t)(bh * NF + c) * SL + t0 + t] = val;
        else        XcIm[(size_t)(bh * NF + (c - 33)) * SL + t0 + t] = val;
    }
}

// K2m: fold partials -> 1/S; softmax-normalize inline; write psf rows<1024; cDFT-64 MFMA -> Pc.
// 64-row tiles (192 blocks).
__global__ __launch_bounds__(256) void k2_mfma(const float* __restrict__ tp,
                                               const float* __restrict__ pSum,
                                               float* __restrict__ psf_out,
                                               float2* __restrict__ Pc) {
    __shared__ union {
        struct { ushort EH[64][72]; ushort CH[80][72]; } s;
        float Dl[66][72];
    } u;
    __shared__ float sInv[64];
    const int t0 = blockIdx.x * 64;
    const int h = blockIdx.y;
    const int tid = threadIdx.x, lane = tid & 63, w = tid >> 6;

    if (tid < 64) {
        float S = 0.f;
        #pragma unroll
        for (int cc = 0; cc < 32; ++cc) S += pSum[(h * 32 + cc) * 64 + tid];
        sInv[tid] = 1.0f / S;
    }
    __syncthreads();

    for (int i = tid; i < 64 * 16; i += 256) {
        int r = i >> 4, q = i & 15;
        float4 v = *(const float4*)&tp[((size_t)h * NTAP + t0 + r) * 64 + q * 4];
        float p0 = expf(v.x - 1.0f) * sInv[q * 4 + 0];
        float p1 = expf(v.y - 1.0f) * sInv[q * 4 + 1];
        float p2 = expf(v.z - 1.0f) * sInv[q * 4 + 2];
        float p3 = expf(v.w - 1.0f) * sInv[q * 4 + 3];
        *(float4*)&psf_out[((size_t)h * NTAP + t0 + r) * 64 + q * 4] = make_float4(p0, p1, p2, p3);
        *(unsigned int*)&u.s.EH[r][q * 4]     = pack2(p0, p1);
        *(unsigned int*)&u.s.EH[r][q * 4 + 2] = pack2(p2, p3);
    }
    for (int i = tid; i < 80 * 32; i += 256) {
        int c = i >> 5, e2 = (i & 31) * 2;
        float v0 = 0.f, v1 = 0.f;
        if (c < 33) {
            v0 = cosf(0.09817477042468103870f * (float)((c * e2) & 63));
            v1 = cosf(0.09817477042468103870f * (float)((c * (e2 + 1)) & 63));
        } else if (c < 66) {
            v0 = -sinf(0.09817477042468103870f * (float)(((c - 33) * e2) & 63));
            v1 = -sinf(0.09817477042468103870f * (float)(((c - 33) * (e2 + 1)) & 63));
        }
        *(unsigned int*)&u.s.CH[c][e2] = pack2(v0, v1);
    }
    __syncthreads();

    f32x4 acc[5] = {};
    const int lr = lane & 15, lg = lane >> 4;
    #pragma unroll
    for (int ks = 0; ks < 64; ks += 32) {
        const int kg = ks + lg * 8;
        bf16x8 bh8[5];
        #pragma unroll
        for (int n = 0; n < 5; ++n) bh8[n] = *(const bf16x8*)&u.s.CH[n * 16 + lr][kg];
        bf16x8 ah8 = *(const bf16x8*)&u.s.EH[w * 16 + lr][kg];
        #pragma unroll
        for (int n = 0; n < 5; ++n)
            acc[n] = __builtin_amdgcn_mfma_f32_16x16x32_bf16(ah8, bh8[n], acc[n], 0, 0, 0);
    }
    __syncthreads();
    #pragma unroll
    for (int n = 0; n < 5; ++n) {
        int c = n * 16 + lr;
        if (c < 66) {
            #pragma unroll
            for (int j = 0; j < 4; ++j)
                u.Dl[c][w * 16 + lg * 4 + j] = acc[n][j];
        }
    }
    __syncthreads();
    for (int i = tid; i < 33 * 64; i += 256) {
        int f = i >> 6, t = i & 63;
        Pc[(size_t)(h * NF + f) * SL + t0 + t] = make_float2(u.Dl[f][t], u.Dl[f + 33][t]);
    }
}

// K3: seq FFT-2048 of psf per (h,f), Stockham (fp16-packed LDS); Pf packed fp16 (Re,Im).
__global__ __launch_bounds__(256) void k3_psf_fft(const float2* __restrict__ Pc, unsigned int* __restrict__ Pf) {
    __shared__ unsigned int A[2304], B[2304];
    __shared__ float2 twd[512];
    int h = blockIdx.x / NF, f = blockIdx.x % NF;
    int tid = threadIdx.x;
    gen_twd(twd, tid);
    const float2* src = Pc + (size_t)(h * NF + f) * SL;
    {
        float2 v[8];
        #pragma unroll
        for (int r = 0; r < 4; ++r) v[r] = src[tid + 256 * r];
        #pragma unroll
        for (int r = 4; r < 8; ++r) v[r] = make_float2(0.f, 0.f);
        dft8v<-1>(v);
        #pragma unroll
        for (int r = 0; r < 8; ++r) A[FPAD(tid * 8 + r)] = hpk(v[r]);
    }
    __syncthreads();
    fft_stage_h<-1, 8, 8>(A, B, twd, tid);  __syncthreads();
    fft_stage_h<-1, 64, 8>(B, A, twd, tid); __syncthreads();
    unsigned int* dst = Pf + (size_t)(h * NF + f) * NSEQ;
    #pragma unroll
    for (int jj = 0; jj < 512; jj += 256) {
        int j = tid + jj;
        float2 v[4];
        #pragma unroll
        for (int r = 0; r < 4; ++r) v[r] = hup(A[FPAD(j + 512 * r)]);
        float2 w1 = twd[j];
        float2 w = w1;
        v[1] = cmul(v[1], w);
        w = cmul(w, w1); v[2] = cmul(v[2], w);
        w = cmul(w, w1); v[3] = cmul(v[3], w);
        dft4v<-1>(v);
        #pragma unroll
        for (int r = 0; r < 4; ++r) dst[j + 512 * r] = hpk(v[r]);
    }
}

// K5: Stockham fwd FFT (pointwise * Pf fused) -> inv FFT; fp16-packed LDS; Xc bf16 in/out.
__global__ __launch_bounds__(256) void k5_seq_conv(ushort* __restrict__ XcRe, ushort* __restrict__ XcIm,
                                                   const unsigned int* __restrict__ Pf) {
    __shared__ unsigned int A[2304], B[2304];
    __shared__ float2 twd[512];
    int f = blockIdx.x % NF;
    int bh = blockIdx.x / NF;
    int h = bh % NH;
    int tid = threadIdx.x;
    gen_twd(twd, tid);
    ushort* xre = XcRe + (size_t)(bh * NF + f) * SL;
    ushort* xim = XcIm + (size_t)(bh * NF + f) * SL;
    {
        float2 v[8];
        #pragma unroll
        for (int r = 0; r < 4; ++r)
            v[r] = make_float2(bf16val(xre[tid + 256 * r]), bf16val(xim[tid + 256 * r]));
        #pragma unroll
        for (int r = 4; r < 8; ++r) v[r] = make_float2(0.f, 0.f);
        dft8v<-1>(v);
        #pragma unroll
        for (int r = 0; r < 8; ++r) A[FPAD(tid * 8 + r)] = hpk(v[r]);
    }
    __syncthreads();
    fft_stage_h<-1, 8, 8>(A, B, twd, tid);   __syncthreads();
    fft_stage_h<-1, 64, 8>(B, A, twd, tid);  __syncthreads();
    // fwd last stage (L=512,R=4) fused with pointwise *Pf; A -> B (natural-order spectrum)
    {
        const unsigned int* pf = Pf + (size_t)(h * NF + f) * NSEQ;
        #pragma unroll
        for (int jj = 0; jj < 512; jj += 256) {
            int j = tid + jj;
            float2 v[4];
            #pragma unroll
            for (int r = 0; r < 4; ++r) v[r] = hup(A[FPAD(j + 512 * r)]);
            float2 w1 = twd[j];
            float2 w = w1;
            v[1] = cmul(v[1], w);
            w = cmul(w, w1); v[2] = cmul(v[2], w);
            w = cmul(w, w1); v[3] = cmul(v[3], w);
            dft4v<-1>(v);
            #pragma unroll
            for (int r = 0; r < 4; ++r) {
                float2 pv = hup(pf[j + 512 * r]);
                B[FPAD(j + 512 * r)] = hpk(cmul(v[r], pv));
            }
        }
    }
    __syncthreads();
    fft_stage_h<1, 1, 8>(B, A, twd, tid);  __syncthreads();
    fft_stage_h<1, 8, 8>(A, B, twd, tid);  __syncthreads();
    fft_stage_h<1, 64, 8>(B, A, twd, tid); __syncthreads();
    const float sc = 1.0f / 2048.0f;
    #pragma unroll
    for (int jj = 0; jj < 512; jj += 256) {
        int j = tid + jj;
        float2 v[4];
        #pragma unroll
        for (int r = 0; r < 4; ++r) v[r] = hup(A[FPAD(j + 512 * r)]);
        float2 w1 = twd[j];
        w1.y = -w1.y;
        float2 w = w1;
        v[1] = cmul(v[1], w);
        w = cmul(w, w1); v[2] = cmul(v[2], w);
        w = cmul(w, w1); v[3] = cmul(v[3], w);
        dft4v<1>(v);
        xre[j] = bf16bits(v[0].x * sc);        xim[j] = bf16bits(v[0].y * sc);
        xre[j + 512] = bf16bits(v[1].x * sc);  xim[j + 512] = bf16bits(v[1].y * sc);
    }
}

// K6m: inverse channel DFT-64 as single-pass bf16 MFMA + exact GELU -> Gh (bf16); Xc bf16 in.
__global__ __launch_bounds__(256) void k6_mfma(const ushort* __restrict__ XcRe,
                                               const ushort* __restrict__ XcIm,
                                               ushort* __restrict__ Gh) {
    __shared__ union {
        float Y32[64][133];
        ushort CH[64][72];
    } uy;
    __shared__ ushort YH[128][72];
    const int t0 = blockIdx.x * 128;
    const int bh = blockIdx.y;
    const int b = bh / NH, h = bh % NH;
    const int tid = threadIdx.x, lane = tid & 63, w = tid >> 6;

    for (int i = tid; i < 64 * 32; i += 256) {
        int c = i >> 5, tq = i & 31;
        const ushort* src = (c < 33) ? XcRe + (size_t)(bh * NF + c) * SL
                                     : XcIm + (size_t)(bh * NF + (c - 32)) * SL;
        ushort4v v = *(const ushort4v*)&src[t0 + tq * 4];
        uy.Y32[c][tq * 4 + 0] = bf16val(v.x); uy.Y32[c][tq * 4 + 1] = bf16val(v.y);
        uy.Y32[c][tq * 4 + 2] = bf16val(v.z); uy.Y32[c][tq * 4 + 3] = bf16val(v.w);
    }
    __syncthreads();
    for (int i = tid; i < 128 * 8; i += 256) {
        int t = i & 127, c0 = (i >> 7) * 8;
        float v[8];
        #pragma unroll
        for (int j = 0; j < 8; ++j) v[j] = uy.Y32[c0 + j][t];
        #pragma unroll
        for (int j = 0; j < 8; j += 2)
            *(unsigned int*)&YH[t][c0 + j] = pack2(v[j], v[j + 1]);
    }
    __syncthreads();
    for (int i = tid; i < 64 * 32; i += 256) {
        int e = i >> 5, c2 = (i & 31) * 2;
        float v[2];
        #pragma unroll
        for (int j = 0; j < 2; ++j) {
            int c = c2 + j;
            if (c <= 32) {
                float wt = (c == 0 || c == 32) ? (1.0f / 64.0f) : (2.0f / 64.0f);
                v[j] = wt * cosf(0.09817477042468103870f * (float)((c * e) & 63));
            } else {
                v[j] = -(2.0f / 64.0f) * sinf(0.09817477042468103870f * (float)(((c - 32) * e) & 63));
            }
        }
        *(unsigned int*)&uy.CH[e][c2] = pack2(v[0], v[1]);
    }
    __syncthreads();

    f32x4 acc[2][4] = {};
    const int lr = lane & 15, lg = lane >> 4;
    #pragma unroll
    for (int ks = 0; ks < 64; ks += 32) {
        const int kg = ks + lg * 8;
        bf16x8 bh8[4];
        #pragma unroll
        for (int n = 0; n < 4; ++n) bh8[n] = *(const bf16x8*)&uy.CH[n * 16 + lr][kg];
        #pragma unroll
        for (int m = 0; m < 2; ++m) {
            bf16x8 ah8 = *(const bf16x8*)&YH[w * 32 + m * 16 + lr][kg];
            #pragma unroll
            for (int n = 0; n < 4; ++n)
                acc[m][n] = __builtin_amdgcn_mfma_f32_16x16x32_bf16(ah8, bh8[n], acc[m][n], 0, 0, 0);
        }
    }
    #pragma unroll
    for (int n = 0; n < 4; ++n) {
        const int col = h * 64 + n * 16 + lr;
        #pragma unroll
        for (int m = 0; m < 2; ++m) {
            #pragma unroll
            for (int j = 0; j < 4; ++j) {
                int t = t0 + w * 32 + m * 16 + lg * 4 + j;
                float v = acc[m][n][j];
                float g = 0.5f * v * (1.0f + erff(v * 0.70710678118654752440f));
                Gh[((size_t)b * SL + t) * ED + col] = bf16bits(g);
            }
        }
    }
}

// K7: projection GEMM, single-pass bf16 MFMA; 64x128 tile, BK=64, 48 KB dbuf,
// XOR bank swizzle (slot ^= row&7, source-side), counted vmcnt(6) pipeline.
#define K7STAGE(p, kk) do { \
    const ushort* gA_ = Gh + (size_t)(i0 + aRow) * ED + (kk) + stCol; \
    const ushort* gB_ = Wh + (size_t)(j0 + bRow) * ED + (kk) + stCol; \
    __builtin_amdgcn_global_load_lds(GLB_U32(gA_),           LDS_U32(&Ah[p][aBase]),        16, 0, 0); \
    __builtin_amdgcn_global_load_lds(GLB_U32(gA_ + 8 * ED),  LDS_U32(&Ah[p][aBase + 512]),  16, 0, 0); \
    __builtin_amdgcn_global_load_lds(GLB_U32(gB_),           LDS_U32(&Bh[p][bBase]),        16, 0, 0); \
    __builtin_amdgcn_global_load_lds(GLB_U32(gB_ + 8 * ED),  LDS_U32(&Bh[p][bBase + 512]),  16, 0, 0); \
    __builtin_amdgcn_global_load_lds(GLB_U32(gB_ + 16 * ED), LDS_U32(&Bh[p][bBase + 1024]), 16, 0, 0); \
    __builtin_amdgcn_global_load_lds(GLB_U32(gB_ + 24 * ED), LDS_U32(&Bh[p][bBase + 1536]), 16, 0, 0); \
} while (0)

__global__ __launch_bounds__(256) void k7_mfma(
        const ushort* __restrict__ Gh, const ushort* __restrict__ Wh,
        const float* __restrict__ bias, float* __restrict__ out) {
    __shared__ ushort Ah[2][64 * 64];    // 8 KB x2
    __shared__ ushort Bh[2][128 * 64];   // 16 KB x2 -> 48 KB total
    const int bid = blockIdx.y * gridDim.x + blockIdx.x;
    const int swz = (bid & 7) * 96 + (bid >> 3);      // 768 = 8 x 96, bijective
    const int j0 = (swz % 6) * 128;
    const int i0 = (swz / 6) * 64;
    const int tid = threadIdx.x;
    const int lane = tid & 63, wid = tid >> 6;
    const int wm = wid >> 1, wn = wid & 1;            // wave = 32x64 output

    const int aRow = wid * 16 + (lane >> 3);
    const int bRow = wid * 32 + (lane >> 3);
    const int stCol = (((lane & 7) ^ ((lane >> 3) & 7)) * 8);
    const int aBase = wid * 1024;   // 16 rows * 64
    const int bBase = wid * 2048;   // 32 rows * 64

    f32x4 acc[2][4] = {};

    const int lr = lane & 15, lg = lane >> 4;
    const int arow = wm * 32 + lr;
    const int brow = wn * 64 + lr;
    const int sw0 = ((lg ^ (lr & 7)) * 8);            // ks=0: slot lg
    const int sw1 = (((4 + lg) ^ (lr & 7)) * 8);      // ks=1: slot 4+lg

    K7STAGE(0, 0);

    for (int t = 0; t < 12; ++t) {
        const int cur = t & 1;
        if (t < 11) {
            K7STAGE(cur ^ 1, (t + 1) * 64);
            asm volatile("s_waitcnt vmcnt(6)" ::: "memory");  // stage(t) landed
        } else {
            asm volatile("s_waitcnt vmcnt(0)" ::: "memory");
        }
        __builtin_amdgcn_s_barrier();

        #pragma unroll
        for (int ks = 0; ks < 2; ++ks) {
            const int sw = ks ? sw1 : sw0;
            bf16x8 a0 = *(const bf16x8*)&Ah[cur][arow * 64 + sw];
            bf16x8 a1 = *(const bf16x8*)&Ah[cur][(arow + 16) * 64 + sw];
            bf16x8 b0 = *(const bf16x8*)&Bh[cur][brow * 64 + sw];
            bf16x8 b1 = *(const bf16x8*)&Bh[cur][(brow + 16) * 64 + sw];
            bf16x8 b2 = *(const bf16x8*)&Bh[cur][(brow + 32) * 64 + sw];
            bf16x8 b3 = *(const bf16x8*)&Bh[cur][(brow + 48) * 64 + sw];
            acc[0][0] = __builtin_amdgcn_mfma_f32_16x16x32_bf16(a0, b0, acc[0][0], 0, 0, 0);
            acc[0][1] = __builtin_amdgcn_mfma_f32_16x16x32_bf16(a0, b1, acc[0][1], 0, 0, 0);
            acc[0][2] = __builtin_amdgcn_mfma_f32_16x16x32_bf16(a0, b2, acc[0][2], 0, 0, 0);
            acc[0][3] = __builtin_amdgcn_mfma_f32_16x16x32_bf16(a0, b3, acc[0][3], 0, 0, 0);
            acc[1][0] = __builtin_amdgcn_mfma_f32_16x16x32_bf16(a1, b0, acc[1][0], 0, 0, 0);
            acc[1][1] = __builtin_amdgcn_mfma_f32_16x16x32_bf16(a1, b1, acc[1][1], 0, 0, 0);
            acc[1][2] = __builtin_amdgcn_mfma_f32_16x16x32_bf16(a1, b2, acc[1][2], 0, 0, 0);
            acc[1][3] = __builtin_amdgcn_mfma_f32_16x16x32_bf16(a1, b3, acc[1][3], 0, 0, 0);
        }
        asm volatile("s_waitcnt lgkmcnt(0)" ::: "memory");
        __builtin_amdgcn_s_barrier();
    }

    const int ocol0 = j0 + wn * 64 + lr;
    const int orow0 = i0 + wm * 32 + (lane >> 4) * 4;
    #pragma unroll
    for (int n = 0; n < 4; ++n) {
        const float bv = bias[ocol0 + n * 16];
        #pragma unroll
        for (int m = 0; m < 2; ++m) {
            #pragma unroll
            for (int j = 0; j < 4; ++j) {
                out[(size_t)(orow0 + m * 16 + j) * ED + ocol0 + n * 16] = acc[m][n][j] + bv;
            }
        }
    }
}

extern "C" void kernel_launch(void* const* d_in, const int* in_sizes, int n_in,
                              void* d_out, int out_size, void* d_ws, size_t ws_size,
                              hipStream_t stream) {
    (void)in_sizes; (void)n_in; (void)out_size; (void)ws_size;
    const float* emb  = (const float*)d_in[0];   // [8,1024,768]
    const float* tp   = (const float*)d_in[1];   // [12,2047,64]
    const float* W    = (const float*)d_in[2];   // [768,768]
    const float* bias = (const float*)d_in[3];   // [768]

    float* out_conv = (float*)d_out;                             // 8*1024*768
    float* out_psf  = out_conv + (size_t)NB * SL * ED;           // 12*2047*64

    // workspace layout:
    float2*       Pc = (float2*)d_ws;                            // 12*33*1024 complex fp32 (dead after k3)
    unsigned int* Pf = (unsigned int*)(Pc + (size_t)NH * NF * SL);  // 12*33*2048 packed fp16x2
    ushort* XcRe = (ushort*)(Pf + (size_t)NH * NF * NSEQ);       // 96*33*1024 bf16
    ushort* XcIm = XcRe + (size_t)NB * NH * NF * SL;             // 96*33*1024 bf16
    ushort* Gh   = XcIm + (size_t)NB * NH * NF * SL;             // 8192*768 bf16
    ushort* Whh  = Gh + (size_t)NB * SL * ED;                    // 768*768 bf16
    // softmax partial sums overlaid on Pf start (dead until k3 writes Pf): 98 KB < 3.2 MB
    float* pSum = (float*)Pf;          // 12*32*64

    k4_fat<<<dim3(1152), dim3(256), 0, stream>>>(emb, tp, W, pSum, out_psf, Whh, XcRe, XcIm);
    k2_mfma<<<dim3(SL / 64, NH), dim3(256), 0, stream>>>(tp, pSum, out_psf, Pc);
    k3_psf_fft<<<dim3(NH * NF), dim3(256), 0, stream>>>(Pc, Pf);
    k5_seq_conv<<<dim3(NB * NH * NF), dim3(256), 0, stream>>>(XcRe, XcIm, Pf);
    k6_mfma<<<dim3(SL / 128, NB * NH), dim3(256), 0, stream>>>(XcRe, XcIm, Gh);
    k7_mfma<<<dim3(ED / 128, (NB * SL) / 64), dim3(256), 0, stream>>>(
        Gh, Whh, bias, out_conv);
}